// Round 6
// baseline (878.676 us; speedup 1.0000x reference)
//
#include <hip/hip_runtime.h>
#include <hip/hip_bf16.h>

// ---------------------------------------------------------------------------
// EncoderBlock (differential attention + swiGLU FFN), MI355X / gfx950
// R5: attention pair-split (p across blocks). R4 showed occupancy is register-
//     capped (~176 unified regs/wave -> 2 waves/SIMD), not grid-capped.
//     Halving per-wave state (one attention map per block) targets 4+/SIMD.
//     + T1 XCD-aware block swizzle in all GEMMs (nwg%8==0 everywhere).
// ---------------------------------------------------------------------------

typedef __attribute__((ext_vector_type(8))) __bf16 bf16x8;
typedef __attribute__((ext_vector_type(4))) float f32x4;

#define GAS __attribute__((address_space(1)))
#define LAS __attribute__((address_space(3)))

__device__ __forceinline__ unsigned short f2bf(float f) {
  unsigned u = __float_as_uint(f);
  u += 0x7fffu + ((u >> 16) & 1u);   // RNE
  return (unsigned short)(u >> 16);
}
__device__ __forceinline__ float bf2f(unsigned short s) {
  return __uint_as_float(((unsigned)s) << 16);
}

// ---------------------------------------------------------------------------
// Transpose + convert: W[K][N] fp32 -> WT[N][K] bf16 * scale.
// ---------------------------------------------------------------------------
__global__ __launch_bounds__(256)
void transpose_cvt(const float* __restrict__ W, unsigned short* __restrict__ WT,
                   int K, int N, float scale) {
  __shared__ float tile[64][65];
  const int n0 = blockIdx.x * 64, k0 = blockIdx.y * 64;
  const int tr = threadIdx.x >> 4, tc = (threadIdx.x & 15) * 4;
#pragma unroll
  for (int i = 0; i < 4; ++i) {
    const float4 v = *(const float4*)&W[(size_t)(k0 + tr + i * 16) * N + n0 + tc];
    tile[tr + i * 16][tc + 0] = v.x;
    tile[tr + i * 16][tc + 1] = v.y;
    tile[tr + i * 16][tc + 2] = v.z;
    tile[tr + i * 16][tc + 3] = v.w;
  }
  __syncthreads();
#pragma unroll
  for (int i = 0; i < 4; ++i) {
    const int n = tr + i * 16;
    ushort4 o;
    o.x = f2bf(tile[tc + 0][n] * scale);
    o.y = f2bf(tile[tc + 1][n] * scale);
    o.z = f2bf(tile[tc + 2][n] * scale);
    o.w = f2bf(tile[tc + 3][n] * scale);
    *(ushort4*)&WT[(size_t)(n0 + n) * K + k0 + tc] = o;
  }
}

// ---------------------------------------------------------------------------
// V transpose (bf16): v[b,s,h*128+e] -> VT[(b*8+h)*128+e][S].
// ---------------------------------------------------------------------------
__global__ __launch_bounds__(256)
void v_transpose(const unsigned short* __restrict__ v, unsigned short* __restrict__ VT) {
  __shared__ unsigned short tile[64][65];
  const int s0 = blockIdx.x * 64, e0 = blockIdx.y * 64, bh = blockIdx.z;
  const int b = bh >> 3, h = bh & 7;
  const int tr = threadIdx.x >> 4, tc = (threadIdx.x & 15) * 4;
  const size_t inbase = (size_t)b * 2048 * 1024 + h * 128;
#pragma unroll
  for (int i = 0; i < 4; ++i) {
    const int r = tr + i * 16;
    const ushort4 val = *(const ushort4*)&v[inbase + (size_t)(s0 + r) * 1024 + e0 + tc];
    tile[r][tc + 0] = val.x;
    tile[r][tc + 1] = val.y;
    tile[r][tc + 2] = val.z;
    tile[r][tc + 3] = val.w;
  }
  __syncthreads();
#pragma unroll
  for (int i = 0; i < 4; ++i) {
    const int n = tr + i * 16;
    ushort4 oo;
    oo.x = tile[tc + 0][n];
    oo.y = tile[tc + 1][n];
    oo.z = tile[tc + 2][n];
    oo.w = tile[tc + 3][n];
    *(ushort4*)&VT[(size_t)(bh * 128 + e0 + n) * 2048 + s0 + tc] = oo;
  }
}

// ---------------------------------------------------------------------------
// lambda[h]
// ---------------------------------------------------------------------------
__global__ void lam_kernel(const float* __restrict__ lq1, const float* __restrict__ lk1,
                           const float* __restrict__ lq2, const float* __restrict__ lk2,
                           float* __restrict__ lam) {
  const int w = threadIdx.x >> 6, d = threadIdx.x & 63;
  float a = lq1[w * 64 + d] * lk1[w * 64 + d];
  float c = lq2[w * 64 + d] * lk2[w * 64 + d];
#pragma unroll
  for (int off = 32; off; off >>= 1) {
    a += __shfl_xor(a, off);
    c += __shfl_xor(c, off);
  }
  if (d == 0) lam[w] = __expf(a) - __expf(c) + 0.8f;
}

// ---------------------------------------------------------------------------
// LayerNorm over rows of 1024.
// ---------------------------------------------------------------------------
template <int WRITE_F32>
__global__ __launch_bounds__(256)
void ln_kernel(const float* __restrict__ x, const float* __restrict__ g,
               const float* __restrict__ bsh, unsigned short* __restrict__ obf,
               float* __restrict__ of32) {
  __shared__ float red[16];
  const int row = blockIdx.x, tid = threadIdx.x;
  const float4 v = *(const float4*)&x[(size_t)row * 1024 + tid * 4];
  float s = v.x + v.y + v.z + v.w;
  float q = v.x * v.x + v.y * v.y + v.z * v.z + v.w * v.w;
#pragma unroll
  for (int off = 32; off; off >>= 1) {
    s += __shfl_xor(s, off);
    q += __shfl_xor(q, off);
  }
  if ((tid & 63) == 0) {
    red[tid >> 6] = s;
    red[8 + (tid >> 6)] = q;
  }
  __syncthreads();
  s = red[0] + red[1] + red[2] + red[3];
  q = red[8] + red[9] + red[10] + red[11];
  const float mean = s * (1.f / 1024.f);
  const float var = q * (1.f / 1024.f) - mean * mean;
  const float rstd = rsqrtf(var + 1e-5f);
  const float4 gg = *(const float4*)&g[tid * 4];
  const float4 bb = *(const float4*)&bsh[tid * 4];
  float y0 = (v.x - mean) * rstd * gg.x + bb.x;
  float y1 = (v.y - mean) * rstd * gg.y + bb.y;
  float y2 = (v.z - mean) * rstd * gg.z + bb.z;
  float y3 = (v.w - mean) * rstd * gg.w + bb.w;
  const size_t base = (size_t)row * 1024 + tid * 4;
  ushort4 o;
  o.x = f2bf(y0); o.y = f2bf(y1); o.z = f2bf(y2); o.w = f2bf(y3);
  *(ushort4*)&obf[base] = o;
  if (WRITE_F32) {
    *(float4*)&of32[base] = make_float4(y0, y1, y2, y3);
  }
}

// ---------------------------------------------------------------------------
// GEMM: C[M][N] = A[M][K](bf16) @ BT[N][K](bf16)^T + bias*bscale.
// 128x128 tile, BK=32, 4 waves, global_load_lds(16B) staging.
// T1: XCD-aware bijective block swizzle (requires nwg % 8 == 0 — true for
// every launch in this file).
// ---------------------------------------------------------------------------
template <int EPI>
__global__ __launch_bounds__(256)
void gemm_bf16(const unsigned short* __restrict__ A,
               const unsigned short* __restrict__ BT,
               const float* __restrict__ bias,
               const float* __restrict__ res,
               const unsigned short* __restrict__ gate_u,
               void* __restrict__ Cout, int M, int N, int K, float bscale) {
  __shared__ unsigned short ldsA[128 * 32];
  __shared__ unsigned short ldsB[128 * 32];
  const int tid = threadIdx.x;
  const int wv = tid >> 6, ln = tid & 63, lg = ln >> 4, lc = ln & 15;
  const int wm = wv >> 1, wn = wv & 1;
  // T1 swizzle: contiguous chunk of tiles per XCD
  const int nwg = gridDim.x * gridDim.y;
  const int linear = blockIdx.y * gridDim.x + blockIdx.x;
  const int swz = (linear & 7) * (nwg >> 3) + (linear >> 3);
  const int m0 = (swz / gridDim.x) * 128, n0 = (swz % gridDim.x) * 128;
  const int rsub = ln >> 2, acol = (ln & 3) * 8;

  f32x4 acc[4][4];
#pragma unroll
  for (int i = 0; i < 4; ++i)
#pragma unroll
    for (int j = 0; j < 4; ++j) acc[i][j] = (f32x4)0.f;

  for (int k0 = 0; k0 < K; k0 += 32) {
#pragma unroll
    for (int j = 0; j < 2; ++j) {
      const int rowblk = wv * 32 + j * 16;
      const unsigned short* ga = A + (size_t)(m0 + rowblk + rsub) * K + (k0 + acol);
      __builtin_amdgcn_global_load_lds((GAS void*)ga, (LAS void*)&ldsA[rowblk * 32], 16, 0, 0);
      const unsigned short* gb = BT + (size_t)(n0 + rowblk + rsub) * K + (k0 + acol);
      __builtin_amdgcn_global_load_lds((GAS void*)gb, (LAS void*)&ldsB[rowblk * 32], 16, 0, 0);
    }
    __syncthreads();
    bf16x8 af[4], bf[4];
#pragma unroll
    for (int m = 0; m < 4; ++m)
      af[m] = *(const bf16x8*)&ldsA[(wm * 64 + m * 16 + lc) * 32 + lg * 8];
#pragma unroll
    for (int n = 0; n < 4; ++n)
      bf[n] = *(const bf16x8*)&ldsB[(wn * 64 + n * 16 + lc) * 32 + lg * 8];
#pragma unroll
    for (int m = 0; m < 4; ++m)
#pragma unroll
      for (int n = 0; n < 4; ++n)
        acc[m][n] = __builtin_amdgcn_mfma_f32_16x16x32_bf16(af[m], bf[n], acc[m][n], 0, 0, 0);
    __syncthreads();
  }

#pragma unroll
  for (int m = 0; m < 4; ++m) {
#pragma unroll
    for (int n = 0; n < 4; ++n) {
      const int c = n0 + wn * 64 + n * 16 + lc;
      const float bc = bias[c] * bscale;
#pragma unroll
      for (int j = 0; j < 4; ++j) {
        const int r = m0 + wm * 64 + m * 16 + lg * 4 + j;
        const size_t idx = (size_t)r * N + c;
        const float v = acc[m][n][j] + bc;
        if (EPI == 0) {
          ((unsigned short*)Cout)[idx] = f2bf(v);
        } else if (EPI == 1) {
          ((float*)Cout)[idx] = res[idx] + v;
        } else {
          const float uu = bf2f(gate_u[idx]);
          const float sw = v / (1.f + __expf(-v));   // silu
          ((unsigned short*)Cout)[idx] = f2bf(uu * sw);
        }
      }
    }
  }
}

// ---------------------------------------------------------------------------
// Differential attention partials, fixed-max softmax, t-split NT=2, PAIR-SPLIT.
// grid(2048): id = xcd(3b) | qt(5b)<<3 | p(1b)<<8 | tcn(1b)<<9 | bhHi(1b)<<10.
// Each block: ONE attention map (pair pp), 64 q-rows x 1024 keys.
// Per-wave state halved vs R4 (O[8] f32x4) -> target 4+ waves/SIMD.
// ---------------------------------------------------------------------------
__global__ __launch_bounds__(256)
void attn_kernel(const unsigned short* __restrict__ q,
                 const unsigned short* __restrict__ k,
                 const unsigned short* __restrict__ VT,
                 float* __restrict__ Opart,
                 float* __restrict__ lsumPart) {
  constexpr int S = 2048;
  __shared__ unsigned short p_lds[4][2][512];   // [wave][buf][16x32 swz]
  const int tid = threadIdx.x, w = tid >> 6, ln = tid & 63, lg = ln >> 4, lc = ln & 15;
  const int id = blockIdx.x;
  const int bh = (id & 7) + 8 * (id >> 10);
  const int qt = (id >> 3) & 31;
  const int pp = (id >> 8) & 1;
  const int tcn = (id >> 9) & 1;
  const size_t chan = (size_t)(bh >> 3) * S * 1024 + (bh & 7) * 128;
  const size_t vtbase = (size_t)bh * 128 * S;
  const int qrow = qt * 64 + w * 16 + lc;

  bf16x8 qf[2];
#pragma unroll
  for (int ks = 0; ks < 2; ++ks)
    qf[ks] = *(const bf16x8*)&q[chan + (size_t)qrow * 1024 + pp * 64 + ks * 32 + lg * 8];

  f32x4 O[8];
#pragma unroll
  for (int ef = 0; ef < 8; ++ef) O[ef] = (f32x4)0.f;
  float lsum[4] = {0.f, 0.f, 0.f, 0.f};

  const int prd = ((lc * 64 + lg * 16) ^ ((lc & 7) << 4)) >> 1;   // PV A-frag read

  auto tile = [&](int t0, int buf) {
    bf16x8 vf[8];
#pragma unroll
    for (int ef = 0; ef < 8; ++ef)
      vf[ef] = *(const bf16x8*)&VT[vtbase + (size_t)(ef * 16 + lc) * S + t0 + lg * 8];

    bf16x8 kf[2][2];
#pragma unroll
    for (int tf = 0; tf < 2; ++tf)
#pragma unroll
      for (int ks = 0; ks < 2; ++ks)
        kf[tf][ks] = *(const bf16x8*)&k[chan + (size_t)(t0 + tf * 16 + lc) * 1024 +
                                        pp * 64 + ks * 32 + lg * 8];
    f32x4 sfr[2];
    __builtin_amdgcn_s_setprio(1);
#pragma unroll
    for (int tf = 0; tf < 2; ++tf) {
      f32x4 acc = (f32x4)0.f;
#pragma unroll
      for (int ks = 0; ks < 2; ++ks)
        acc = __builtin_amdgcn_mfma_f32_16x16x32_bf16(qf[ks], kf[tf][ks], acc, 0, 0, 0);
      sfr[tf] = acc;
    }
    __builtin_amdgcn_s_setprio(0);

#pragma unroll
    for (int tf = 0; tf < 2; ++tf)
#pragma unroll
      for (int j = 0; j < 4; ++j) {
        const float e = __expf(sfr[tf][j]);
        lsum[j] += e;
        const int qq = lg * 4 + j;
        const int wi = ((qq * 64 + (tf * 16 + lc) * 2) ^ ((qq & 7) << 4)) >> 1;
        p_lds[w][buf][wi] = f2bf(e);
      }

    const bf16x8 pa = *(const bf16x8*)&p_lds[w][buf][prd];
    __builtin_amdgcn_s_setprio(1);
#pragma unroll
    for (int ef = 0; ef < 8; ++ef)
      O[ef] = __builtin_amdgcn_mfma_f32_16x16x32_bf16(pa, vf[ef], O[ef], 0, 0, 0);
    __builtin_amdgcn_s_setprio(0);
  };

  const int tbeg = tcn * (S / 2);
  for (int t0 = tbeg; t0 < tbeg + S / 2; t0 += 64) {
    tile(t0, 0);
    tile(t0 + 32, 1);
  }

  // write partials
  const size_t rowbase = ((size_t)tcn * 16 + bh) * S;
#pragma unroll
  for (int j = 0; j < 4; ++j) {
    float s = lsum[j];
    s += __shfl_xor(s, 1);
    s += __shfl_xor(s, 2);
    s += __shfl_xor(s, 4);
    s += __shfl_xor(s, 8);
    const int row = qt * 64 + w * 16 + lg * 4 + j;
    if (lc == 0)
      lsumPart[(rowbase + row) * 2 + pp] = s;
#pragma unroll
    for (int ef = 0; ef < 8; ++ef)
      Opart[(rowbase + row) * 256 + pp * 128 + ef * 16 + lc] = O[ef][j];
  }
}

// ---------------------------------------------------------------------------
// Combine t-chunk partials: normalize, lambda-diff, headwise GroupNorm, *0.2.
// ---------------------------------------------------------------------------
__global__ __launch_bounds__(256)
void attn_reduce(const float* __restrict__ Opart, const float* __restrict__ lsumPart,
                 const float* __restrict__ lam,
                 const float* __restrict__ gn_w, const float* __restrict__ gn_b,
                 unsigned short* __restrict__ o) {
  constexpr int S = 2048;
  const int gw = (blockIdx.x * 256 + threadIdx.x) >> 6;
  const int ln = threadIdx.x & 63;
  const int bh = gw >> 11, s = gw & 2047;
  const int b = bh >> 3, h = bh & 7;
  const size_t r0 = ((size_t)bh * S + s) * 256;
  const size_t r1 = (((size_t)16 + bh) * S + s) * 256;
  const int e = ln * 2;
  const float2 o1a = *(const float2*)&Opart[r0 + e];
  const float2 o1b = *(const float2*)&Opart[r1 + e];
  const float2 o2a = *(const float2*)&Opart[r0 + 128 + e];
  const float2 o2b = *(const float2*)&Opart[r1 + 128 + e];
  const size_t l0 = ((size_t)bh * S + s) * 2;
  const size_t l1 = (((size_t)16 + bh) * S + s) * 2;
  const float inv1 = 1.f / (lsumPart[l0] + lsumPart[l1]);
  const float inv2 = lam[h] / (lsumPart[l0 + 1] + lsumPart[l1 + 1]);
  float d0 = (o1a.x + o1b.x) * inv1 - (o2a.x + o2b.x) * inv2;
  float d1 = (o1a.y + o1b.y) * inv1 - (o2a.y + o2b.y) * inv2;
  float sum = d0 + d1, sq = d0 * d0 + d1 * d1;
#pragma unroll
  for (int off = 32; off; off >>= 1) {
    sum += __shfl_xor(sum, off);
    sq += __shfl_xor(sq, off);
  }
  const float mean = sum * (1.f / 128.f);
  const float var = sq * (1.f / 128.f) - mean * mean;
  const float rstd = rsqrtf(var + 1e-5f);
  const float v0 = ((d0 - mean) * rstd * gn_w[h * 128 + e] + gn_b[h * 128 + e]) * 0.2f;
  const float v1 = ((d1 - mean) * rstd * gn_w[h * 128 + e + 1] + gn_b[h * 128 + e + 1]) * 0.2f;
  ushort2 ov;
  ov.x = f2bf(v0);
  ov.y = f2bf(v1);
  *(ushort2*)&o[(size_t)b * S * 1024 + (size_t)s * 1024 + h * 128 + e] = ov;
}

// ---------------------------------------------------------------------------
extern "C" void kernel_launch(void* const* d_in, const int* in_sizes, int n_in,
                              void* d_out, int out_size, void* d_ws, size_t ws_size,
                              hipStream_t stream) {
  (void)in_sizes; (void)n_in; (void)out_size; (void)ws_size;
  const float* x    = (const float*)d_in[0];
  const float* ln1g = (const float*)d_in[1];
  const float* ln1b = (const float*)d_in[2];
  const float* ln2g = (const float*)d_in[3];
  const float* ln2b = (const float*)d_in[4];
  const float* Wq   = (const float*)d_in[5];
  const float* bq   = (const float*)d_in[6];
  const float* Wk   = (const float*)d_in[7];
  const float* bk   = (const float*)d_in[8];
  const float* Wv   = (const float*)d_in[9];
  const float* bv   = (const float*)d_in[10];
  const float* Wo   = (const float*)d_in[11];
  const float* bo   = (const float*)d_in[12];
  const float* lq1  = (const float*)d_in[13];
  const float* lk1  = (const float*)d_in[14];
  const float* lq2  = (const float*)d_in[15];
  const float* lk2  = (const float*)d_in[16];
  const float* gnw  = (const float*)d_in[17];
  const float* gnb  = (const float*)d_in[18];
  const float* W1   = (const float*)d_in[19];
  const float* b1   = (const float*)d_in[20];
  const float* Wg   = (const float*)d_in[21];
  const float* bg   = (const float*)d_in[22];
  const float* W2   = (const float*)d_in[23];
  const float* b2   = (const float*)d_in[24];

  const int B = 2, S = 2048, D = 1024, F = 4096;
  const int M = B * S;  // 4096
  const float qscale = 0.125f;

  char* ws = (char*)d_ws;
  size_t off = 0;
  auto alloc = [&](size_t bytes) {
    char* p = ws + off;
    off += (bytes + 255) & ~(size_t)255;
    return p;
  };
  unsigned short* WqT = (unsigned short*)alloc((size_t)D * D * 2);
  unsigned short* WkT = (unsigned short*)alloc((size_t)D * D * 2);
  unsigned short* WvT = (unsigned short*)alloc((size_t)D * D * 2);
  unsigned short* WoT = (unsigned short*)alloc((size_t)D * D * 2);
  unsigned short* W1T = (unsigned short*)alloc((size_t)F * D * 2);
  unsigned short* WgT = (unsigned short*)alloc((size_t)F * F * 2);
  unsigned short* W2T = (unsigned short*)alloc((size_t)D * F * 2);
  float*          lamw= (float*)alloc(256);
  unsigned short* h_bf= (unsigned short*)alloc((size_t)M * D * 2);
  unsigned short* q_bf= (unsigned short*)alloc((size_t)M * D * 2);
  unsigned short* k_bf= (unsigned short*)alloc((size_t)M * D * 2);
  unsigned short* v_bf= (unsigned short*)alloc((size_t)M * D * 2);
  unsigned short* o_bf= (unsigned short*)alloc((size_t)M * D * 2);
  float*          x1  = (float*)alloc((size_t)M * D * 4);
  float*          x2  = (float*)alloc((size_t)M * D * 4);
  unsigned short* x2b = (unsigned short*)alloc((size_t)M * D * 2);
  unsigned short* u_bf= (unsigned short*)alloc((size_t)M * F * 2);
  unsigned short* w_bf= h_bf;   // gated act reuses h span (dead after q/k/v GEMMs)

  // Attention scratch overlays:
  //  Opart (64MB fp32) overlays x1+x2+x2b+u_bf[0:24MB) — all dead during attn.
  //  VT (8MB) in the last 8MB of the u_bf span; lsumP fresh 1MB.
  float* Opart = (float*)x1;
  float* lsumP = (float*)alloc((size_t)2 * 16 * S * 2 * 4);
  unsigned short* VT = u_bf + (size_t)12 * 1024 * 1024;

  // --- weight prep ---
  transpose_cvt<<<dim3(D / 64, D / 64), 256, 0, stream>>>(Wq, WqT, D, D, qscale);
  transpose_cvt<<<dim3(D / 64, D / 64), 256, 0, stream>>>(Wk, WkT, D, D, 1.0f);
  transpose_cvt<<<dim3(D / 64, D / 64), 256, 0, stream>>>(Wv, WvT, D, D, 1.0f);
  transpose_cvt<<<dim3(D / 64, D / 64), 256, 0, stream>>>(Wo, WoT, D, D, 1.0f);
  transpose_cvt<<<dim3(F / 64, D / 64), 256, 0, stream>>>(W1, W1T, D, F, 1.0f);
  transpose_cvt<<<dim3(F / 64, F / 64), 256, 0, stream>>>(Wg, WgT, F, F, 1.0f);
  transpose_cvt<<<dim3(D / 64, F / 64), 256, 0, stream>>>(W2, W2T, F, D, 1.0f);
  lam_kernel<<<1, 512, 0, stream>>>(lq1, lk1, lq2, lk2, lamw);

  // --- attention sublayer ---
  ln_kernel<0><<<M, 256, 0, stream>>>(x, ln1g, ln1b, h_bf, nullptr);
  gemm_bf16<0><<<dim3(D / 128, M / 128), 256, 0, stream>>>(h_bf, WqT, bq, nullptr, nullptr, q_bf, M, D, D, qscale);
  gemm_bf16<0><<<dim3(D / 128, M / 128), 256, 0, stream>>>(h_bf, WkT, bk, nullptr, nullptr, k_bf, M, D, D, 1.0f);
  gemm_bf16<0><<<dim3(D / 128, M / 128), 256, 0, stream>>>(h_bf, WvT, bv, nullptr, nullptr, v_bf, M, D, D, 1.0f);
  v_transpose<<<dim3(S / 64, 2, 16), 256, 0, stream>>>(v_bf, VT);
  attn_kernel<<<dim3(2048), 256, 0, stream>>>(q_bf, k_bf, VT, Opart, lsumP);
  attn_reduce<<<dim3(8192), 256, 0, stream>>>(Opart, lsumP, lamw, gnw, gnb, o_bf);
  gemm_bf16<1><<<dim3(D / 128, M / 128), 256, 0, stream>>>(o_bf, WoT, bo, x, nullptr, x1, M, D, D, 1.0f);

  // --- FFN sublayer ---
  ln_kernel<1><<<M, 256, 0, stream>>>(x1, ln2g, ln2b, x2b, x2);
  gemm_bf16<0><<<dim3(F / 128, M / 128), 256, 0, stream>>>(x2b, W1T, b1, nullptr, nullptr, u_bf, M, F, D, 1.0f);
  gemm_bf16<2><<<dim3(F / 128, M / 128), 256, 0, stream>>>(u_bf, WgT, bg, nullptr, u_bf, w_bf, M, F, F, 1.0f);
  gemm_bf16<1><<<dim3(D / 128, M / 128), 256, 0, stream>>>(w_bf, W2T, b2, x2, nullptr, (float*)d_out, M, D, F, 1.0f);
}

// Round 7
// 640.459 us; speedup vs baseline: 1.3719x; 1.3719x over previous
//
#include <hip/hip_runtime.h>
#include <hip/hip_bf16.h>

// ---------------------------------------------------------------------------
// EncoderBlock (differential attention + swiGLU FFN), MI355X / gfx950
// R6: attention rebuilt on the 2-phase LDS-staged pipeline:
//     - K/V tiles staged via global_load_lds (no VGPR round-trip; R2-R5's
//       stall was serialized per-fragment global loads under reg pressure)
//     - pre-swizzled global source + linear LDS dest (m173 pattern), XOR-
//       swizzled reads -> conflict-light ds_read_b128
//     - both pairs per wave (ILP), t-split NT=2, one barrier per 32-key tile
// ---------------------------------------------------------------------------

typedef __attribute__((ext_vector_type(8))) __bf16 bf16x8;
typedef __attribute__((ext_vector_type(4))) float f32x4;

#define GAS __attribute__((address_space(1)))
#define LAS __attribute__((address_space(3)))

__device__ __forceinline__ unsigned short f2bf(float f) {
  unsigned u = __float_as_uint(f);
  u += 0x7fffu + ((u >> 16) & 1u);   // RNE
  return (unsigned short)(u >> 16);
}
__device__ __forceinline__ float bf2f(unsigned short s) {
  return __uint_as_float(((unsigned)s) << 16);
}

// ---------------------------------------------------------------------------
// Transpose + convert: W[K][N] fp32 -> WT[N][K] bf16 * scale.
// ---------------------------------------------------------------------------
__global__ __launch_bounds__(256)
void transpose_cvt(const float* __restrict__ W, unsigned short* __restrict__ WT,
                   int K, int N, float scale) {
  __shared__ float tile[64][65];
  const int n0 = blockIdx.x * 64, k0 = blockIdx.y * 64;
  const int tr = threadIdx.x >> 4, tc = (threadIdx.x & 15) * 4;
#pragma unroll
  for (int i = 0; i < 4; ++i) {
    const float4 v = *(const float4*)&W[(size_t)(k0 + tr + i * 16) * N + n0 + tc];
    tile[tr + i * 16][tc + 0] = v.x;
    tile[tr + i * 16][tc + 1] = v.y;
    tile[tr + i * 16][tc + 2] = v.z;
    tile[tr + i * 16][tc + 3] = v.w;
  }
  __syncthreads();
#pragma unroll
  for (int i = 0; i < 4; ++i) {
    const int n = tr + i * 16;
    ushort4 o;
    o.x = f2bf(tile[tc + 0][n] * scale);
    o.y = f2bf(tile[tc + 1][n] * scale);
    o.z = f2bf(tile[tc + 2][n] * scale);
    o.w = f2bf(tile[tc + 3][n] * scale);
    *(ushort4*)&WT[(size_t)(n0 + n) * K + k0 + tc] = o;
  }
}

// ---------------------------------------------------------------------------
// V transpose (bf16): v[b,s,h*128+e] -> VT[(b*8+h)*128+e][S].
// ---------------------------------------------------------------------------
__global__ __launch_bounds__(256)
void v_transpose(const unsigned short* __restrict__ v, unsigned short* __restrict__ VT) {
  __shared__ unsigned short tile[64][65];
  const int s0 = blockIdx.x * 64, e0 = blockIdx.y * 64, bh = blockIdx.z;
  const int b = bh >> 3, h = bh & 7;
  const int tr = threadIdx.x >> 4, tc = (threadIdx.x & 15) * 4;
  const size_t inbase = (size_t)b * 2048 * 1024 + h * 128;
#pragma unroll
  for (int i = 0; i < 4; ++i) {
    const int r = tr + i * 16;
    const ushort4 val = *(const ushort4*)&v[inbase + (size_t)(s0 + r) * 1024 + e0 + tc];
    tile[r][tc + 0] = val.x;
    tile[r][tc + 1] = val.y;
    tile[r][tc + 2] = val.z;
    tile[r][tc + 3] = val.w;
  }
  __syncthreads();
#pragma unroll
  for (int i = 0; i < 4; ++i) {
    const int n = tr + i * 16;
    ushort4 oo;
    oo.x = tile[tc + 0][n];
    oo.y = tile[tc + 1][n];
    oo.z = tile[tc + 2][n];
    oo.w = tile[tc + 3][n];
    *(ushort4*)&VT[(size_t)(bh * 128 + e0 + n) * 2048 + s0 + tc] = oo;
  }
}

// ---------------------------------------------------------------------------
// lambda[h]
// ---------------------------------------------------------------------------
__global__ void lam_kernel(const float* __restrict__ lq1, const float* __restrict__ lk1,
                           const float* __restrict__ lq2, const float* __restrict__ lk2,
                           float* __restrict__ lam) {
  const int w = threadIdx.x >> 6, d = threadIdx.x & 63;
  float a = lq1[w * 64 + d] * lk1[w * 64 + d];
  float c = lq2[w * 64 + d] * lk2[w * 64 + d];
#pragma unroll
  for (int off = 32; off; off >>= 1) {
    a += __shfl_xor(a, off);
    c += __shfl_xor(c, off);
  }
  if (d == 0) lam[w] = __expf(a) - __expf(c) + 0.8f;
}

// ---------------------------------------------------------------------------
// LayerNorm over rows of 1024.
// ---------------------------------------------------------------------------
template <int WRITE_F32>
__global__ __launch_bounds__(256)
void ln_kernel(const float* __restrict__ x, const float* __restrict__ g,
               const float* __restrict__ bsh, unsigned short* __restrict__ obf,
               float* __restrict__ of32) {
  __shared__ float red[16];
  const int row = blockIdx.x, tid = threadIdx.x;
  const float4 v = *(const float4*)&x[(size_t)row * 1024 + tid * 4];
  float s = v.x + v.y + v.z + v.w;
  float q = v.x * v.x + v.y * v.y + v.z * v.z + v.w * v.w;
#pragma unroll
  for (int off = 32; off; off >>= 1) {
    s += __shfl_xor(s, off);
    q += __shfl_xor(q, off);
  }
  if ((tid & 63) == 0) {
    red[tid >> 6] = s;
    red[8 + (tid >> 6)] = q;
  }
  __syncthreads();
  s = red[0] + red[1] + red[2] + red[3];
  q = red[8] + red[9] + red[10] + red[11];
  const float mean = s * (1.f / 1024.f);
  const float var = q * (1.f / 1024.f) - mean * mean;
  const float rstd = rsqrtf(var + 1e-5f);
  const float4 gg = *(const float4*)&g[tid * 4];
  const float4 bb = *(const float4*)&bsh[tid * 4];
  float y0 = (v.x - mean) * rstd * gg.x + bb.x;
  float y1 = (v.y - mean) * rstd * gg.y + bb.y;
  float y2 = (v.z - mean) * rstd * gg.z + bb.z;
  float y3 = (v.w - mean) * rstd * gg.w + bb.w;
  const size_t base = (size_t)row * 1024 + tid * 4;
  ushort4 o;
  o.x = f2bf(y0); o.y = f2bf(y1); o.z = f2bf(y2); o.w = f2bf(y3);
  *(ushort4*)&obf[base] = o;
  if (WRITE_F32) {
    *(float4*)&of32[base] = make_float4(y0, y1, y2, y3);
  }
}

// ---------------------------------------------------------------------------
// GEMM: C[M][N] = A[M][K](bf16) @ BT[N][K](bf16)^T + bias*bscale.
// 128x128 tile, BK=32, 4 waves, global_load_lds(16B) staging, T1 XCD swizzle.
// ---------------------------------------------------------------------------
template <int EPI>
__global__ __launch_bounds__(256)
void gemm_bf16(const unsigned short* __restrict__ A,
               const unsigned short* __restrict__ BT,
               const float* __restrict__ bias,
               const float* __restrict__ res,
               const unsigned short* __restrict__ gate_u,
               void* __restrict__ Cout, int M, int N, int K, float bscale) {
  __shared__ unsigned short ldsA[128 * 32];
  __shared__ unsigned short ldsB[128 * 32];
  const int tid = threadIdx.x;
  const int wv = tid >> 6, ln = tid & 63, lg = ln >> 4, lc = ln & 15;
  const int wm = wv >> 1, wn = wv & 1;
  const int nwg = gridDim.x * gridDim.y;
  const int linear = blockIdx.y * gridDim.x + blockIdx.x;
  const int swz = (linear & 7) * (nwg >> 3) + (linear >> 3);
  const int m0 = (swz / gridDim.x) * 128, n0 = (swz % gridDim.x) * 128;
  const int rsub = ln >> 2, acol = (ln & 3) * 8;

  f32x4 acc[4][4];
#pragma unroll
  for (int i = 0; i < 4; ++i)
#pragma unroll
    for (int j = 0; j < 4; ++j) acc[i][j] = (f32x4)0.f;

  for (int k0 = 0; k0 < K; k0 += 32) {
#pragma unroll
    for (int j = 0; j < 2; ++j) {
      const int rowblk = wv * 32 + j * 16;
      const unsigned short* ga = A + (size_t)(m0 + rowblk + rsub) * K + (k0 + acol);
      __builtin_amdgcn_global_load_lds((GAS void*)ga, (LAS void*)&ldsA[rowblk * 32], 16, 0, 0);
      const unsigned short* gb = BT + (size_t)(n0 + rowblk + rsub) * K + (k0 + acol);
      __builtin_amdgcn_global_load_lds((GAS void*)gb, (LAS void*)&ldsB[rowblk * 32], 16, 0, 0);
    }
    __syncthreads();
    bf16x8 af[4], bf[4];
#pragma unroll
    for (int m = 0; m < 4; ++m)
      af[m] = *(const bf16x8*)&ldsA[(wm * 64 + m * 16 + lc) * 32 + lg * 8];
#pragma unroll
    for (int n = 0; n < 4; ++n)
      bf[n] = *(const bf16x8*)&ldsB[(wn * 64 + n * 16 + lc) * 32 + lg * 8];
#pragma unroll
    for (int m = 0; m < 4; ++m)
#pragma unroll
      for (int n = 0; n < 4; ++n)
        acc[m][n] = __builtin_amdgcn_mfma_f32_16x16x32_bf16(af[m], bf[n], acc[m][n], 0, 0, 0);
    __syncthreads();
  }

#pragma unroll
  for (int m = 0; m < 4; ++m) {
#pragma unroll
    for (int n = 0; n < 4; ++n) {
      const int c = n0 + wn * 64 + n * 16 + lc;
      const float bc = bias[c] * bscale;
#pragma unroll
      for (int j = 0; j < 4; ++j) {
        const int r = m0 + wm * 64 + m * 16 + lg * 4 + j;
        const size_t idx = (size_t)r * N + c;
        const float v = acc[m][n][j] + bc;
        if (EPI == 0) {
          ((unsigned short*)Cout)[idx] = f2bf(v);
        } else if (EPI == 1) {
          ((float*)Cout)[idx] = res[idx] + v;
        } else {
          const float uu = bf2f(gate_u[idx]);
          const float sw = v / (1.f + __expf(-v));   // silu
          ((unsigned short*)Cout)[idx] = f2bf(uu * sw);
        }
      }
    }
  }
}

// ---------------------------------------------------------------------------
// Differential attention partials: LDS-staged K/V, 2-phase double buffer.
// grid(1024): id = xcd(3b) | qt(5b)<<3 | tcn(1b)<<8 | bhHi(1b)<<9.
// Block: 4 waves x 16 q-rows = 64 q-rows, both pairs, 1024 keys (NT=2),
// KVBLK=32, one barrier per tile. K tile [32][128] XOR(r&7)<<4-swizzled;
// VT tile [128][32] XOR(e&3)<<4-swizzled; swizzle applied via the GLOBAL
// source address (global_load_lds writes linearly).
// ---------------------------------------------------------------------------
__global__ __launch_bounds__(256)
void attn_kernel(const unsigned short* __restrict__ q,
                 const unsigned short* __restrict__ k,
                 const unsigned short* __restrict__ VT,
                 float* __restrict__ Opart,
                 float* __restrict__ lsumPart) {
  constexpr int S = 2048;
  __shared__ unsigned short k_tile[2][32 * 128];   // 16 KB
  __shared__ unsigned short v_tile[2][128 * 32];   // 16 KB
  __shared__ unsigned short p_lds[4][2][512];      // 8 KB (wave, pair)
  const int tid = threadIdx.x, w = tid >> 6, ln = tid & 63, lg = ln >> 4, lc = ln & 15;
  const int id = blockIdx.x;
  const int bh = (id & 7) + 8 * ((id >> 9) & 1);
  const int qt = (id >> 3) & 31;
  const int tcn = (id >> 8) & 1;
  const size_t chan = (size_t)(bh >> 3) * S * 1024 + (bh & 7) * 128;
  const size_t vtbase = (size_t)bh * 128 * S;
  const int qrow = qt * 64 + w * 16 + lc;

  bf16x8 qf[2][2];
#pragma unroll
  for (int p = 0; p < 2; ++p)
#pragma unroll
    for (int ks = 0; ks < 2; ++ks)
      qf[p][ks] = *(const bf16x8*)&q[chan + (size_t)qrow * 1024 + p * 64 + ks * 32 + lg * 8];

  f32x4 O[2][8];
#pragma unroll
  for (int p = 0; p < 2; ++p)
#pragma unroll
    for (int ef = 0; ef < 8; ++ef) O[p][ef] = (f32x4)0.f;
  float lsum[2][4];
#pragma unroll
  for (int p = 0; p < 2; ++p)
#pragma unroll
    for (int j = 0; j < 4; ++j) lsum[p][j] = 0.f;

  const int prd = ((lc * 64 + lg * 16) ^ ((lc & 7) << 4)) >> 1;   // PV A-frag read

  // ---- staging: pre-swizzled global source, linear LDS dest ----
  auto stage = [&](int buf, int t0) {
#pragma unroll
    for (int c = 0; c < 2; ++c) {
      // K: 1KB chunk per call per wave; rows r of 256B
      {
        const int L = (w * 2 + c) * 1024 + ln * 16;
        const int r = L >> 8, inner = L & 255;
        const char* src = (const char*)(k + chan + (size_t)(t0 + r) * 1024) +
                          (inner ^ ((r & 7) << 4));
        __builtin_amdgcn_global_load_lds((GAS void*)src,
            (LAS void*)((char*)&k_tile[buf][0] + (w * 2 + c) * 1024), 16, 0, 0);
      }
      // V: 1KB chunk; rows e of 64B
      {
        const int L = (w * 2 + c) * 1024 + ln * 16;
        const int e = L >> 6, inner = L & 63;
        const char* src = (const char*)(VT + vtbase + (size_t)e * S + t0) +
                          (inner ^ ((e & 3) << 4));
        __builtin_amdgcn_global_load_lds((GAS void*)src,
            (LAS void*)((char*)&v_tile[buf][0] + (w * 2 + c) * 1024), 16, 0, 0);
      }
    }
  };

  auto compute = [&](int buf) {
    const char* kb = (const char*)&k_tile[buf][0];
    const char* vb = (const char*)&v_tile[buf][0];
    // V B-fragments
    bf16x8 vf[8];
#pragma unroll
    for (int ef = 0; ef < 8; ++ef) {
      const int e = ef * 16 + lc;
      vf[ef] = *(const bf16x8*)(vb + e * 64 + ((lg * 16) ^ ((e & 3) << 4)));
    }
#pragma unroll
    for (int p = 0; p < 2; ++p) {
      bf16x8 kf[2][2];
#pragma unroll
      for (int tf = 0; tf < 2; ++tf) {
        const int r = tf * 16 + lc;
#pragma unroll
        for (int ks = 0; ks < 2; ++ks)
          kf[tf][ks] = *(const bf16x8*)(kb + r * 256 +
                          ((p * 128 + ks * 64 + lg * 16) ^ ((r & 7) << 4)));
      }
      f32x4 sfr[2];
      __builtin_amdgcn_s_setprio(1);
#pragma unroll
      for (int tf = 0; tf < 2; ++tf) {
        f32x4 acc = (f32x4)0.f;
#pragma unroll
        for (int ks = 0; ks < 2; ++ks)
          acc = __builtin_amdgcn_mfma_f32_16x16x32_bf16(qf[p][ks], kf[tf][ks], acc, 0, 0, 0);
        sfr[tf] = acc;
      }
      __builtin_amdgcn_s_setprio(0);

#pragma unroll
      for (int tf = 0; tf < 2; ++tf)
#pragma unroll
        for (int j = 0; j < 4; ++j) {
          const float e = __expf(sfr[tf][j]);
          lsum[p][j] += e;
          const int qq = lg * 4 + j;
          const int wi = ((qq * 64 + (tf * 16 + lc) * 2) ^ ((qq & 7) << 4)) >> 1;
          p_lds[w][p][wi] = f2bf(e);
        }

      const bf16x8 pa = *(const bf16x8*)&p_lds[w][p][prd];
      __builtin_amdgcn_s_setprio(1);
#pragma unroll
      for (int ef = 0; ef < 8; ++ef)
        O[p][ef] = __builtin_amdgcn_mfma_f32_16x16x32_bf16(pa, vf[ef], O[p][ef], 0, 0, 0);
      __builtin_amdgcn_s_setprio(0);
    }
  };

  const int tbeg = tcn * (S / 2);
  stage(0, tbeg);
  __syncthreads();
  int cur = 0;
  for (int it = 0; it < 32; ++it) {
    if (it < 31) stage(cur ^ 1, tbeg + (it + 1) * 32);
    compute(cur);
    __syncthreads();   // drains staging vmcnt + protects buffers
    cur ^= 1;
  }

  // write partials
  const size_t rowbase = ((size_t)tcn * 16 + bh) * S;
#pragma unroll
  for (int p = 0; p < 2; ++p)
#pragma unroll
    for (int j = 0; j < 4; ++j) {
      float s = lsum[p][j];
      s += __shfl_xor(s, 1);
      s += __shfl_xor(s, 2);
      s += __shfl_xor(s, 4);
      s += __shfl_xor(s, 8);
      const int row = qt * 64 + w * 16 + lg * 4 + j;
      if (lc == 0)
        lsumPart[(rowbase + row) * 2 + p] = s;
#pragma unroll
      for (int ef = 0; ef < 8; ++ef)
        Opart[(rowbase + row) * 256 + p * 128 + ef * 16 + lc] = O[p][ef][j];
    }
}

// ---------------------------------------------------------------------------
// Combine t-chunk partials: normalize, lambda-diff, headwise GroupNorm, *0.2.
// ---------------------------------------------------------------------------
__global__ __launch_bounds__(256)
void attn_reduce(const float* __restrict__ Opart, const float* __restrict__ lsumPart,
                 const float* __restrict__ lam,
                 const float* __restrict__ gn_w, const float* __restrict__ gn_b,
                 unsigned short* __restrict__ o) {
  constexpr int S = 2048;
  const int gw = (blockIdx.x * 256 + threadIdx.x) >> 6;
  const int ln = threadIdx.x & 63;
  const int bh = gw >> 11, s = gw & 2047;
  const int b = bh >> 3, h = bh & 7;
  const size_t r0 = ((size_t)bh * S + s) * 256;
  const size_t r1 = (((size_t)16 + bh) * S + s) * 256;
  const int e = ln * 2;
  const float2 o1a = *(const float2*)&Opart[r0 + e];
  const float2 o1b = *(const float2*)&Opart[r1 + e];
  const float2 o2a = *(const float2*)&Opart[r0 + 128 + e];
  const float2 o2b = *(const float2*)&Opart[r1 + 128 + e];
  const size_t l0 = ((size_t)bh * S + s) * 2;
  const size_t l1 = (((size_t)16 + bh) * S + s) * 2;
  const float inv1 = 1.f / (lsumPart[l0] + lsumPart[l1]);
  const float inv2 = lam[h] / (lsumPart[l0 + 1] + lsumPart[l1 + 1]);
  float d0 = (o1a.x + o1b.x) * inv1 - (o2a.x + o2b.x) * inv2;
  float d1 = (o1a.y + o1b.y) * inv1 - (o2a.y + o2b.y) * inv2;
  float sum = d0 + d1, sq = d0 * d0 + d1 * d1;
#pragma unroll
  for (int off = 32; off; off >>= 1) {
    sum += __shfl_xor(sum, off);
    sq += __shfl_xor(sq, off);
  }
  const float mean = sum * (1.f / 128.f);
  const float var = sq * (1.f / 128.f) - mean * mean;
  const float rstd = rsqrtf(var + 1e-5f);
  const float v0 = ((d0 - mean) * rstd * gn_w[h * 128 + e] + gn_b[h * 128 + e]) * 0.2f;
  const float v1 = ((d1 - mean) * rstd * gn_w[h * 128 + e + 1] + gn_b[h * 128 + e + 1]) * 0.2f;
  ushort2 ov;
  ov.x = f2bf(v0);
  ov.y = f2bf(v1);
  *(ushort2*)&o[(size_t)b * S * 1024 + (size_t)s * 1024 + h * 128 + e] = ov;
}

// ---------------------------------------------------------------------------
extern "C" void kernel_launch(void* const* d_in, const int* in_sizes, int n_in,
                              void* d_out, int out_size, void* d_ws, size_t ws_size,
                              hipStream_t stream) {
  (void)in_sizes; (void)n_in; (void)out_size; (void)ws_size;
  const float* x    = (const float*)d_in[0];
  const float* ln1g = (const float*)d_in[1];
  const float* ln1b = (const float*)d_in[2];
  const float* ln2g = (const float*)d_in[3];
  const float* ln2b = (const float*)d_in[4];
  const float* Wq   = (const float*)d_in[5];
  const float* bq   = (const float*)d_in[6];
  const float* Wk   = (const float*)d_in[7];
  const float* bk   = (const float*)d_in[8];
  const float* Wv   = (const float*)d_in[9];
  const float* bv   = (const float*)d_in[10];
  const float* Wo   = (const float*)d_in[11];
  const float* bo   = (const float*)d_in[12];
  const float* lq1  = (const float*)d_in[13];
  const float* lk1  = (const float*)d_in[14];
  const float* lq2  = (const float*)d_in[15];
  const float* lk2  = (const float*)d_in[16];
  const float* gnw  = (const float*)d_in[17];
  const float* gnb  = (const float*)d_in[18];
  const float* W1   = (const float*)d_in[19];
  const float* b1   = (const float*)d_in[20];
  const float* Wg   = (const float*)d_in[21];
  const float* bg   = (const float*)d_in[22];
  const float* W2   = (const float*)d_in[23];
  const float* b2   = (const float*)d_in[24];

  const int B = 2, S = 2048, D = 1024, F = 4096;
  const int M = B * S;  // 4096
  const float qscale = 0.125f;

  char* ws = (char*)d_ws;
  size_t off = 0;
  auto alloc = [&](size_t bytes) {
    char* p = ws + off;
    off += (bytes + 255) & ~(size_t)255;
    return p;
  };
  unsigned short* WqT = (unsigned short*)alloc((size_t)D * D * 2);
  unsigned short* WkT = (unsigned short*)alloc((size_t)D * D * 2);
  unsigned short* WvT = (unsigned short*)alloc((size_t)D * D * 2);
  unsigned short* WoT = (unsigned short*)alloc((size_t)D * D * 2);
  unsigned short* W1T = (unsigned short*)alloc((size_t)F * D * 2);
  unsigned short* WgT = (unsigned short*)alloc((size_t)F * F * 2);
  unsigned short* W2T = (unsigned short*)alloc((size_t)D * F * 2);
  float*          lamw= (float*)alloc(256);
  unsigned short* h_bf= (unsigned short*)alloc((size_t)M * D * 2);
  unsigned short* q_bf= (unsigned short*)alloc((size_t)M * D * 2);
  unsigned short* k_bf= (unsigned short*)alloc((size_t)M * D * 2);
  unsigned short* v_bf= (unsigned short*)alloc((size_t)M * D * 2);
  unsigned short* o_bf= (unsigned short*)alloc((size_t)M * D * 2);
  float*          x1  = (float*)alloc((size_t)M * D * 4);
  float*          x2  = (float*)alloc((size_t)M * D * 4);
  unsigned short* x2b = (unsigned short*)alloc((size_t)M * D * 2);
  unsigned short* u_bf= (unsigned short*)alloc((size_t)M * F * 2);
  unsigned short* w_bf= h_bf;   // gated act reuses h span (dead after q/k/v GEMMs)

  // Attention scratch overlays:
  //  Opart (64MB fp32) overlays x1+x2+x2b+u_bf[0:24MB) — all dead during attn.
  //  VT (8MB) in the last 8MB of the u_bf span; lsumP fresh 1MB.
  float* Opart = (float*)x1;
  float* lsumP = (float*)alloc((size_t)2 * 16 * S * 2 * 4);
  unsigned short* VT = u_bf + (size_t)12 * 1024 * 1024;

  // --- weight prep ---
  transpose_cvt<<<dim3(D / 64, D / 64), 256, 0, stream>>>(Wq, WqT, D, D, qscale);
  transpose_cvt<<<dim3(D / 64, D / 64), 256, 0, stream>>>(Wk, WkT, D, D, 1.0f);
  transpose_cvt<<<dim3(D / 64, D / 64), 256, 0, stream>>>(Wv, WvT, D, D, 1.0f);
  transpose_cvt<<<dim3(D / 64, D / 64), 256, 0, stream>>>(Wo, WoT, D, D, 1.0f);
  transpose_cvt<<<dim3(F / 64, D / 64), 256, 0, stream>>>(W1, W1T, D, F, 1.0f);
  transpose_cvt<<<dim3(F / 64, F / 64), 256, 0, stream>>>(Wg, WgT, F, F, 1.0f);
  transpose_cvt<<<dim3(D / 64, F / 64), 256, 0, stream>>>(W2, W2T, F, D, 1.0f);
  lam_kernel<<<1, 512, 0, stream>>>(lq1, lk1, lq2, lk2, lamw);

  // --- attention sublayer ---
  ln_kernel<0><<<M, 256, 0, stream>>>(x, ln1g, ln1b, h_bf, nullptr);
  gemm_bf16<0><<<dim3(D / 128, M / 128), 256, 0, stream>>>(h_bf, WqT, bq, nullptr, nullptr, q_bf, M, D, D, qscale);
  gemm_bf16<0><<<dim3(D / 128, M / 128), 256, 0, stream>>>(h_bf, WkT, bk, nullptr, nullptr, k_bf, M, D, D, 1.0f);
  gemm_bf16<0><<<dim3(D / 128, M / 128), 256, 0, stream>>>(h_bf, WvT, bv, nullptr, nullptr, v_bf, M, D, D, 1.0f);
  v_transpose<<<dim3(S / 64, 2, 16), 256, 0, stream>>>(v_bf, VT);
  attn_kernel<<<dim3(1024), 256, 0, stream>>>(q_bf, k_bf, VT, Opart, lsumP);
  attn_reduce<<<dim3(8192), 256, 0, stream>>>(Opart, lsumP, lamw, gnw, gnb, o_bf);
  gemm_bf16<1><<<dim3(D / 128, M / 128), 256, 0, stream>>>(o_bf, WoT, bo, x, nullptr, x1, M, D, D, 1.0f);

  // --- FFN sublayer ---
  ln_kernel<1><<<M, 256, 0, stream>>>(x1, ln2g, ln2b, x2b, x2);
  gemm_bf16<0><<<dim3(F / 128, M / 128), 256, 0, stream>>>(x2b, W1T, b1, nullptr, nullptr, u_bf, M, F, D, 1.0f);
  gemm_bf16<2><<<dim3(F / 128, M / 128), 256, 0, stream>>>(u_bf, WgT, bg, nullptr, u_bf, w_bf, M, F, F, 1.0f);
  gemm_bf16<1><<<dim3(D / 128, M / 128), 256, 0, stream>>>(w_bf, W2T, b2, x2, nullptr, (float*)d_out, M, D, F, 1.0f);
}

// Round 8
// 525.458 us; speedup vs baseline: 1.6722x; 1.2189x over previous
//
#include <hip/hip_runtime.h>
#include <hip/hip_bf16.h>

// ---------------------------------------------------------------------------
// EncoderBlock (differential attention + swiGLU FFN), MI355X / gfx950
// R7: 256x256 8-phase deep-pipelined GEMM (T2 swizzle + T3/T4 counted vmcnt +
//     T5 setprio) for the two N=4096 GEMMs (W1, Wg). 128KB LDS ring of 8
//     half-tile slots; stage targets proven dead at issue; vmcnt(4) at
//     phases 4/8 only. Attention & 128-tile GEMMs unchanged from R6.
// ---------------------------------------------------------------------------

typedef __attribute__((ext_vector_type(8))) __bf16 bf16x8;
typedef __attribute__((ext_vector_type(4))) float f32x4;

#define GAS __attribute__((address_space(1)))
#define LAS __attribute__((address_space(3)))

__device__ __forceinline__ unsigned short f2bf(float f) {
  unsigned u = __float_as_uint(f);
  u += 0x7fffu + ((u >> 16) & 1u);   // RNE
  return (unsigned short)(u >> 16);
}
__device__ __forceinline__ float bf2f(unsigned short s) {
  return __uint_as_float(((unsigned)s) << 16);
}

// ---------------------------------------------------------------------------
// Transpose + convert: W[K][N] fp32 -> WT[N][K] bf16 * scale.
// ---------------------------------------------------------------------------
__global__ __launch_bounds__(256)
void transpose_cvt(const float* __restrict__ W, unsigned short* __restrict__ WT,
                   int K, int N, float scale) {
  __shared__ float tile[64][65];
  const int n0 = blockIdx.x * 64, k0 = blockIdx.y * 64;
  const int tr = threadIdx.x >> 4, tc = (threadIdx.x & 15) * 4;
#pragma unroll
  for (int i = 0; i < 4; ++i) {
    const float4 v = *(const float4*)&W[(size_t)(k0 + tr + i * 16) * N + n0 + tc];
    tile[tr + i * 16][tc + 0] = v.x;
    tile[tr + i * 16][tc + 1] = v.y;
    tile[tr + i * 16][tc + 2] = v.z;
    tile[tr + i * 16][tc + 3] = v.w;
  }
  __syncthreads();
#pragma unroll
  for (int i = 0; i < 4; ++i) {
    const int n = tr + i * 16;
    ushort4 o;
    o.x = f2bf(tile[tc + 0][n] * scale);
    o.y = f2bf(tile[tc + 1][n] * scale);
    o.z = f2bf(tile[tc + 2][n] * scale);
    o.w = f2bf(tile[tc + 3][n] * scale);
    *(ushort4*)&WT[(size_t)(n0 + n) * K + k0 + tc] = o;
  }
}

// ---------------------------------------------------------------------------
// V transpose (bf16): v[b,s,h*128+e] -> VT[(b*8+h)*128+e][S].
// ---------------------------------------------------------------------------
__global__ __launch_bounds__(256)
void v_transpose(const unsigned short* __restrict__ v, unsigned short* __restrict__ VT) {
  __shared__ unsigned short tile[64][65];
  const int s0 = blockIdx.x * 64, e0 = blockIdx.y * 64, bh = blockIdx.z;
  const int b = bh >> 3, h = bh & 7;
  const int tr = threadIdx.x >> 4, tc = (threadIdx.x & 15) * 4;
  const size_t inbase = (size_t)b * 2048 * 1024 + h * 128;
#pragma unroll
  for (int i = 0; i < 4; ++i) {
    const int r = tr + i * 16;
    const ushort4 val = *(const ushort4*)&v[inbase + (size_t)(s0 + r) * 1024 + e0 + tc];
    tile[r][tc + 0] = val.x;
    tile[r][tc + 1] = val.y;
    tile[r][tc + 2] = val.z;
    tile[r][tc + 3] = val.w;
  }
  __syncthreads();
#pragma unroll
  for (int i = 0; i < 4; ++i) {
    const int n = tr + i * 16;
    ushort4 oo;
    oo.x = tile[tc + 0][n];
    oo.y = tile[tc + 1][n];
    oo.z = tile[tc + 2][n];
    oo.w = tile[tc + 3][n];
    *(ushort4*)&VT[(size_t)(bh * 128 + e0 + n) * 2048 + s0 + tc] = oo;
  }
}

// ---------------------------------------------------------------------------
// lambda[h]
// ---------------------------------------------------------------------------
__global__ void lam_kernel(const float* __restrict__ lq1, const float* __restrict__ lk1,
                           const float* __restrict__ lq2, const float* __restrict__ lk2,
                           float* __restrict__ lam) {
  const int w = threadIdx.x >> 6, d = threadIdx.x & 63;
  float a = lq1[w * 64 + d] * lk1[w * 64 + d];
  float c = lq2[w * 64 + d] * lk2[w * 64 + d];
#pragma unroll
  for (int off = 32; off; off >>= 1) {
    a += __shfl_xor(a, off);
    c += __shfl_xor(c, off);
  }
  if (d == 0) lam[w] = __expf(a) - __expf(c) + 0.8f;
}

// ---------------------------------------------------------------------------
// LayerNorm over rows of 1024.
// ---------------------------------------------------------------------------
template <int WRITE_F32>
__global__ __launch_bounds__(256)
void ln_kernel(const float* __restrict__ x, const float* __restrict__ g,
               const float* __restrict__ bsh, unsigned short* __restrict__ obf,
               float* __restrict__ of32) {
  __shared__ float red[16];
  const int row = blockIdx.x, tid = threadIdx.x;
  const float4 v = *(const float4*)&x[(size_t)row * 1024 + tid * 4];
  float s = v.x + v.y + v.z + v.w;
  float q = v.x * v.x + v.y * v.y + v.z * v.z + v.w * v.w;
#pragma unroll
  for (int off = 32; off; off >>= 1) {
    s += __shfl_xor(s, off);
    q += __shfl_xor(q, off);
  }
  if ((tid & 63) == 0) {
    red[tid >> 6] = s;
    red[8 + (tid >> 6)] = q;
  }
  __syncthreads();
  s = red[0] + red[1] + red[2] + red[3];
  q = red[8] + red[9] + red[10] + red[11];
  const float mean = s * (1.f / 1024.f);
  const float var = q * (1.f / 1024.f) - mean * mean;
  const float rstd = rsqrtf(var + 1e-5f);
  const float4 gg = *(const float4*)&g[tid * 4];
  const float4 bb = *(const float4*)&bsh[tid * 4];
  float y0 = (v.x - mean) * rstd * gg.x + bb.x;
  float y1 = (v.y - mean) * rstd * gg.y + bb.y;
  float y2 = (v.z - mean) * rstd * gg.z + bb.z;
  float y3 = (v.w - mean) * rstd * gg.w + bb.w;
  const size_t base = (size_t)row * 1024 + tid * 4;
  ushort4 o;
  o.x = f2bf(y0); o.y = f2bf(y1); o.z = f2bf(y2); o.w = f2bf(y3);
  *(ushort4*)&obf[base] = o;
  if (WRITE_F32) {
    *(float4*)&of32[base] = make_float4(y0, y1, y2, y3);
  }
}

// ---------------------------------------------------------------------------
// GEMM 128x128 (m97 structure): used for the N=1024 GEMMs.
// ---------------------------------------------------------------------------
template <int EPI>
__global__ __launch_bounds__(256)
void gemm_bf16(const unsigned short* __restrict__ A,
               const unsigned short* __restrict__ BT,
               const float* __restrict__ bias,
               const float* __restrict__ res,
               const unsigned short* __restrict__ gate_u,
               void* __restrict__ Cout, int M, int N, int K, float bscale) {
  __shared__ unsigned short ldsA[128 * 32];
  __shared__ unsigned short ldsB[128 * 32];
  const int tid = threadIdx.x;
  const int wv = tid >> 6, ln = tid & 63, lg = ln >> 4, lc = ln & 15;
  const int wm = wv >> 1, wn = wv & 1;
  const int nwg = gridDim.x * gridDim.y;
  const int linear = blockIdx.y * gridDim.x + blockIdx.x;
  const int swz = (linear & 7) * (nwg >> 3) + (linear >> 3);
  const int m0 = (swz / gridDim.x) * 128, n0 = (swz % gridDim.x) * 128;
  const int rsub = ln >> 2, acol = (ln & 3) * 8;

  f32x4 acc[4][4];
#pragma unroll
  for (int i = 0; i < 4; ++i)
#pragma unroll
    for (int j = 0; j < 4; ++j) acc[i][j] = (f32x4)0.f;

  for (int k0 = 0; k0 < K; k0 += 32) {
#pragma unroll
    for (int j = 0; j < 2; ++j) {
      const int rowblk = wv * 32 + j * 16;
      const unsigned short* ga = A + (size_t)(m0 + rowblk + rsub) * K + (k0 + acol);
      __builtin_amdgcn_global_load_lds((GAS void*)ga, (LAS void*)&ldsA[rowblk * 32], 16, 0, 0);
      const unsigned short* gb = BT + (size_t)(n0 + rowblk + rsub) * K + (k0 + acol);
      __builtin_amdgcn_global_load_lds((GAS void*)gb, (LAS void*)&ldsB[rowblk * 32], 16, 0, 0);
    }
    __syncthreads();
    bf16x8 af[4], bf[4];
#pragma unroll
    for (int m = 0; m < 4; ++m)
      af[m] = *(const bf16x8*)&ldsA[(wm * 64 + m * 16 + lc) * 32 + lg * 8];
#pragma unroll
    for (int n = 0; n < 4; ++n)
      bf[n] = *(const bf16x8*)&ldsB[(wn * 64 + n * 16 + lc) * 32 + lg * 8];
#pragma unroll
    for (int m = 0; m < 4; ++m)
#pragma unroll
      for (int n = 0; n < 4; ++n)
        acc[m][n] = __builtin_amdgcn_mfma_f32_16x16x32_bf16(af[m], bf[n], acc[m][n], 0, 0, 0);
    __syncthreads();
  }

#pragma unroll
  for (int m = 0; m < 4; ++m) {
#pragma unroll
    for (int n = 0; n < 4; ++n) {
      const int c = n0 + wn * 64 + n * 16 + lc;
      const float bc = bias[c] * bscale;
#pragma unroll
      for (int j = 0; j < 4; ++j) {
        const int r = m0 + wm * 64 + m * 16 + lg * 4 + j;
        const size_t idx = (size_t)r * N + c;
        const float v = acc[m][n][j] + bc;
        if (EPI == 0) {
          ((unsigned short*)Cout)[idx] = f2bf(v);
        } else if (EPI == 1) {
          ((float*)Cout)[idx] = res[idx] + v;
        } else {
          const float uu = bf2f(gate_u[idx]);
          const float sw = v / (1.f + __expf(-v));   // silu
          ((unsigned short*)Cout)[idx] = f2bf(uu * sw);
        }
      }
    }
  }
}

// ---------------------------------------------------------------------------
// GEMM 256x256, 8-wave (2Mx4N), BK=64, 8-phase deep pipeline.
// LDS ring: 8 half-tile slots x 16KB (A-even h0/h1, A-odd h0/h1, B-even x2,
// B-odd x2). Per iteration (2 K-tiles J,J+1):
//   P1..P4 compute kt J   (quadrants q=0..3), staging A(J+1)h0, A(J+1)h1,
//                                                B(J+2)h0, B(J+2)h1
//   P5..P8 compute kt J+1, staging A(J+2)h0, A(J+2)h1, B(J+3)h0, B(J+3)h1
// vmcnt(4) at P4/P8 (2 half-tiles = 4 loads in flight). Raw s_barrier (no
// compiler vmcnt(0) drain). XOR swizzle byte^=(r&7)<<4, pre-swizzled source.
// EPI 0: bf16 out = acc + bias.  EPI 2: bf16 out = gate_u * silu(acc + bias).
// ---------------------------------------------------------------------------
template <int EPI>
__global__ __launch_bounds__(512)
void gemm256(const unsigned short* __restrict__ A,
             const unsigned short* __restrict__ BT,
             const float* __restrict__ bias,
             const unsigned short* __restrict__ gate_u,
             unsigned short* __restrict__ Cout, int M, int N, int K) {
  __shared__ unsigned short lds[65536];   // 128 KB = 8 x 16KB slots
  const int tid = threadIdx.x;
  const int w = tid >> 6, ln = tid & 63, lg = ln >> 4, lc = ln & 15;
  const int wm = w >> 2, wn = w & 3;
  const int nwg = gridDim.x * gridDim.y;
  const int linear = blockIdx.y * gridDim.x + blockIdx.x;
  const int swzb = (linear & 7) * (nwg >> 3) + (linear >> 3);
  const int m0 = (swzb / gridDim.x) * 256, n0 = (swzb % gridDim.x) * 256;

  f32x4 acc[8][4];
#pragma unroll
  for (int i = 0; i < 8; ++i)
#pragma unroll
    for (int j = 0; j < 4; ++j) acc[i][j] = (f32x4)0.f;

  // stage one half-tile (tensor 0=A,1=B; ktile j; half hh): 2 loads/thread
  auto stage_half = [&](int tensor, int j, int hh) {
    const unsigned short* base = tensor ? BT : A;
    const int row0 = (tensor ? n0 : m0) + hh * 128;
    const int slot = tensor * 4 + (j & 1) * 2 + hh;
#pragma unroll
    for (int c = 0; c < 2; ++c) {
      const int chunk = w * 2 + c;
      const int L = chunk * 1024 + ln * 16;
      const int r = L >> 7, inner = L & 127;
      const char* src = (const char*)(base + (size_t)(row0 + r) * K + j * 64) +
                        (inner ^ ((r & 7) << 4));
      __builtin_amdgcn_global_load_lds((GAS void*)src,
          (LAS void*)((char*)lds + slot * 16384 + chunk * 1024), 16, 0, 0);
    }
  };
  auto read_a = [&](int j, int mf, int ks) -> bf16x8 {
    const int r = mf * 16 + lc;
    const int slot = (j & 1) * 2 + wm;
    const int cb = ks * 64 + lg * 16;
    return *(const bf16x8*)((const char*)lds + slot * 16384 + r * 128 +
                            (cb ^ ((r & 7) << 4)));
  };
  auto read_b = [&](int j, int nf, int ks) -> bf16x8 {
    const int R = wn * 64 + nf * 16 + lc;
    const int slot = 4 + (j & 1) * 2 + (R >> 7);
    const int r = R & 127;
    const int cb = ks * 64 + lg * 16;
    return *(const bf16x8*)((const char*)lds + slot * 16384 + r * 128 +
                            (cb ^ ((r & 7) << 4)));
  };

  const int nkt = K / 64;

  // prologue: A(0), B(0), B(1); full drain once.
  stage_half(0, 0, 0); stage_half(0, 0, 1);
  stage_half(1, 0, 0); stage_half(1, 0, 1);
  stage_half(1, 1, 0); stage_half(1, 1, 1);
  asm volatile("s_waitcnt vmcnt(0)" ::: "memory");
  __builtin_amdgcn_s_barrier();

  bf16x8 bfr[4][2];
  for (int it = 0; it < nkt / 2; ++it) {
    const int J = it * 2;
    // ---- phases 1-4: compute kt J ----
#pragma unroll
    for (int q = 0; q < 4; ++q) {
      if (q == 0) {
#pragma unroll
        for (int nf = 0; nf < 4; ++nf)
#pragma unroll
          for (int ks = 0; ks < 2; ++ks) bfr[nf][ks] = read_b(J, nf, ks);
      }
      bf16x8 afr[2][2];
#pragma unroll
      for (int mm = 0; mm < 2; ++mm)
#pragma unroll
        for (int ks = 0; ks < 2; ++ks) afr[mm][ks] = read_a(J, q * 2 + mm, ks);
      if (q == 0) stage_half(0, J + 1, 0);
      if (q == 1) stage_half(0, J + 1, 1);
      if (q == 2 && J + 2 < nkt) stage_half(1, J + 2, 0);
      if (q == 3) {
        if (J + 2 < nkt) stage_half(1, J + 2, 1);
        asm volatile("s_waitcnt vmcnt(4)" ::: "memory");
      }
      __builtin_amdgcn_s_barrier();
      __builtin_amdgcn_s_setprio(1);
#pragma unroll
      for (int mm = 0; mm < 2; ++mm)
#pragma unroll
        for (int nf = 0; nf < 4; ++nf)
#pragma unroll
          for (int ks = 0; ks < 2; ++ks)
            acc[q * 2 + mm][nf] = __builtin_amdgcn_mfma_f32_16x16x32_bf16(
                afr[mm][ks], bfr[nf][ks], acc[q * 2 + mm][nf], 0, 0, 0);
      __builtin_amdgcn_s_setprio(0);
      __builtin_amdgcn_s_barrier();
    }
    // ---- phases 5-8: compute kt J+1 ----
#pragma unroll
    for (int q = 0; q < 4; ++q) {
      if (q == 0) {
#pragma unroll
        for (int nf = 0; nf < 4; ++nf)
#pragma unroll
          for (int ks = 0; ks < 2; ++ks) bfr[nf][ks] = read_b(J + 1, nf, ks);
      }
      bf16x8 afr[2][2];
#pragma unroll
      for (int mm = 0; mm < 2; ++mm)
#pragma unroll
        for (int ks = 0; ks < 2; ++ks) afr[mm][ks] = read_a(J + 1, q * 2 + mm, ks);
      if (q == 0 && J + 2 < nkt) stage_half(0, J + 2, 0);
      if (q == 1 && J + 2 < nkt) stage_half(0, J + 2, 1);
      if (q == 2 && J + 3 < nkt) stage_half(1, J + 3, 0);
      if (q == 3) {
        if (J + 3 < nkt) stage_half(1, J + 3, 1);
        asm volatile("s_waitcnt vmcnt(4)" ::: "memory");
      }
      __builtin_amdgcn_s_barrier();
      __builtin_amdgcn_s_setprio(1);
#pragma unroll
      for (int mm = 0; mm < 2; ++mm)
#pragma unroll
        for (int nf = 0; nf < 4; ++nf)
#pragma unroll
          for (int ks = 0; ks < 2; ++ks)
            acc[q * 2 + mm][nf] = __builtin_amdgcn_mfma_f32_16x16x32_bf16(
                afr[mm][ks], bfr[nf][ks], acc[q * 2 + mm][nf], 0, 0, 0);
      __builtin_amdgcn_s_setprio(0);
      __builtin_amdgcn_s_barrier();
    }
  }

  // epilogue
#pragma unroll
  for (int mf = 0; mf < 8; ++mf) {
#pragma unroll
    for (int nf = 0; nf < 4; ++nf) {
      const int c = n0 + wn * 64 + nf * 16 + lc;
      const float bc = bias[c];
#pragma unroll
      for (int jj = 0; jj < 4; ++jj) {
        const int r = m0 + wm * 128 + mf * 16 + lg * 4 + jj;
        const size_t idx = (size_t)r * N + c;
        const float v = acc[mf][nf][jj] + bc;
        if (EPI == 0) {
          Cout[idx] = f2bf(v);
        } else {
          const float uu = bf2f(gate_u[idx]);
          const float sw = v / (1.f + __expf(-v));   // silu
          Cout[idx] = f2bf(uu * sw);
        }
      }
    }
  }
}

// ---------------------------------------------------------------------------
// Differential attention partials: LDS-staged K/V, 2-phase double buffer.
// (unchanged from R6)
// ---------------------------------------------------------------------------
__global__ __launch_bounds__(256)
void attn_kernel(const unsigned short* __restrict__ q,
                 const unsigned short* __restrict__ k,
                 const unsigned short* __restrict__ VT,
                 float* __restrict__ Opart,
                 float* __restrict__ lsumPart) {
  constexpr int S = 2048;
  __shared__ unsigned short k_tile[2][32 * 128];
  __shared__ unsigned short v_tile[2][128 * 32];
  __shared__ unsigned short p_lds[4][2][512];
  const int tid = threadIdx.x, w = tid >> 6, ln = tid & 63, lg = ln >> 4, lc = ln & 15;
  const int id = blockIdx.x;
  const int bh = (id & 7) + 8 * ((id >> 9) & 1);
  const int qt = (id >> 3) & 31;
  const int tcn = (id >> 8) & 1;
  const size_t chan = (size_t)(bh >> 3) * S * 1024 + (bh & 7) * 128;
  const size_t vtbase = (size_t)bh * 128 * S;
  const int qrow = qt * 64 + w * 16 + lc;

  bf16x8 qf[2][2];
#pragma unroll
  for (int p = 0; p < 2; ++p)
#pragma unroll
    for (int ks = 0; ks < 2; ++ks)
      qf[p][ks] = *(const bf16x8*)&q[chan + (size_t)qrow * 1024 + p * 64 + ks * 32 + lg * 8];

  f32x4 O[2][8];
#pragma unroll
  for (int p = 0; p < 2; ++p)
#pragma unroll
    for (int ef = 0; ef < 8; ++ef) O[p][ef] = (f32x4)0.f;
  float lsum[2][4];
#pragma unroll
  for (int p = 0; p < 2; ++p)
#pragma unroll
    for (int j = 0; j < 4; ++j) lsum[p][j] = 0.f;

  const int prd = ((lc * 64 + lg * 16) ^ ((lc & 7) << 4)) >> 1;

  auto stage = [&](int buf, int t0) {
#pragma unroll
    for (int c = 0; c < 2; ++c) {
      {
        const int L = (w * 2 + c) * 1024 + ln * 16;
        const int r = L >> 8, inner = L & 255;
        const char* src = (const char*)(k + chan + (size_t)(t0 + r) * 1024) +
                          (inner ^ ((r & 7) << 4));
        __builtin_amdgcn_global_load_lds((GAS void*)src,
            (LAS void*)((char*)&k_tile[buf][0] + (w * 2 + c) * 1024), 16, 0, 0);
      }
      {
        const int L = (w * 2 + c) * 1024 + ln * 16;
        const int e = L >> 6, inner = L & 63;
        const char* src = (const char*)(VT + vtbase + (size_t)e * S + t0) +
                          (inner ^ ((e & 3) << 4));
        __builtin_amdgcn_global_load_lds((GAS void*)src,
            (LAS void*)((char*)&v_tile[buf][0] + (w * 2 + c) * 1024), 16, 0, 0);
      }
    }
  };

  auto compute = [&](int buf) {
    const char* kb = (const char*)&k_tile[buf][0];
    const char* vb = (const char*)&v_tile[buf][0];
    bf16x8 vf[8];
#pragma unroll
    for (int ef = 0; ef < 8; ++ef) {
      const int e = ef * 16 + lc;
      vf[ef] = *(const bf16x8*)(vb + e * 64 + ((lg * 16) ^ ((e & 3) << 4)));
    }
#pragma unroll
    for (int p = 0; p < 2; ++p) {
      bf16x8 kf[2][2];
#pragma unroll
      for (int tf = 0; tf < 2; ++tf) {
        const int r = tf * 16 + lc;
#pragma unroll
        for (int ks = 0; ks < 2; ++ks)
          kf[tf][ks] = *(const bf16x8*)(kb + r * 256 +
                          ((p * 128 + ks * 64 + lg * 16) ^ ((r & 7) << 4)));
      }
      f32x4 sfr[2];
      __builtin_amdgcn_s_setprio(1);
#pragma unroll
      for (int tf = 0; tf < 2; ++tf) {
        f32x4 acc = (f32x4)0.f;
#pragma unroll
        for (int ks = 0; ks < 2; ++ks)
          acc = __builtin_amdgcn_mfma_f32_16x16x32_bf16(qf[p][ks], kf[tf][ks], acc, 0, 0, 0);
        sfr[tf] = acc;
      }
      __builtin_amdgcn_s_setprio(0);

#pragma unroll
      for (int tf = 0; tf < 2; ++tf)
#pragma unroll
        for (int j = 0; j < 4; ++j) {
          const float e = __expf(sfr[tf][j]);
          lsum[p][j] += e;
          const int qq = lg * 4 + j;
          const int wi = ((qq * 64 + (tf * 16 + lc) * 2) ^ ((qq & 7) << 4)) >> 1;
          p_lds[w][p][wi] = f2bf(e);
        }

      const bf16x8 pa = *(const bf16x8*)&p_lds[w][p][prd];
      __builtin_amdgcn_s_setprio(1);
#pragma unroll
      for (int ef = 0; ef < 8; ++ef)
        O[p][ef] = __builtin_amdgcn_mfma_f32_16x16x32_bf16(pa, vf[ef], O[p][ef], 0, 0, 0);
      __builtin_amdgcn_s_setprio(0);
    }
  };

  const int tbeg = tcn * (S / 2);
  stage(0, tbeg);
  __syncthreads();
  int cur = 0;
  for (int it = 0; it < 32; ++it) {
    if (it < 31) stage(cur ^ 1, tbeg + (it + 1) * 32);
    compute(cur);
    __syncthreads();
    cur ^= 1;
  }

  const size_t rowbase = ((size_t)tcn * 16 + bh) * S;
#pragma unroll
  for (int p = 0; p < 2; ++p)
#pragma unroll
    for (int j = 0; j < 4; ++j) {
      float s = lsum[p][j];
      s += __shfl_xor(s, 1);
      s += __shfl_xor(s, 2);
      s += __shfl_xor(s, 4);
      s += __shfl_xor(s, 8);
      const int row = qt * 64 + w * 16 + lg * 4 + j;
      if (lc == 0)
        lsumPart[(rowbase + row) * 2 + p] = s;
#pragma unroll
      for (int ef = 0; ef < 8; ++ef)
        Opart[(rowbase + row) * 256 + p * 128 + ef * 16 + lc] = O[p][ef][j];
    }
}

// ---------------------------------------------------------------------------
// Combine t-chunk partials: normalize, lambda-diff, headwise GroupNorm, *0.2.
// ---------------------------------------------------------------------------
__global__ __launch_bounds__(256)
void attn_reduce(const float* __restrict__ Opart, const float* __restrict__ lsumPart,
                 const float* __restrict__ lam,
                 const float* __restrict__ gn_w, const float* __restrict__ gn_b,
                 unsigned short* __restrict__ o) {
  constexpr int S = 2048;
  const int gw = (blockIdx.x * 256 + threadIdx.x) >> 6;
  const int ln = threadIdx.x & 63;
  const int bh = gw >> 11, s = gw & 2047;
  const int b = bh >> 3, h = bh & 7;
  const size_t r0 = ((size_t)bh * S + s) * 256;
  const size_t r1 = (((size_t)16 + bh) * S + s) * 256;
  const int e = ln * 2;
  const float2 o1a = *(const float2*)&Opart[r0 + e];
  const float2 o1b = *(const float2*)&Opart[r1 + e];
  const float2 o2a = *(const float2*)&Opart[r0 + 128 + e];
  const float2 o2b = *(const float2*)&Opart[r1 + 128 + e];
  const size_t l0 = ((size_t)bh * S + s) * 2;
  const size_t l1 = (((size_t)16 + bh) * S + s) * 2;
  const float inv1 = 1.f / (lsumPart[l0] + lsumPart[l1]);
  const float inv2 = lam[h] / (lsumPart[l0 + 1] + lsumPart[l1 + 1]);
  float d0 = (o1a.x + o1b.x) * inv1 - (o2a.x + o2b.x) * inv2;
  float d1 = (o1a.y + o1b.y) * inv1 - (o2a.y + o2b.y) * inv2;
  float sum = d0 + d1, sq = d0 * d0 + d1 * d1;
#pragma unroll
  for (int off = 32; off; off >>= 1) {
    sum += __shfl_xor(sum, off);
    sq += __shfl_xor(sq, off);
  }
  const float mean = sum * (1.f / 128.f);
  const float var = sq * (1.f / 128.f) - mean * mean;
  const float rstd = rsqrtf(var + 1e-5f);
  const float v0 = ((d0 - mean) * rstd * gn_w[h * 128 + e] + gn_b[h * 128 + e]) * 0.2f;
  const float v1 = ((d1 - mean) * rstd * gn_w[h * 128 + e + 1] + gn_b[h * 128 + e + 1]) * 0.2f;
  ushort2 ov;
  ov.x = f2bf(v0);
  ov.y = f2bf(v1);
  *(ushort2*)&o[(size_t)b * S * 1024 + (size_t)s * 1024 + h * 128 + e] = ov;
}

// ---------------------------------------------------------------------------
extern "C" void kernel_launch(void* const* d_in, const int* in_sizes, int n_in,
                              void* d_out, int out_size, void* d_ws, size_t ws_size,
                              hipStream_t stream) {
  (void)in_sizes; (void)n_in; (void)out_size; (void)ws_size;
  const float* x    = (const float*)d_in[0];
  const float* ln1g = (const float*)d_in[1];
  const float* ln1b = (const float*)d_in[2];
  const float* ln2g = (const float*)d_in[3];
  const float* ln2b = (const float*)d_in[4];
  const float* Wq   = (const float*)d_in[5];
  const float* bq   = (const float*)d_in[6];
  const float* Wk   = (const float*)d_in[7];
  const float* bk   = (const float*)d_in[8];
  const float* Wv   = (const float*)d_in[9];
  const float* bv   = (const float*)d_in[10];
  const float* Wo   = (const float*)d_in[11];
  const float* bo   = (const float*)d_in[12];
  const float* lq1  = (const float*)d_in[13];
  const float* lk1  = (const float*)d_in[14];
  const float* lq2  = (const float*)d_in[15];
  const float* lk2  = (const float*)d_in[16];
  const float* gnw  = (const float*)d_in[17];
  const float* gnb  = (const float*)d_in[18];
  const float* W1   = (const float*)d_in[19];
  const float* b1   = (const float*)d_in[20];
  const float* Wg   = (const float*)d_in[21];
  const float* bg   = (const float*)d_in[22];
  const float* W2   = (const float*)d_in[23];
  const float* b2   = (const float*)d_in[24];

  const int B = 2, S = 2048, D = 1024, F = 4096;
  const int M = B * S;  // 4096
  const float qscale = 0.125f;

  char* ws = (char*)d_ws;
  size_t off = 0;
  auto alloc = [&](size_t bytes) {
    char* p = ws + off;
    off += (bytes + 255) & ~(size_t)255;
    return p;
  };
  unsigned short* WqT = (unsigned short*)alloc((size_t)D * D * 2);
  unsigned short* WkT = (unsigned short*)alloc((size_t)D * D * 2);
  unsigned short* WvT = (unsigned short*)alloc((size_t)D * D * 2);
  unsigned short* WoT = (unsigned short*)alloc((size_t)D * D * 2);
  unsigned short* W1T = (unsigned short*)alloc((size_t)F * D * 2);
  unsigned short* WgT = (unsigned short*)alloc((size_t)F * F * 2);
  unsigned short* W2T = (unsigned short*)alloc((size_t)D * F * 2);
  float*          lamw= (float*)alloc(256);
  unsigned short* h_bf= (unsigned short*)alloc((size_t)M * D * 2);
  unsigned short* q_bf= (unsigned short*)alloc((size_t)M * D * 2);
  unsigned short* k_bf= (unsigned short*)alloc((size_t)M * D * 2);
  unsigned short* v_bf= (unsigned short*)alloc((size_t)M * D * 2);
  unsigned short* o_bf= (unsigned short*)alloc((size_t)M * D * 2);
  float*          x1  = (float*)alloc((size_t)M * D * 4);
  float*          x2  = (float*)alloc((size_t)M * D * 4);
  unsigned short* x2b = (unsigned short*)alloc((size_t)M * D * 2);
  unsigned short* u_bf= (unsigned short*)alloc((size_t)M * F * 2);
  unsigned short* w_bf= h_bf;   // gated act reuses h span (dead after q/k/v GEMMs)

  float* Opart = (float*)x1;
  float* lsumP = (float*)alloc((size_t)2 * 16 * S * 2 * 4);
  unsigned short* VT = u_bf + (size_t)12 * 1024 * 1024;

  // --- weight prep ---
  transpose_cvt<<<dim3(D / 64, D / 64), 256, 0, stream>>>(Wq, WqT, D, D, qscale);
  transpose_cvt<<<dim3(D / 64, D / 64), 256, 0, stream>>>(Wk, WkT, D, D, 1.0f);
  transpose_cvt<<<dim3(D / 64, D / 64), 256, 0, stream>>>(Wv, WvT, D, D, 1.0f);
  transpose_cvt<<<dim3(D / 64, D / 64), 256, 0, stream>>>(Wo, WoT, D, D, 1.0f);
  transpose_cvt<<<dim3(F / 64, D / 64), 256, 0, stream>>>(W1, W1T, D, F, 1.0f);
  transpose_cvt<<<dim3(F / 64, F / 64), 256, 0, stream>>>(Wg, WgT, F, F, 1.0f);
  transpose_cvt<<<dim3(D / 64, F / 64), 256, 0, stream>>>(W2, W2T, F, D, 1.0f);
  lam_kernel<<<1, 512, 0, stream>>>(lq1, lk1, lq2, lk2, lamw);

  // --- attention sublayer ---
  ln_kernel<0><<<M, 256, 0, stream>>>(x, ln1g, ln1b, h_bf, nullptr);
  gemm_bf16<0><<<dim3(D / 128, M / 128), 256, 0, stream>>>(h_bf, WqT, bq, nullptr, nullptr, q_bf, M, D, D, qscale);
  gemm_bf16<0><<<dim3(D / 128, M / 128), 256, 0, stream>>>(h_bf, WkT, bk, nullptr, nullptr, k_bf, M, D, D, 1.0f);
  gemm_bf16<0><<<dim3(D / 128, M / 128), 256, 0, stream>>>(h_bf, WvT, bv, nullptr, nullptr, v_bf, M, D, D, 1.0f);
  v_transpose<<<dim3(S / 64, 2, 16), 256, 0, stream>>>(v_bf, VT);
  attn_kernel<<<dim3(1024), 256, 0, stream>>>(q_bf, k_bf, VT, Opart, lsumP);
  attn_reduce<<<dim3(8192), 256, 0, stream>>>(Opart, lsumP, lamw, gnw, gnb, o_bf);
  gemm_bf16<1><<<dim3(D / 128, M / 128), 256, 0, stream>>>(o_bf, WoT, bo, x, nullptr, x1, M, D, D, 1.0f);

  // --- FFN sublayer ---
  ln_kernel<1><<<M, 256, 0, stream>>>(x1, ln2g, ln2b, x2b, x2);
  gemm256<0><<<dim3(F / 256, M / 256), 512, 0, stream>>>(x2b, W1T, b1, nullptr, u_bf, M, F, D);
  gemm256<2><<<dim3(F / 256, M / 256), 512, 0, stream>>>(u_bf, WgT, bg, u_bf, w_bf, M, F, F);
  gemm_bf16<1><<<dim3(D / 128, M / 128), 256, 0, stream>>>(w_bf, W2T, b2, x2, nullptr, (float*)d_out, M, D, F, 1.0f);
}

// Round 9
// 486.273 us; speedup vs baseline: 1.8070x; 1.0806x over previous
//
#include <hip/hip_runtime.h>
#include <hip/hip_bf16.h>

// ---------------------------------------------------------------------------
// EncoderBlock (differential attention + swiGLU FFN), MI355X / gfx950
// R8: fused q/k/v projection as ONE gemm256 (N=3072) with concatenated
//     pre-scaled weights; attention reads qkv with stride 3072.
//     + lgkmcnt(8) hint in gemm256's 12-ds_read phases (m201 template).
// ---------------------------------------------------------------------------

typedef __attribute__((ext_vector_type(8))) __bf16 bf16x8;
typedef __attribute__((ext_vector_type(4))) float f32x4;

#define GAS __attribute__((address_space(1)))
#define LAS __attribute__((address_space(3)))

__device__ __forceinline__ unsigned short f2bf(float f) {
  unsigned u = __float_as_uint(f);
  u += 0x7fffu + ((u >> 16) & 1u);   // RNE
  return (unsigned short)(u >> 16);
}
__device__ __forceinline__ float bf2f(unsigned short s) {
  return __uint_as_float(((unsigned)s) << 16);
}

// ---------------------------------------------------------------------------
// Transpose + convert: W[K][N] fp32 -> WT[N][K] bf16 * scale.
// ---------------------------------------------------------------------------
__global__ __launch_bounds__(256)
void transpose_cvt(const float* __restrict__ W, unsigned short* __restrict__ WT,
                   int K, int N, float scale) {
  __shared__ float tile[64][65];
  const int n0 = blockIdx.x * 64, k0 = blockIdx.y * 64;
  const int tr = threadIdx.x >> 4, tc = (threadIdx.x & 15) * 4;
#pragma unroll
  for (int i = 0; i < 4; ++i) {
    const float4 v = *(const float4*)&W[(size_t)(k0 + tr + i * 16) * N + n0 + tc];
    tile[tr + i * 16][tc + 0] = v.x;
    tile[tr + i * 16][tc + 1] = v.y;
    tile[tr + i * 16][tc + 2] = v.z;
    tile[tr + i * 16][tc + 3] = v.w;
  }
  __syncthreads();
#pragma unroll
  for (int i = 0; i < 4; ++i) {
    const int n = tr + i * 16;
    ushort4 o;
    o.x = f2bf(tile[tc + 0][n] * scale);
    o.y = f2bf(tile[tc + 1][n] * scale);
    o.z = f2bf(tile[tc + 2][n] * scale);
    o.w = f2bf(tile[tc + 3][n] * scale);
    *(ushort4*)&WT[(size_t)(n0 + n) * K + k0 + tc] = o;
  }
}

// ---------------------------------------------------------------------------
// Combined qkv bias: [0,1024)=bq*s, [1024,2048)=bk, [2048,3072)=bv.
// ---------------------------------------------------------------------------
__global__ void prep_bias(const float* __restrict__ bq, const float* __restrict__ bk,
                          const float* __restrict__ bv, float* __restrict__ out,
                          float qscale) {
  const int i = blockIdx.x * 256 + threadIdx.x;
  if (i < 1024) out[i] = bq[i] * qscale;
  else if (i < 2048) out[i] = bk[i - 1024];
  else out[i] = bv[i - 2048];
}

// ---------------------------------------------------------------------------
// V transpose (bf16): qkv[b,s,2048+h*128+e] -> VT[(b*8+h)*128+e][S].
// ---------------------------------------------------------------------------
__global__ __launch_bounds__(256)
void v_transpose(const unsigned short* __restrict__ v, unsigned short* __restrict__ VT) {
  __shared__ unsigned short tile[64][65];
  const int s0 = blockIdx.x * 64, e0 = blockIdx.y * 64, bh = blockIdx.z;
  const int b = bh >> 3, h = bh & 7;
  const int tr = threadIdx.x >> 4, tc = (threadIdx.x & 15) * 4;
  const size_t inbase = (size_t)b * 2048 * 3072 + h * 128;   // v base passed in
#pragma unroll
  for (int i = 0; i < 4; ++i) {
    const int r = tr + i * 16;
    const ushort4 val = *(const ushort4*)&v[inbase + (size_t)(s0 + r) * 3072 + e0 + tc];
    tile[r][tc + 0] = val.x;
    tile[r][tc + 1] = val.y;
    tile[r][tc + 2] = val.z;
    tile[r][tc + 3] = val.w;
  }
  __syncthreads();
#pragma unroll
  for (int i = 0; i < 4; ++i) {
    const int n = tr + i * 16;
    ushort4 oo;
    oo.x = tile[tc + 0][n];
    oo.y = tile[tc + 1][n];
    oo.z = tile[tc + 2][n];
    oo.w = tile[tc + 3][n];
    *(ushort4*)&VT[(size_t)(bh * 128 + e0 + n) * 2048 + s0 + tc] = oo;
  }
}

// ---------------------------------------------------------------------------
// lambda[h]
// ---------------------------------------------------------------------------
__global__ void lam_kernel(const float* __restrict__ lq1, const float* __restrict__ lk1,
                           const float* __restrict__ lq2, const float* __restrict__ lk2,
                           float* __restrict__ lam) {
  const int w = threadIdx.x >> 6, d = threadIdx.x & 63;
  float a = lq1[w * 64 + d] * lk1[w * 64 + d];
  float c = lq2[w * 64 + d] * lk2[w * 64 + d];
#pragma unroll
  for (int off = 32; off; off >>= 1) {
    a += __shfl_xor(a, off);
    c += __shfl_xor(c, off);
  }
  if (d == 0) lam[w] = __expf(a) - __expf(c) + 0.8f;
}

// ---------------------------------------------------------------------------
// LayerNorm over rows of 1024.
// ---------------------------------------------------------------------------
template <int WRITE_F32>
__global__ __launch_bounds__(256)
void ln_kernel(const float* __restrict__ x, const float* __restrict__ g,
               const float* __restrict__ bsh, unsigned short* __restrict__ obf,
               float* __restrict__ of32) {
  __shared__ float red[16];
  const int row = blockIdx.x, tid = threadIdx.x;
  const float4 v = *(const float4*)&x[(size_t)row * 1024 + tid * 4];
  float s = v.x + v.y + v.z + v.w;
  float q = v.x * v.x + v.y * v.y + v.z * v.z + v.w * v.w;
#pragma unroll
  for (int off = 32; off; off >>= 1) {
    s += __shfl_xor(s, off);
    q += __shfl_xor(q, off);
  }
  if ((tid & 63) == 0) {
    red[tid >> 6] = s;
    red[8 + (tid >> 6)] = q;
  }
  __syncthreads();
  s = red[0] + red[1] + red[2] + red[3];
  q = red[8] + red[9] + red[10] + red[11];
  const float mean = s * (1.f / 1024.f);
  const float var = q * (1.f / 1024.f) - mean * mean;
  const float rstd = rsqrtf(var + 1e-5f);
  const float4 gg = *(const float4*)&g[tid * 4];
  const float4 bb = *(const float4*)&bsh[tid * 4];
  float y0 = (v.x - mean) * rstd * gg.x + bb.x;
  float y1 = (v.y - mean) * rstd * gg.y + bb.y;
  float y2 = (v.z - mean) * rstd * gg.z + bb.z;
  float y3 = (v.w - mean) * rstd * gg.w + bb.w;
  const size_t base = (size_t)row * 1024 + tid * 4;
  ushort4 o;
  o.x = f2bf(y0); o.y = f2bf(y1); o.z = f2bf(y2); o.w = f2bf(y3);
  *(ushort4*)&obf[base] = o;
  if (WRITE_F32) {
    *(float4*)&of32[base] = make_float4(y0, y1, y2, y3);
  }
}

// ---------------------------------------------------------------------------
// GEMM 128x128 (m97 structure): used for the N=1024 GEMMs (Wo, W2).
// ---------------------------------------------------------------------------
template <int EPI>
__global__ __launch_bounds__(256)
void gemm_bf16(const unsigned short* __restrict__ A,
               const unsigned short* __restrict__ BT,
               const float* __restrict__ bias,
               const float* __restrict__ res,
               const unsigned short* __restrict__ gate_u,
               void* __restrict__ Cout, int M, int N, int K, float bscale) {
  __shared__ unsigned short ldsA[128 * 32];
  __shared__ unsigned short ldsB[128 * 32];
  const int tid = threadIdx.x;
  const int wv = tid >> 6, ln = tid & 63, lg = ln >> 4, lc = ln & 15;
  const int wm = wv >> 1, wn = wv & 1;
  const int nwg = gridDim.x * gridDim.y;
  const int linear = blockIdx.y * gridDim.x + blockIdx.x;
  const int swz = (linear & 7) * (nwg >> 3) + (linear >> 3);
  const int m0 = (swz / gridDim.x) * 128, n0 = (swz % gridDim.x) * 128;
  const int rsub = ln >> 2, acol = (ln & 3) * 8;

  f32x4 acc[4][4];
#pragma unroll
  for (int i = 0; i < 4; ++i)
#pragma unroll
    for (int j = 0; j < 4; ++j) acc[i][j] = (f32x4)0.f;

  for (int k0 = 0; k0 < K; k0 += 32) {
#pragma unroll
    for (int j = 0; j < 2; ++j) {
      const int rowblk = wv * 32 + j * 16;
      const unsigned short* ga = A + (size_t)(m0 + rowblk + rsub) * K + (k0 + acol);
      __builtin_amdgcn_global_load_lds((GAS void*)ga, (LAS void*)&ldsA[rowblk * 32], 16, 0, 0);
      const unsigned short* gb = BT + (size_t)(n0 + rowblk + rsub) * K + (k0 + acol);
      __builtin_amdgcn_global_load_lds((GAS void*)gb, (LAS void*)&ldsB[rowblk * 32], 16, 0, 0);
    }
    __syncthreads();
    bf16x8 af[4], bf[4];
#pragma unroll
    for (int m = 0; m < 4; ++m)
      af[m] = *(const bf16x8*)&ldsA[(wm * 64 + m * 16 + lc) * 32 + lg * 8];
#pragma unroll
    for (int n = 0; n < 4; ++n)
      bf[n] = *(const bf16x8*)&ldsB[(wn * 64 + n * 16 + lc) * 32 + lg * 8];
#pragma unroll
    for (int m = 0; m < 4; ++m)
#pragma unroll
      for (int n = 0; n < 4; ++n)
        acc[m][n] = __builtin_amdgcn_mfma_f32_16x16x32_bf16(af[m], bf[n], acc[m][n], 0, 0, 0);
    __syncthreads();
  }

#pragma unroll
  for (int m = 0; m < 4; ++m) {
#pragma unroll
    for (int n = 0; n < 4; ++n) {
      const int c = n0 + wn * 64 + n * 16 + lc;
      const float bc = bias[c] * bscale;
#pragma unroll
      for (int j = 0; j < 4; ++j) {
        const int r = m0 + wm * 64 + m * 16 + lg * 4 + j;
        const size_t idx = (size_t)r * N + c;
        const float v = acc[m][n][j] + bc;
        if (EPI == 0) {
          ((unsigned short*)Cout)[idx] = f2bf(v);
        } else if (EPI == 1) {
          ((float*)Cout)[idx] = res[idx] + v;
        } else {
          const float uu = bf2f(gate_u[idx]);
          const float sw = v / (1.f + __expf(-v));   // silu
          ((unsigned short*)Cout)[idx] = f2bf(uu * sw);
        }
      }
    }
  }
}

// ---------------------------------------------------------------------------
// GEMM 256x256, 8-wave (2Mx4N), BK=64, 8-phase deep pipeline (m201 template).
// vmcnt(4) at P4/P8 only; lgkmcnt(8) hint in 12-ds_read phases; raw barriers;
// XOR swizzle byte^=(r&7)<<4 via pre-swizzled source.
// EPI 0: bf16 out = acc + bias.  EPI 2: bf16 out = gate_u * silu(acc + bias).
// ---------------------------------------------------------------------------
template <int EPI>
__global__ __launch_bounds__(512)
void gemm256(const unsigned short* __restrict__ A,
             const unsigned short* __restrict__ BT,
             const float* __restrict__ bias,
             const unsigned short* __restrict__ gate_u,
             unsigned short* __restrict__ Cout, int M, int N, int K) {
  __shared__ unsigned short lds[65536];   // 128 KB = 8 x 16KB slots
  const int tid = threadIdx.x;
  const int w = tid >> 6, ln = tid & 63, lg = ln >> 4, lc = ln & 15;
  const int wm = w >> 2, wn = w & 3;
  const int nwg = gridDim.x * gridDim.y;
  const int linear = blockIdx.y * gridDim.x + blockIdx.x;
  const int swzb = (linear & 7) * (nwg >> 3) + (linear >> 3);
  const int m0 = (swzb / gridDim.x) * 256, n0 = (swzb % gridDim.x) * 256;

  f32x4 acc[8][4];
#pragma unroll
  for (int i = 0; i < 8; ++i)
#pragma unroll
    for (int j = 0; j < 4; ++j) acc[i][j] = (f32x4)0.f;

  auto stage_half = [&](int tensor, int j, int hh) {
    const unsigned short* base = tensor ? BT : A;
    const int row0 = (tensor ? n0 : m0) + hh * 128;
    const int slot = tensor * 4 + (j & 1) * 2 + hh;
#pragma unroll
    for (int c = 0; c < 2; ++c) {
      const int chunk = w * 2 + c;
      const int L = chunk * 1024 + ln * 16;
      const int r = L >> 7, inner = L & 127;
      const char* src = (const char*)(base + (size_t)(row0 + r) * K + j * 64) +
                        (inner ^ ((r & 7) << 4));
      __builtin_amdgcn_global_load_lds((GAS void*)src,
          (LAS void*)((char*)lds + slot * 16384 + chunk * 1024), 16, 0, 0);
    }
  };
  auto read_a = [&](int j, int mf, int ks) -> bf16x8 {
    const int r = mf * 16 + lc;
    const int slot = (j & 1) * 2 + wm;
    const int cb = ks * 64 + lg * 16;
    return *(const bf16x8*)((const char*)lds + slot * 16384 + r * 128 +
                            (cb ^ ((r & 7) << 4)));
  };
  auto read_b = [&](int j, int nf, int ks) -> bf16x8 {
    const int R = wn * 64 + nf * 16 + lc;
    const int slot = 4 + (j & 1) * 2 + (R >> 7);
    const int r = R & 127;
    const int cb = ks * 64 + lg * 16;
    return *(const bf16x8*)((const char*)lds + slot * 16384 + r * 128 +
                            (cb ^ ((r & 7) << 4)));
  };

  const int nkt = K / 64;

  stage_half(0, 0, 0); stage_half(0, 0, 1);
  stage_half(1, 0, 0); stage_half(1, 0, 1);
  stage_half(1, 1, 0); stage_half(1, 1, 1);
  asm volatile("s_waitcnt vmcnt(0)" ::: "memory");
  __builtin_amdgcn_s_barrier();

  bf16x8 bfr[4][2];
  for (int it = 0; it < nkt / 2; ++it) {
    const int J = it * 2;
#pragma unroll
    for (int half = 0; half < 2; ++half) {
      const int jc = J + half;            // K-tile computed in this 4-phase group
#pragma unroll
      for (int q = 0; q < 4; ++q) {
        if (q == 0) {
#pragma unroll
          for (int nf = 0; nf < 4; ++nf)
#pragma unroll
            for (int ks = 0; ks < 2; ++ks) bfr[nf][ks] = read_b(jc, nf, ks);
        }
        bf16x8 afr[2][2];
#pragma unroll
        for (int mm = 0; mm < 2; ++mm)
#pragma unroll
          for (int ks = 0; ks < 2; ++ks) afr[mm][ks] = read_a(jc, q * 2 + mm, ks);
        // staging schedule: half0: A(J+1)h0,h1 / B(J+2)h0,h1
        //                   half1: A(J+2)h0,h1 / B(J+3)h0,h1
        if (half == 0) {
          if (q == 0) stage_half(0, J + 1, 0);
          if (q == 1) stage_half(0, J + 1, 1);
          if (q == 2 && J + 2 < nkt) stage_half(1, J + 2, 0);
          if (q == 3 && J + 2 < nkt) stage_half(1, J + 2, 1);
        } else {
          if (q == 0 && J + 2 < nkt) stage_half(0, J + 2, 0);
          if (q == 1 && J + 2 < nkt) stage_half(0, J + 2, 1);
          if (q == 2 && J + 3 < nkt) stage_half(1, J + 3, 0);
          if (q == 3 && J + 3 < nkt) stage_half(1, J + 3, 1);
        }
        if (q == 0) asm volatile("s_waitcnt lgkmcnt(8)" ::: "memory");
        if (q == 3) asm volatile("s_waitcnt vmcnt(4)" ::: "memory");
        __builtin_amdgcn_s_barrier();
        __builtin_amdgcn_s_setprio(1);
#pragma unroll
        for (int mm = 0; mm < 2; ++mm)
#pragma unroll
          for (int nf = 0; nf < 4; ++nf)
#pragma unroll
            for (int ks = 0; ks < 2; ++ks)
              acc[q * 2 + mm][nf] = __builtin_amdgcn_mfma_f32_16x16x32_bf16(
                  afr[mm][ks], bfr[nf][ks], acc[q * 2 + mm][nf], 0, 0, 0);
        __builtin_amdgcn_s_setprio(0);
        __builtin_amdgcn_s_barrier();
      }
    }
  }

#pragma unroll
  for (int mf = 0; mf < 8; ++mf) {
#pragma unroll
    for (int nf = 0; nf < 4; ++nf) {
      const int c = n0 + wn * 64 + nf * 16 + lc;
      const float bc = bias[c];
#pragma unroll
      for (int jj = 0; jj < 4; ++jj) {
        const int r = m0 + wm * 128 + mf * 16 + lg * 4 + jj;
        const size_t idx = (size_t)r * N + c;
        const float v = acc[mf][nf][jj] + bc;
        if (EPI == 0) {
          Cout[idx] = f2bf(v);
        } else {
          const float uu = bf2f(gate_u[idx]);
          const float sw = v / (1.f + __expf(-v));   // silu
          Cout[idx] = f2bf(uu * sw);
        }
      }
    }
  }
}

// ---------------------------------------------------------------------------
// Differential attention partials: LDS-staged K/V, 2-phase double buffer.
// qkv layout: [b,s,3072]; q at +0, k at +1024 (passed as separate pointers).
// ---------------------------------------------------------------------------
__global__ __launch_bounds__(256)
void attn_kernel(const unsigned short* __restrict__ q,
                 const unsigned short* __restrict__ k,
                 const unsigned short* __restrict__ VT,
                 float* __restrict__ Opart,
                 float* __restrict__ lsumPart) {
  constexpr int S = 2048;
  constexpr int QS = 3072;   // row stride of fused qkv
  __shared__ unsigned short k_tile[2][32 * 128];
  __shared__ unsigned short v_tile[2][128 * 32];
  __shared__ unsigned short p_lds[4][2][512];
  const int tid = threadIdx.x, w = tid >> 6, ln = tid & 63, lg = ln >> 4, lc = ln & 15;
  const int id = blockIdx.x;
  const int bh = (id & 7) + 8 * ((id >> 9) & 1);
  const int qt = (id >> 3) & 31;
  const int tcn = (id >> 8) & 1;
  const size_t chan = (size_t)(bh >> 3) * S * QS + (bh & 7) * 128;
  const size_t vtbase = (size_t)bh * 128 * S;
  const int qrow = qt * 64 + w * 16 + lc;

  bf16x8 qf[2][2];
#pragma unroll
  for (int p = 0; p < 2; ++p)
#pragma unroll
    for (int ks = 0; ks < 2; ++ks)
      qf[p][ks] = *(const bf16x8*)&q[chan + (size_t)qrow * QS + p * 64 + ks * 32 + lg * 8];

  f32x4 O[2][8];
#pragma unroll
  for (int p = 0; p < 2; ++p)
#pragma unroll
    for (int ef = 0; ef < 8; ++ef) O[p][ef] = (f32x4)0.f;
  float lsum[2][4];
#pragma unroll
  for (int p = 0; p < 2; ++p)
#pragma unroll
    for (int j = 0; j < 4; ++j) lsum[p][j] = 0.f;

  const int prd = ((lc * 64 + lg * 16) ^ ((lc & 7) << 4)) >> 1;

  auto stage = [&](int buf, int t0) {
#pragma unroll
    for (int c = 0; c < 2; ++c) {
      {
        const int L = (w * 2 + c) * 1024 + ln * 16;
        const int r = L >> 8, inner = L & 255;
        const char* src = (const char*)(k + chan + (size_t)(t0 + r) * QS) +
                          (inner ^ ((r & 7) << 4));
        __builtin_amdgcn_global_load_lds((GAS void*)src,
            (LAS void*)((char*)&k_tile[buf][0] + (w * 2 + c) * 1024), 16, 0, 0);
      }
      {
        const int L = (w * 2 + c) * 1024 + ln * 16;
        const int e = L >> 6, inner = L & 63;
        const char* src = (const char*)(VT + vtbase + (size_t)e * S + t0) +
                          (inner ^ ((e & 3) << 4));
        __builtin_amdgcn_global_load_lds((GAS void*)src,
            (LAS void*)((char*)&v_tile[buf][0] + (w * 2 + c) * 1024), 16, 0, 0);
      }
    }
  };

  auto compute = [&](int buf) {
    const char* kb = (const char*)&k_tile[buf][0];
    const char* vb = (const char*)&v_tile[buf][0];
    bf16x8 vf[8];
#pragma unroll
    for (int ef = 0; ef < 8; ++ef) {
      const int e = ef * 16 + lc;
      vf[ef] = *(const bf16x8*)(vb + e * 64 + ((lg * 16) ^ ((e & 3) << 4)));
    }
#pragma unroll
    for (int p = 0; p < 2; ++p) {
      bf16x8 kf[2][2];
#pragma unroll
      for (int tf = 0; tf < 2; ++tf) {
        const int r = tf * 16 + lc;
#pragma unroll
        for (int ks = 0; ks < 2; ++ks)
          kf[tf][ks] = *(const bf16x8*)(kb + r * 256 +
                          ((p * 128 + ks * 64 + lg * 16) ^ ((r & 7) << 4)));
      }
      f32x4 sfr[2];
      __builtin_amdgcn_s_setprio(1);
#pragma unroll
      for (int tf = 0; tf < 2; ++tf) {
        f32x4 acc = (f32x4)0.f;
#pragma unroll
        for (int ks = 0; ks < 2; ++ks)
          acc = __builtin_amdgcn_mfma_f32_16x16x32_bf16(qf[p][ks], kf[tf][ks], acc, 0, 0, 0);
        sfr[tf] = acc;
      }
      __builtin_amdgcn_s_setprio(0);

#pragma unroll
      for (int tf = 0; tf < 2; ++tf)
#pragma unroll
        for (int j = 0; j < 4; ++j) {
          const float e = __expf(sfr[tf][j]);
          lsum[p][j] += e;
          const int qq = lg * 4 + j;
          const int wi = ((qq * 64 + (tf * 16 + lc) * 2) ^ ((qq & 7) << 4)) >> 1;
          p_lds[w][p][wi] = f2bf(e);
        }

      const bf16x8 pa = *(const bf16x8*)&p_lds[w][p][prd];
      __builtin_amdgcn_s_setprio(1);
#pragma unroll
      for (int ef = 0; ef < 8; ++ef)
        O[p][ef] = __builtin_amdgcn_mfma_f32_16x16x32_bf16(pa, vf[ef], O[p][ef], 0, 0, 0);
      __builtin_amdgcn_s_setprio(0);
    }
  };

  const int tbeg = tcn * (S / 2);
  stage(0, tbeg);
  __syncthreads();
  int cur = 0;
  for (int it = 0; it < 32; ++it) {
    if (it < 31) stage(cur ^ 1, tbeg + (it + 1) * 32);
    compute(cur);
    __syncthreads();
    cur ^= 1;
  }

  const size_t rowbase = ((size_t)tcn * 16 + bh) * S;
#pragma unroll
  for (int p = 0; p < 2; ++p)
#pragma unroll
    for (int j = 0; j < 4; ++j) {
      float s = lsum[p][j];
      s += __shfl_xor(s, 1);
      s += __shfl_xor(s, 2);
      s += __shfl_xor(s, 4);
      s += __shfl_xor(s, 8);
      const int row = qt * 64 + w * 16 + lg * 4 + j;
      if (lc == 0)
        lsumPart[(rowbase + row) * 2 + p] = s;
#pragma unroll
      for (int ef = 0; ef < 8; ++ef)
        Opart[(rowbase + row) * 256 + p * 128 + ef * 16 + lc] = O[p][ef][j];
    }
}

// ---------------------------------------------------------------------------
// Combine t-chunk partials: normalize, lambda-diff, headwise GroupNorm, *0.2.
// ---------------------------------------------------------------------------
__global__ __launch_bounds__(256)
void attn_reduce(const float* __restrict__ Opart, const float* __restrict__ lsumPart,
                 const float* __restrict__ lam,
                 const float* __restrict__ gn_w, const float* __restrict__ gn_b,
                 unsigned short* __restrict__ o) {
  constexpr int S = 2048;
  const int gw = (blockIdx.x * 256 + threadIdx.x) >> 6;
  const int ln = threadIdx.x & 63;
  const int bh = gw >> 11, s = gw & 2047;
  const int b = bh >> 3, h = bh & 7;
  const size_t r0 = ((size_t)bh * S + s) * 256;
  const size_t r1 = (((size_t)16 + bh) * S + s) * 256;
  const int e = ln * 2;
  const float2 o1a = *(const float2*)&Opart[r0 + e];
  const float2 o1b = *(const float2*)&Opart[r1 + e];
  const float2 o2a = *(const float2*)&Opart[r0 + 128 + e];
  const float2 o2b = *(const float2*)&Opart[r1 + 128 + e];
  const size_t l0 = ((size_t)bh * S + s) * 2;
  const size_t l1 = (((size_t)16 + bh) * S + s) * 2;
  const float inv1 = 1.f / (lsumPart[l0] + lsumPart[l1]);
  const float inv2 = lam[h] / (lsumPart[l0 + 1] + lsumPart[l1 + 1]);
  float d0 = (o1a.x + o1b.x) * inv1 - (o2a.x + o2b.x) * inv2;
  float d1 = (o1a.y + o1b.y) * inv1 - (o2a.y + o2b.y) * inv2;
  float sum = d0 + d1, sq = d0 * d0 + d1 * d1;
#pragma unroll
  for (int off = 32; off; off >>= 1) {
    sum += __shfl_xor(sum, off);
    sq += __shfl_xor(sq, off);
  }
  const float mean = sum * (1.f / 128.f);
  const float var = sq * (1.f / 128.f) - mean * mean;
  const float rstd = rsqrtf(var + 1e-5f);
  const float v0 = ((d0 - mean) * rstd * gn_w[h * 128 + e] + gn_b[h * 128 + e]) * 0.2f;
  const float v1 = ((d1 - mean) * rstd * gn_w[h * 128 + e + 1] + gn_b[h * 128 + e + 1]) * 0.2f;
  ushort2 ov;
  ov.x = f2bf(v0);
  ov.y = f2bf(v1);
  *(ushort2*)&o[(size_t)b * S * 1024 + (size_t)s * 1024 + h * 128 + e] = ov;
}

// ---------------------------------------------------------------------------
extern "C" void kernel_launch(void* const* d_in, const int* in_sizes, int n_in,
                              void* d_out, int out_size, void* d_ws, size_t ws_size,
                              hipStream_t stream) {
  (void)in_sizes; (void)n_in; (void)out_size; (void)ws_size;
  const float* x    = (const float*)d_in[0];
  const float* ln1g = (const float*)d_in[1];
  const float* ln1b = (const float*)d_in[2];
  const float* ln2g = (const float*)d_in[3];
  const float* ln2b = (const float*)d_in[4];
  const float* Wq   = (const float*)d_in[5];
  const float* bq   = (const float*)d_in[6];
  const float* Wk   = (const float*)d_in[7];
  const float* bk   = (const float*)d_in[8];
  const float* Wv   = (const float*)d_in[9];
  const float* bv   = (const float*)d_in[10];
  const float* Wo   = (const float*)d_in[11];
  const float* bo   = (const float*)d_in[12];
  const float* lq1  = (const float*)d_in[13];
  const float* lk1  = (const float*)d_in[14];
  const float* lq2  = (const float*)d_in[15];
  const float* lk2  = (const float*)d_in[16];
  const float* gnw  = (const float*)d_in[17];
  const float* gnb  = (const float*)d_in[18];
  const float* W1   = (const float*)d_in[19];
  const float* b1   = (const float*)d_in[20];
  const float* Wg   = (const float*)d_in[21];
  const float* bg   = (const float*)d_in[22];
  const float* W2   = (const float*)d_in[23];
  const float* b2   = (const float*)d_in[24];

  const int B = 2, S = 2048, D = 1024, F = 4096;
  const int M = B * S;  // 4096
  const float qscale = 0.125f;

  char* ws = (char*)d_ws;
  size_t off = 0;
  auto alloc = [&](size_t bytes) {
    char* p = ws + off;
    off += (bytes + 255) & ~(size_t)255;
    return p;
  };
  unsigned short* WqkvT = (unsigned short*)alloc((size_t)3 * D * D * 2);  // [3072][1024]
  unsigned short* WoT = (unsigned short*)alloc((size_t)D * D * 2);
  unsigned short* W1T = (unsigned short*)alloc((size_t)F * D * 2);
  unsigned short* WgT = (unsigned short*)alloc((size_t)F * F * 2);
  unsigned short* W2T = (unsigned short*)alloc((size_t)D * F * 2);
  float*          lamw= (float*)alloc(256);
  float*          bqkv= (float*)alloc(3072 * 4);
  unsigned short* h_bf= (unsigned short*)alloc((size_t)M * D * 2);
  unsigned short* qkv = (unsigned short*)alloc((size_t)M * 3 * D * 2);  // 24MB
  unsigned short* o_bf= (unsigned short*)alloc((size_t)M * D * 2);
  float*          x1  = (float*)alloc((size_t)M * D * 4);
  float*          x2  = (float*)alloc((size_t)M * D * 4);
  unsigned short* x2b = (unsigned short*)alloc((size_t)M * D * 2);
  unsigned short* u_bf= (unsigned short*)alloc((size_t)M * F * 2);
  float*          lsumP = (float*)alloc((size_t)2 * 16 * S * 2 * 4);
  unsigned short* w_bf= h_bf;   // gated act reuses h span (dead after qkv GEMM)

  // Overlays: Opart (64MB fp32) on x1+x2+x2b+u_bf[0:24MB) — dead during attn.
  // VT (8MB) in u_bf[24:32MB) — dead once W1-gemm writes u_bf (after attn).
  float* Opart = (float*)x1;
  unsigned short* VT = u_bf + (size_t)12 * 1024 * 1024;

  // --- weight prep ---
  transpose_cvt<<<dim3(D / 64, D / 64), 256, 0, stream>>>(Wq, WqkvT, D, D, qscale);
  transpose_cvt<<<dim3(D / 64, D / 64), 256, 0, stream>>>(Wk, WqkvT + (size_t)D * D, D, D, 1.0f);
  transpose_cvt<<<dim3(D / 64, D / 64), 256, 0, stream>>>(Wv, WqkvT + (size_t)2 * D * D, D, D, 1.0f);
  transpose_cvt<<<dim3(D / 64, D / 64), 256, 0, stream>>>(Wo, WoT, D, D, 1.0f);
  transpose_cvt<<<dim3(F / 64, D / 64), 256, 0, stream>>>(W1, W1T, D, F, 1.0f);
  transpose_cvt<<<dim3(F / 64, F / 64), 256, 0, stream>>>(Wg, WgT, F, F, 1.0f);
  transpose_cvt<<<dim3(D / 64, F / 64), 256, 0, stream>>>(W2, W2T, F, D, 1.0f);
  prep_bias<<<12, 256, 0, stream>>>(bq, bk, bv, bqkv, qscale);
  lam_kernel<<<1, 512, 0, stream>>>(lq1, lk1, lq2, lk2, lamw);

  // --- attention sublayer ---
  ln_kernel<0><<<M, 256, 0, stream>>>(x, ln1g, ln1b, h_bf, nullptr);
  gemm256<0><<<dim3(3 * D / 256, M / 256), 512, 0, stream>>>(h_bf, WqkvT, bqkv, nullptr, qkv, M, 3 * D, D);
  v_transpose<<<dim3(S / 64, 2, 16), 256, 0, stream>>>(qkv + 2048, VT);
  attn_kernel<<<dim3(1024), 256, 0, stream>>>(qkv, qkv + 1024, VT, Opart, lsumP);
  attn_reduce<<<dim3(8192), 256, 0, stream>>>(Opart, lsumP, lamw, gnw, gnb, o_bf);
  gemm_bf16<1><<<dim3(D / 128, M / 128), 256, 0, stream>>>(o_bf, WoT, bo, x, nullptr, x1, M, D, D, 1.0f);

  // --- FFN sublayer ---
  ln_kernel<1><<<M, 256, 0, stream>>>(x1, ln2g, ln2b, x2b, x2);
  gemm256<0><<<dim3(F / 256, M / 256), 512, 0, stream>>>(x2b, W1T, b1, nullptr, u_bf, M, F, D);
  gemm256<2><<<dim3(F / 256, M / 256), 512, 0, stream>>>(u_bf, WgT, bg, u_bf, w_bf, M, F, F);
  gemm_bf16<1><<<dim3(D / 128, M / 128), 256, 0, stream>>>(w_bf, W2T, b2, x2, nullptr, (float*)d_out, M, D, F, 1.0f);
}

// Round 10
// 478.332 us; speedup vs baseline: 1.8370x; 1.0166x over previous
//
#include <hip/hip_runtime.h>
#include <hip/hip_bf16.h>

// ---------------------------------------------------------------------------
// EncoderBlock (differential attention + swiGLU FFN), MI355X / gfx950
// R9: T4 counted-vmcnt in attn_kernel and gemm_bf16 — replace __syncthreads
//     (vmcnt(0) drain) with {stage; vmcnt(4); raw barrier; compute; barrier}.
//     gemm_bf16 now true double-buffered. gemm256/attn math unchanged.
// ---------------------------------------------------------------------------

typedef __attribute__((ext_vector_type(8))) __bf16 bf16x8;
typedef __attribute__((ext_vector_type(4))) float f32x4;

#define GAS __attribute__((address_space(1)))
#define LAS __attribute__((address_space(3)))

__device__ __forceinline__ unsigned short f2bf(float f) {
  unsigned u = __float_as_uint(f);
  u += 0x7fffu + ((u >> 16) & 1u);   // RNE
  return (unsigned short)(u >> 16);
}
__device__ __forceinline__ float bf2f(unsigned short s) {
  return __uint_as_float(((unsigned)s) << 16);
}

// ---------------------------------------------------------------------------
// Transpose + convert: W[K][N] fp32 -> WT[N][K] bf16 * scale.
// ---------------------------------------------------------------------------
__global__ __launch_bounds__(256)
void transpose_cvt(const float* __restrict__ W, unsigned short* __restrict__ WT,
                   int K, int N, float scale) {
  __shared__ float tile[64][65];
  const int n0 = blockIdx.x * 64, k0 = blockIdx.y * 64;
  const int tr = threadIdx.x >> 4, tc = (threadIdx.x & 15) * 4;
#pragma unroll
  for (int i = 0; i < 4; ++i) {
    const float4 v = *(const float4*)&W[(size_t)(k0 + tr + i * 16) * N + n0 + tc];
    tile[tr + i * 16][tc + 0] = v.x;
    tile[tr + i * 16][tc + 1] = v.y;
    tile[tr + i * 16][tc + 2] = v.z;
    tile[tr + i * 16][tc + 3] = v.w;
  }
  __syncthreads();
#pragma unroll
  for (int i = 0; i < 4; ++i) {
    const int n = tr + i * 16;
    ushort4 o;
    o.x = f2bf(tile[tc + 0][n] * scale);
    o.y = f2bf(tile[tc + 1][n] * scale);
    o.z = f2bf(tile[tc + 2][n] * scale);
    o.w = f2bf(tile[tc + 3][n] * scale);
    *(ushort4*)&WT[(size_t)(n0 + n) * K + k0 + tc] = o;
  }
}

// ---------------------------------------------------------------------------
// Combined qkv bias: [0,1024)=bq*s, [1024,2048)=bk, [2048,3072)=bv.
// ---------------------------------------------------------------------------
__global__ void prep_bias(const float* __restrict__ bq, const float* __restrict__ bk,
                          const float* __restrict__ bv, float* __restrict__ out,
                          float qscale) {
  const int i = blockIdx.x * 256 + threadIdx.x;
  if (i < 1024) out[i] = bq[i] * qscale;
  else if (i < 2048) out[i] = bk[i - 1024];
  else out[i] = bv[i - 2048];
}

// ---------------------------------------------------------------------------
// V transpose (bf16): qkv[b,s,2048+h*128+e] -> VT[(b*8+h)*128+e][S].
// ---------------------------------------------------------------------------
__global__ __launch_bounds__(256)
void v_transpose(const unsigned short* __restrict__ v, unsigned short* __restrict__ VT) {
  __shared__ unsigned short tile[64][65];
  const int s0 = blockIdx.x * 64, e0 = blockIdx.y * 64, bh = blockIdx.z;
  const int b = bh >> 3, h = bh & 7;
  const int tr = threadIdx.x >> 4, tc = (threadIdx.x & 15) * 4;
  const size_t inbase = (size_t)b * 2048 * 3072 + h * 128;
#pragma unroll
  for (int i = 0; i < 4; ++i) {
    const int r = tr + i * 16;
    const ushort4 val = *(const ushort4*)&v[inbase + (size_t)(s0 + r) * 3072 + e0 + tc];
    tile[r][tc + 0] = val.x;
    tile[r][tc + 1] = val.y;
    tile[r][tc + 2] = val.z;
    tile[r][tc + 3] = val.w;
  }
  __syncthreads();
#pragma unroll
  for (int i = 0; i < 4; ++i) {
    const int n = tr + i * 16;
    ushort4 oo;
    oo.x = tile[tc + 0][n];
    oo.y = tile[tc + 1][n];
    oo.z = tile[tc + 2][n];
    oo.w = tile[tc + 3][n];
    *(ushort4*)&VT[(size_t)(bh * 128 + e0 + n) * 2048 + s0 + tc] = oo;
  }
}

// ---------------------------------------------------------------------------
// lambda[h]
// ---------------------------------------------------------------------------
__global__ void lam_kernel(const float* __restrict__ lq1, const float* __restrict__ lk1,
                           const float* __restrict__ lq2, const float* __restrict__ lk2,
                           float* __restrict__ lam) {
  const int w = threadIdx.x >> 6, d = threadIdx.x & 63;
  float a = lq1[w * 64 + d] * lk1[w * 64 + d];
  float c = lq2[w * 64 + d] * lk2[w * 64 + d];
#pragma unroll
  for (int off = 32; off; off >>= 1) {
    a += __shfl_xor(a, off);
    c += __shfl_xor(c, off);
  }
  if (d == 0) lam[w] = __expf(a) - __expf(c) + 0.8f;
}

// ---------------------------------------------------------------------------
// LayerNorm over rows of 1024.
// ---------------------------------------------------------------------------
template <int WRITE_F32>
__global__ __launch_bounds__(256)
void ln_kernel(const float* __restrict__ x, const float* __restrict__ g,
               const float* __restrict__ bsh, unsigned short* __restrict__ obf,
               float* __restrict__ of32) {
  __shared__ float red[16];
  const int row = blockIdx.x, tid = threadIdx.x;
  const float4 v = *(const float4*)&x[(size_t)row * 1024 + tid * 4];
  float s = v.x + v.y + v.z + v.w;
  float q = v.x * v.x + v.y * v.y + v.z * v.z + v.w * v.w;
#pragma unroll
  for (int off = 32; off; off >>= 1) {
    s += __shfl_xor(s, off);
    q += __shfl_xor(q, off);
  }
  if ((tid & 63) == 0) {
    red[tid >> 6] = s;
    red[8 + (tid >> 6)] = q;
  }
  __syncthreads();
  s = red[0] + red[1] + red[2] + red[3];
  q = red[8] + red[9] + red[10] + red[11];
  const float mean = s * (1.f / 1024.f);
  const float var = q * (1.f / 1024.f) - mean * mean;
  const float rstd = rsqrtf(var + 1e-5f);
  const float4 gg = *(const float4*)&g[tid * 4];
  const float4 bb = *(const float4*)&bsh[tid * 4];
  float y0 = (v.x - mean) * rstd * gg.x + bb.x;
  float y1 = (v.y - mean) * rstd * gg.y + bb.y;
  float y2 = (v.z - mean) * rstd * gg.z + bb.z;
  float y3 = (v.w - mean) * rstd * gg.w + bb.w;
  const size_t base = (size_t)row * 1024 + tid * 4;
  ushort4 o;
  o.x = f2bf(y0); o.y = f2bf(y1); o.z = f2bf(y2); o.w = f2bf(y3);
  *(ushort4*)&obf[base] = o;
  if (WRITE_F32) {
    *(float4*)&of32[base] = make_float4(y0, y1, y2, y3);
  }
}

// ---------------------------------------------------------------------------
// GEMM 128x128 (m97 structure + T4): double-buffered LDS, counted vmcnt(4),
// raw barriers. Used for the N=1024 GEMMs (Wo, W2).
// ---------------------------------------------------------------------------
template <int EPI>
__global__ __launch_bounds__(256)
void gemm_bf16(const unsigned short* __restrict__ A,
               const unsigned short* __restrict__ BT,
               const float* __restrict__ bias,
               const float* __restrict__ res,
               const unsigned short* __restrict__ gate_u,
               void* __restrict__ Cout, int M, int N, int K, float bscale) {
  __shared__ unsigned short ldsA[2][128 * 32];
  __shared__ unsigned short ldsB[2][128 * 32];
  const int tid = threadIdx.x;
  const int wv = tid >> 6, ln = tid & 63, lg = ln >> 4, lc = ln & 15;
  const int wm = wv >> 1, wn = wv & 1;
  const int nwg = gridDim.x * gridDim.y;
  const int linear = blockIdx.y * gridDim.x + blockIdx.x;
  const int swz = (linear & 7) * (nwg >> 3) + (linear >> 3);
  const int m0 = (swz / gridDim.x) * 128, n0 = (swz % gridDim.x) * 128;
  const int rsub = ln >> 2, acol = (ln & 3) * 8;

  f32x4 acc[4][4];
#pragma unroll
  for (int i = 0; i < 4; ++i)
#pragma unroll
    for (int j = 0; j < 4; ++j) acc[i][j] = (f32x4)0.f;

  auto stage = [&](int buf, int k0) {
#pragma unroll
    for (int j = 0; j < 2; ++j) {
      const int rowblk = wv * 32 + j * 16;
      const unsigned short* ga = A + (size_t)(m0 + rowblk + rsub) * K + (k0 + acol);
      __builtin_amdgcn_global_load_lds((GAS void*)ga,
          (LAS void*)&ldsA[buf][rowblk * 32], 16, 0, 0);
      const unsigned short* gb = BT + (size_t)(n0 + rowblk + rsub) * K + (k0 + acol);
      __builtin_amdgcn_global_load_lds((GAS void*)gb,
          (LAS void*)&ldsB[buf][rowblk * 32], 16, 0, 0);
    }
  };

  const int nk = K / 32;
  stage(0, 0);
  int cur = 0;
  for (int i = 0; i < nk; ++i) {
    if (i + 1 < nk) {
      stage(cur ^ 1, (i + 1) * 32);
      asm volatile("s_waitcnt vmcnt(4)" ::: "memory");
    } else {
      asm volatile("s_waitcnt vmcnt(0)" ::: "memory");
    }
    __builtin_amdgcn_s_barrier();
    bf16x8 af[4], bf[4];
#pragma unroll
    for (int m = 0; m < 4; ++m)
      af[m] = *(const bf16x8*)&ldsA[cur][(wm * 64 + m * 16 + lc) * 32 + lg * 8];
#pragma unroll
    for (int n = 0; n < 4; ++n)
      bf[n] = *(const bf16x8*)&ldsB[cur][(wn * 64 + n * 16 + lc) * 32 + lg * 8];
    __builtin_amdgcn_s_setprio(1);
#pragma unroll
    for (int m = 0; m < 4; ++m)
#pragma unroll
      for (int n = 0; n < 4; ++n)
        acc[m][n] = __builtin_amdgcn_mfma_f32_16x16x32_bf16(af[m], bf[n], acc[m][n], 0, 0, 0);
    __builtin_amdgcn_s_setprio(0);
    __builtin_amdgcn_s_barrier();
    cur ^= 1;
  }

#pragma unroll
  for (int m = 0; m < 4; ++m) {
#pragma unroll
    for (int n = 0; n < 4; ++n) {
      const int c = n0 + wn * 64 + n * 16 + lc;
      const float bc = bias[c] * bscale;
#pragma unroll
      for (int j = 0; j < 4; ++j) {
        const int r = m0 + wm * 64 + m * 16 + lg * 4 + j;
        const size_t idx = (size_t)r * N + c;
        const float v = acc[m][n][j] + bc;
        if (EPI == 0) {
          ((unsigned short*)Cout)[idx] = f2bf(v);
        } else if (EPI == 1) {
          ((float*)Cout)[idx] = res[idx] + v;
        } else {
          const float uu = bf2f(gate_u[idx]);
          const float sw = v / (1.f + __expf(-v));   // silu
          ((unsigned short*)Cout)[idx] = f2bf(uu * sw);
        }
      }
    }
  }
}

// ---------------------------------------------------------------------------
// GEMM 256x256, 8-wave, BK=64, 8-phase deep pipeline (m201 template).
// ---------------------------------------------------------------------------
template <int EPI>
__global__ __launch_bounds__(512)
void gemm256(const unsigned short* __restrict__ A,
             const unsigned short* __restrict__ BT,
             const float* __restrict__ bias,
             const unsigned short* __restrict__ gate_u,
             unsigned short* __restrict__ Cout, int M, int N, int K) {
  __shared__ unsigned short lds[65536];   // 128 KB = 8 x 16KB slots
  const int tid = threadIdx.x;
  const int w = tid >> 6, ln = tid & 63, lg = ln >> 4, lc = ln & 15;
  const int wm = w >> 2, wn = w & 3;
  const int nwg = gridDim.x * gridDim.y;
  const int linear = blockIdx.y * gridDim.x + blockIdx.x;
  const int swzb = (linear & 7) * (nwg >> 3) + (linear >> 3);
  const int m0 = (swzb / gridDim.x) * 256, n0 = (swzb % gridDim.x) * 256;

  f32x4 acc[8][4];
#pragma unroll
  for (int i = 0; i < 8; ++i)
#pragma unroll
    for (int j = 0; j < 4; ++j) acc[i][j] = (f32x4)0.f;

  auto stage_half = [&](int tensor, int j, int hh) {
    const unsigned short* base = tensor ? BT : A;
    const int row0 = (tensor ? n0 : m0) + hh * 128;
    const int slot = tensor * 4 + (j & 1) * 2 + hh;
#pragma unroll
    for (int c = 0; c < 2; ++c) {
      const int chunk = w * 2 + c;
      const int L = chunk * 1024 + ln * 16;
      const int r = L >> 7, inner = L & 127;
      const char* src = (const char*)(base + (size_t)(row0 + r) * K + j * 64) +
                        (inner ^ ((r & 7) << 4));
      __builtin_amdgcn_global_load_lds((GAS void*)src,
          (LAS void*)((char*)lds + slot * 16384 + chunk * 1024), 16, 0, 0);
    }
  };
  auto read_a = [&](int j, int mf, int ks) -> bf16x8 {
    const int r = mf * 16 + lc;
    const int slot = (j & 1) * 2 + wm;
    const int cb = ks * 64 + lg * 16;
    return *(const bf16x8*)((const char*)lds + slot * 16384 + r * 128 +
                            (cb ^ ((r & 7) << 4)));
  };
  auto read_b = [&](int j, int nf, int ks) -> bf16x8 {
    const int R = wn * 64 + nf * 16 + lc;
    const int slot = 4 + (j & 1) * 2 + (R >> 7);
    const int r = R & 127;
    const int cb = ks * 64 + lg * 16;
    return *(const bf16x8*)((const char*)lds + slot * 16384 + r * 128 +
                            (cb ^ ((r & 7) << 4)));
  };

  const int nkt = K / 64;

  stage_half(0, 0, 0); stage_half(0, 0, 1);
  stage_half(1, 0, 0); stage_half(1, 0, 1);
  stage_half(1, 1, 0); stage_half(1, 1, 1);
  asm volatile("s_waitcnt vmcnt(0)" ::: "memory");
  __builtin_amdgcn_s_barrier();

  bf16x8 bfr[4][2];
  for (int it = 0; it < nkt / 2; ++it) {
    const int J = it * 2;
#pragma unroll
    for (int half = 0; half < 2; ++half) {
      const int jc = J + half;
#pragma unroll
      for (int q = 0; q < 4; ++q) {
        if (q == 0) {
#pragma unroll
          for (int nf = 0; nf < 4; ++nf)
#pragma unroll
            for (int ks = 0; ks < 2; ++ks) bfr[nf][ks] = read_b(jc, nf, ks);
        }
        bf16x8 afr[2][2];
#pragma unroll
        for (int mm = 0; mm < 2; ++mm)
#pragma unroll
          for (int ks = 0; ks < 2; ++ks) afr[mm][ks] = read_a(jc, q * 2 + mm, ks);
        if (half == 0) {
          if (q == 0) stage_half(0, J + 1, 0);
          if (q == 1) stage_half(0, J + 1, 1);
          if (q == 2 && J + 2 < nkt) stage_half(1, J + 2, 0);
          if (q == 3 && J + 2 < nkt) stage_half(1, J + 2, 1);
        } else {
          if (q == 0 && J + 2 < nkt) stage_half(0, J + 2, 0);
          if (q == 1 && J + 2 < nkt) stage_half(0, J + 2, 1);
          if (q == 2 && J + 3 < nkt) stage_half(1, J + 3, 0);
          if (q == 3 && J + 3 < nkt) stage_half(1, J + 3, 1);
        }
        if (q == 0) asm volatile("s_waitcnt lgkmcnt(8)" ::: "memory");
        if (q == 3) asm volatile("s_waitcnt vmcnt(4)" ::: "memory");
        __builtin_amdgcn_s_barrier();
        __builtin_amdgcn_s_setprio(1);
#pragma unroll
        for (int mm = 0; mm < 2; ++mm)
#pragma unroll
          for (int nf = 0; nf < 4; ++nf)
#pragma unroll
            for (int ks = 0; ks < 2; ++ks)
              acc[q * 2 + mm][nf] = __builtin_amdgcn_mfma_f32_16x16x32_bf16(
                  afr[mm][ks], bfr[nf][ks], acc[q * 2 + mm][nf], 0, 0, 0);
        __builtin_amdgcn_s_setprio(0);
        __builtin_amdgcn_s_barrier();
      }
    }
  }

#pragma unroll
  for (int mf = 0; mf < 8; ++mf) {
#pragma unroll
    for (int nf = 0; nf < 4; ++nf) {
      const int c = n0 + wn * 64 + nf * 16 + lc;
      const float bc = bias[c];
#pragma unroll
      for (int jj = 0; jj < 4; ++jj) {
        const int r = m0 + wm * 128 + mf * 16 + lg * 4 + jj;
        const size_t idx = (size_t)r * N + c;
        const float v = acc[mf][nf][jj] + bc;
        if (EPI == 0) {
          Cout[idx] = f2bf(v);
        } else {
          const float uu = bf2f(gate_u[idx]);
          const float sw = v / (1.f + __expf(-v));   // silu
          Cout[idx] = f2bf(uu * sw);
        }
      }
    }
  }
}

// ---------------------------------------------------------------------------
// Differential attention partials: LDS-staged K/V, double buffer, counted
// vmcnt(4) (T4) instead of __syncthreads drain. qkv stride 3072.
// ---------------------------------------------------------------------------
__global__ __launch_bounds__(256)
void attn_kernel(const unsigned short* __restrict__ q,
                 const unsigned short* __restrict__ k,
                 const unsigned short* __restrict__ VT,
                 float* __restrict__ Opart,
                 float* __restrict__ lsumPart) {
  constexpr int S = 2048;
  constexpr int QS = 3072;
  __shared__ unsigned short k_tile[2][32 * 128];
  __shared__ unsigned short v_tile[2][128 * 32];
  __shared__ unsigned short p_lds[4][2][512];
  const int tid = threadIdx.x, w = tid >> 6, ln = tid & 63, lg = ln >> 4, lc = ln & 15;
  const int id = blockIdx.x;
  const int bh = (id & 7) + 8 * ((id >> 9) & 1);
  const int qt = (id >> 3) & 31;
  const int tcn = (id >> 8) & 1;
  const size_t chan = (size_t)(bh >> 3) * S * QS + (bh & 7) * 128;
  const size_t vtbase = (size_t)bh * 128 * S;
  const int qrow = qt * 64 + w * 16 + lc;

  bf16x8 qf[2][2];
#pragma unroll
  for (int p = 0; p < 2; ++p)
#pragma unroll
    for (int ks = 0; ks < 2; ++ks)
      qf[p][ks] = *(const bf16x8*)&q[chan + (size_t)qrow * QS + p * 64 + ks * 32 + lg * 8];

  f32x4 O[2][8];
#pragma unroll
  for (int p = 0; p < 2; ++p)
#pragma unroll
    for (int ef = 0; ef < 8; ++ef) O[p][ef] = (f32x4)0.f;
  float lsum[2][4];
#pragma unroll
  for (int p = 0; p < 2; ++p)
#pragma unroll
    for (int j = 0; j < 4; ++j) lsum[p][j] = 0.f;

  const int prd = ((lc * 64 + lg * 16) ^ ((lc & 7) << 4)) >> 1;

  auto stage = [&](int buf, int t0) {
#pragma unroll
    for (int c = 0; c < 2; ++c) {
      {
        const int L = (w * 2 + c) * 1024 + ln * 16;
        const int r = L >> 8, inner = L & 255;
        const char* src = (const char*)(k + chan + (size_t)(t0 + r) * QS) +
                          (inner ^ ((r & 7) << 4));
        __builtin_amdgcn_global_load_lds((GAS void*)src,
            (LAS void*)((char*)&k_tile[buf][0] + (w * 2 + c) * 1024), 16, 0, 0);
      }
      {
        const int L = (w * 2 + c) * 1024 + ln * 16;
        const int e = L >> 6, inner = L & 63;
        const char* src = (const char*)(VT + vtbase + (size_t)e * S + t0) +
                          (inner ^ ((e & 3) << 4));
        __builtin_amdgcn_global_load_lds((GAS void*)src,
            (LAS void*)((char*)&v_tile[buf][0] + (w * 2 + c) * 1024), 16, 0, 0);
      }
    }
  };

  auto compute = [&](int buf) {
    const char* kb = (const char*)&k_tile[buf][0];
    const char* vb = (const char*)&v_tile[buf][0];
    bf16x8 vf[8];
#pragma unroll
    for (int ef = 0; ef < 8; ++ef) {
      const int e = ef * 16 + lc;
      vf[ef] = *(const bf16x8*)(vb + e * 64 + ((lg * 16) ^ ((e & 3) << 4)));
    }
#pragma unroll
    for (int p = 0; p < 2; ++p) {
      bf16x8 kf[2][2];
#pragma unroll
      for (int tf = 0; tf < 2; ++tf) {
        const int r = tf * 16 + lc;
#pragma unroll
        for (int ks = 0; ks < 2; ++ks)
          kf[tf][ks] = *(const bf16x8*)(kb + r * 256 +
                          ((p * 128 + ks * 64 + lg * 16) ^ ((r & 7) << 4)));
      }
      f32x4 sfr[2];
      __builtin_amdgcn_s_setprio(1);
#pragma unroll
      for (int tf = 0; tf < 2; ++tf) {
        f32x4 acc = (f32x4)0.f;
#pragma unroll
        for (int ks = 0; ks < 2; ++ks)
          acc = __builtin_amdgcn_mfma_f32_16x16x32_bf16(qf[p][ks], kf[tf][ks], acc, 0, 0, 0);
        sfr[tf] = acc;
      }
      __builtin_amdgcn_s_setprio(0);

#pragma unroll
      for (int tf = 0; tf < 2; ++tf)
#pragma unroll
        for (int j = 0; j < 4; ++j) {
          const float e = __expf(sfr[tf][j]);
          lsum[p][j] += e;
          const int qq = lg * 4 + j;
          const int wi = ((qq * 64 + (tf * 16 + lc) * 2) ^ ((qq & 7) << 4)) >> 1;
          p_lds[w][p][wi] = f2bf(e);
        }

      const bf16x8 pa = *(const bf16x8*)&p_lds[w][p][prd];
      __builtin_amdgcn_s_setprio(1);
#pragma unroll
      for (int ef = 0; ef < 8; ++ef)
        O[p][ef] = __builtin_amdgcn_mfma_f32_16x16x32_bf16(pa, vf[ef], O[p][ef], 0, 0, 0);
      __builtin_amdgcn_s_setprio(0);
    }
  };

  const int tbeg = tcn * (S / 2);
  stage(0, tbeg);
  int cur = 0;
  for (int it = 0; it < 32; ++it) {
    if (it < 31) {
      stage(cur ^ 1, tbeg + (it + 1) * 32);
      asm volatile("s_waitcnt vmcnt(4)" ::: "memory");
    } else {
      asm volatile("s_waitcnt vmcnt(0)" ::: "memory");
    }
    __builtin_amdgcn_s_barrier();   // tile `cur` resident in LDS for all waves
    compute(cur);
    __builtin_amdgcn_s_barrier();   // all reads done before next overwrite
    cur ^= 1;
  }

  const size_t rowbase = ((size_t)tcn * 16 + bh) * S;
#pragma unroll
  for (int p = 0; p < 2; ++p)
#pragma unroll
    for (int j = 0; j < 4; ++j) {
      float s = lsum[p][j];
      s += __shfl_xor(s, 1);
      s += __shfl_xor(s, 2);
      s += __shfl_xor(s, 4);
      s += __shfl_xor(s, 8);
      const int row = qt * 64 + w * 16 + lg * 4 + j;
      if (lc == 0)
        lsumPart[(rowbase + row) * 2 + p] = s;
#pragma unroll
      for (int ef = 0; ef < 8; ++ef)
        Opart[(rowbase + row) * 256 + p * 128 + ef * 16 + lc] = O[p][ef][j];
    }
}

// ---------------------------------------------------------------------------
// Combine t-chunk partials: normalize, lambda-diff, headwise GroupNorm, *0.2.
// ---------------------------------------------------------------------------
__global__ __launch_bounds__(256)
void attn_reduce(const float* __restrict__ Opart, const float* __restrict__ lsumPart,
                 const float* __restrict__ lam,
                 const float* __restrict__ gn_w, const float* __restrict__ gn_b,
                 unsigned short* __restrict__ o) {
  constexpr int S = 2048;
  const int gw = (blockIdx.x * 256 + threadIdx.x) >> 6;
  const int ln = threadIdx.x & 63;
  const int bh = gw >> 11, s = gw & 2047;
  const int b = bh >> 3, h = bh & 7;
  const size_t r0 = ((size_t)bh * S + s) * 256;
  const size_t r1 = (((size_t)16 + bh) * S + s) * 256;
  const int e = ln * 2;
  const float2 o1a = *(const float2*)&Opart[r0 + e];
  const float2 o1b = *(const float2*)&Opart[r1 + e];
  const float2 o2a = *(const float2*)&Opart[r0 + 128 + e];
  const float2 o2b = *(const float2*)&Opart[r1 + 128 + e];
  const size_t l0 = ((size_t)bh * S + s) * 2;
  const size_t l1 = (((size_t)16 + bh) * S + s) * 2;
  const float inv1 = 1.f / (lsumPart[l0] + lsumPart[l1]);
  const float inv2 = lam[h] / (lsumPart[l0 + 1] + lsumPart[l1 + 1]);
  float d0 = (o1a.x + o1b.x) * inv1 - (o2a.x + o2b.x) * inv2;
  float d1 = (o1a.y + o1b.y) * inv1 - (o2a.y + o2b.y) * inv2;
  float sum = d0 + d1, sq = d0 * d0 + d1 * d1;
#pragma unroll
  for (int off = 32; off; off >>= 1) {
    sum += __shfl_xor(sum, off);
    sq += __shfl_xor(sq, off);
  }
  const float mean = sum * (1.f / 128.f);
  const float var = sq * (1.f / 128.f) - mean * mean;
  const float rstd = rsqrtf(var + 1e-5f);
  const float v0 = ((d0 - mean) * rstd * gn_w[h * 128 + e] + gn_b[h * 128 + e]) * 0.2f;
  const float v1 = ((d1 - mean) * rstd * gn_w[h * 128 + e + 1] + gn_b[h * 128 + e + 1]) * 0.2f;
  ushort2 ov;
  ov.x = f2bf(v0);
  ov.y = f2bf(v1);
  *(ushort2*)&o[(size_t)b * S * 1024 + (size_t)s * 1024 + h * 128 + e] = ov;
}

// ---------------------------------------------------------------------------
extern "C" void kernel_launch(void* const* d_in, const int* in_sizes, int n_in,
                              void* d_out, int out_size, void* d_ws, size_t ws_size,
                              hipStream_t stream) {
  (void)in_sizes; (void)n_in; (void)out_size; (void)ws_size;
  const float* x    = (const float*)d_in[0];
  const float* ln1g = (const float*)d_in[1];
  const float* ln1b = (const float*)d_in[2];
  const float* ln2g = (const float*)d_in[3];
  const float* ln2b = (const float*)d_in[4];
  const float* Wq   = (const float*)d_in[5];
  const float* bq   = (const float*)d_in[6];
  const float* Wk   = (const float*)d_in[7];
  const float* bk   = (const float*)d_in[8];
  const float* Wv   = (const float*)d_in[9];
  const float* bv   = (const float*)d_in[10];
  const float* Wo   = (const float*)d_in[11];
  const float* bo   = (const float*)d_in[12];
  const float* lq1  = (const float*)d_in[13];
  const float* lk1  = (const float*)d_in[14];
  const float* lq2  = (const float*)d_in[15];
  const float* lk2  = (const float*)d_in[16];
  const float* gnw  = (const float*)d_in[17];
  const float* gnb  = (const float*)d_in[18];
  const float* W1   = (const float*)d_in[19];
  const float* b1   = (const float*)d_in[20];
  const float* Wg   = (const float*)d_in[21];
  const float* bg   = (const float*)d_in[22];
  const float* W2   = (const float*)d_in[23];
  const float* b2   = (const float*)d_in[24];

  const int B = 2, S = 2048, D = 1024, F = 4096;
  const int M = B * S;  // 4096
  const float qscale = 0.125f;

  char* ws = (char*)d_ws;
  size_t off = 0;
  auto alloc = [&](size_t bytes) {
    char* p = ws + off;
    off += (bytes + 255) & ~(size_t)255;
    return p;
  };
  unsigned short* WqkvT = (unsigned short*)alloc((size_t)3 * D * D * 2);
  unsigned short* WoT = (unsigned short*)alloc((size_t)D * D * 2);
  unsigned short* W1T = (unsigned short*)alloc((size_t)F * D * 2);
  unsigned short* WgT = (unsigned short*)alloc((size_t)F * F * 2);
  unsigned short* W2T = (unsigned short*)alloc((size_t)D * F * 2);
  float*          lamw= (float*)alloc(256);
  float*          bqkv= (float*)alloc(3072 * 4);
  unsigned short* h_bf= (unsigned short*)alloc((size_t)M * D * 2);
  unsigned short* qkv = (unsigned short*)alloc((size_t)M * 3 * D * 2);
  unsigned short* o_bf= (unsigned short*)alloc((size_t)M * D * 2);
  float*          x1  = (float*)alloc((size_t)M * D * 4);
  float*          x2  = (float*)alloc((size_t)M * D * 4);
  unsigned short* x2b = (unsigned short*)alloc((size_t)M * D * 2);
  unsigned short* u_bf= (unsigned short*)alloc((size_t)M * F * 2);
  float*          lsumP = (float*)alloc((size_t)2 * 16 * S * 2 * 4);
  unsigned short* w_bf= h_bf;

  float* Opart = (float*)x1;
  unsigned short* VT = u_bf + (size_t)12 * 1024 * 1024;

  // --- weight prep ---
  transpose_cvt<<<dim3(D / 64, D / 64), 256, 0, stream>>>(Wq, WqkvT, D, D, qscale);
  transpose_cvt<<<dim3(D / 64, D / 64), 256, 0, stream>>>(Wk, WqkvT + (size_t)D * D, D, D, 1.0f);
  transpose_cvt<<<dim3(D / 64, D / 64), 256, 0, stream>>>(Wv, WqkvT + (size_t)2 * D * D, D, D, 1.0f);
  transpose_cvt<<<dim3(D / 64, D / 64), 256, 0, stream>>>(Wo, WoT, D, D, 1.0f);
  transpose_cvt<<<dim3(F / 64, D / 64), 256, 0, stream>>>(W1, W1T, D, F, 1.0f);
  transpose_cvt<<<dim3(F / 64, F / 64), 256, 0, stream>>>(Wg, WgT, F, F, 1.0f);
  transpose_cvt<<<dim3(D / 64, F / 64), 256, 0, stream>>>(W2, W2T, F, D, 1.0f);
  prep_bias<<<12, 256, 0, stream>>>(bq, bk, bv, bqkv, qscale);
  lam_kernel<<<1, 512, 0, stream>>>(lq1, lk1, lq2, lk2, lamw);

  // --- attention sublayer ---
  ln_kernel<0><<<M, 256, 0, stream>>>(x, ln1g, ln1b, h_bf, nullptr);
  gemm256<0><<<dim3(3 * D / 256, M / 256), 512, 0, stream>>>(h_bf, WqkvT, bqkv, nullptr, qkv, M, 3 * D, D);
  v_transpose<<<dim3(S / 64, 2, 16), 256, 0, stream>>>(qkv + 2048, VT);
  attn_kernel<<<dim3(1024), 256, 0, stream>>>(qkv, qkv + 1024, VT, Opart, lsumP);
  attn_reduce<<<dim3(8192), 256, 0, stream>>>(Opart, lsumP, lamw, gnw, gnb, o_bf);
  gemm_bf16<1><<<dim3(D / 128, M / 128), 256, 0, stream>>>(o_bf, WoT, bo, x, nullptr, x1, M, D, D, 1.0f);

  // --- FFN sublayer ---
  ln_kernel<1><<<M, 256, 0, stream>>>(x1, ln2g, ln2b, x2b, x2);
  gemm256<0><<<dim3(F / 256, M / 256), 512, 0, stream>>>(x2b, W1T, b1, nullptr, u_bf, M, F, D);
  gemm256<2><<<dim3(F / 256, M / 256), 512, 0, stream>>>(u_bf, WgT, bg, u_bf, w_bf, M, F, F);
  gemm_bf16<1><<<dim3(D / 128, M / 128), 256, 0, stream>>>(w_bf, W2T, b2, x2, nullptr, (float*)d_out, M, D, F, 1.0f);
}

// Round 11
// 464.399 us; speedup vs baseline: 1.8921x; 1.0300x over previous
//
#include <hip/hip_runtime.h>
#include <hip/hip_bf16.h>

// ---------------------------------------------------------------------------
// EncoderBlock (differential attention + swiGLU FFN), MI355X / gfx950
// R10: (1) K packed contiguous per (b,h) (KP) — the fused-qkv 6144B row
//      stride folded K onto 128 L2 sets (32 lines/16-way set = thrash);
//      attn staged-load waits were L3-latency-bound. KP overlays o_bf.
//      (2) W2/Wo on a 128x64-tile GEMM: 512 blocks (2/CU, was 1/CU) +
//      T2 XOR swizzle (was 8-way bank conflict, 1.7e7 cycles measured).
// ---------------------------------------------------------------------------

typedef __attribute__((ext_vector_type(8))) __bf16 bf16x8;
typedef __attribute__((ext_vector_type(4))) float f32x4;

#define GAS __attribute__((address_space(1)))
#define LAS __attribute__((address_space(3)))

__device__ __forceinline__ unsigned short f2bf(float f) {
  unsigned u = __float_as_uint(f);
  u += 0x7fffu + ((u >> 16) & 1u);   // RNE
  return (unsigned short)(u >> 16);
}
__device__ __forceinline__ float bf2f(unsigned short s) {
  return __uint_as_float(((unsigned)s) << 16);
}

// ---------------------------------------------------------------------------
// Transpose + convert: W[K][N] fp32 -> WT[N][K] bf16 * scale.
// ---------------------------------------------------------------------------
__global__ __launch_bounds__(256)
void transpose_cvt(const float* __restrict__ W, unsigned short* __restrict__ WT,
                   int K, int N, float scale) {
  __shared__ float tile[64][65];
  const int n0 = blockIdx.x * 64, k0 = blockIdx.y * 64;
  const int tr = threadIdx.x >> 4, tc = (threadIdx.x & 15) * 4;
#pragma unroll
  for (int i = 0; i < 4; ++i) {
    const float4 v = *(const float4*)&W[(size_t)(k0 + tr + i * 16) * N + n0 + tc];
    tile[tr + i * 16][tc + 0] = v.x;
    tile[tr + i * 16][tc + 1] = v.y;
    tile[tr + i * 16][tc + 2] = v.z;
    tile[tr + i * 16][tc + 3] = v.w;
  }
  __syncthreads();
#pragma unroll
  for (int i = 0; i < 4; ++i) {
    const int n = tr + i * 16;
    ushort4 o;
    o.x = f2bf(tile[tc + 0][n] * scale);
    o.y = f2bf(tile[tc + 1][n] * scale);
    o.z = f2bf(tile[tc + 2][n] * scale);
    o.w = f2bf(tile[tc + 3][n] * scale);
    *(ushort4*)&WT[(size_t)(n0 + n) * K + k0 + tc] = o;
  }
}

// ---------------------------------------------------------------------------
// Combined qkv bias: [0,1024)=bq*s, [1024,2048)=bk, [2048,3072)=bv.
// ---------------------------------------------------------------------------
__global__ void prep_bias(const float* __restrict__ bq, const float* __restrict__ bk,
                          const float* __restrict__ bv, float* __restrict__ out,
                          float qscale) {
  const int i = blockIdx.x * 256 + threadIdx.x;
  if (i < 1024) out[i] = bq[i] * qscale;
  else if (i < 2048) out[i] = bk[i - 1024];
  else out[i] = bv[i - 2048];
}

// ---------------------------------------------------------------------------
// K pack: qkv[b,s,1024+h*128+e] -> KP[(b*8+h)*2048 + s][e] (contiguous).
// grid(128, 16): x = s-block of 16 rows, y = bh. 16B per thread.
// ---------------------------------------------------------------------------
__global__ __launch_bounds__(256)
void k_pack(const unsigned short* __restrict__ qkv, unsigned short* __restrict__ KP) {
  const int bh = blockIdx.y, b = bh >> 3, h = bh & 7;
  const int s0 = blockIdx.x * 16;
  const int sl = threadIdx.x >> 4, e8 = (threadIdx.x & 15) * 8;
  const size_t src = (size_t)b * 2048 * 3072 + (size_t)(s0 + sl) * 3072 + 1024 + h * 128 + e8;
  const size_t dst = ((size_t)bh * 2048 + s0 + sl) * 128 + e8;
  *(uint4*)&KP[dst] = *(const uint4*)&qkv[src];
}

// ---------------------------------------------------------------------------
// V transpose (bf16): qkv[b,s,2048+h*128+e] -> VT[(b*8+h)*128+e][S].
// ---------------------------------------------------------------------------
__global__ __launch_bounds__(256)
void v_transpose(const unsigned short* __restrict__ v, unsigned short* __restrict__ VT) {
  __shared__ unsigned short tile[64][65];
  const int s0 = blockIdx.x * 64, e0 = blockIdx.y * 64, bh = blockIdx.z;
  const int b = bh >> 3, h = bh & 7;
  const int tr = threadIdx.x >> 4, tc = (threadIdx.x & 15) * 4;
  const size_t inbase = (size_t)b * 2048 * 3072 + h * 128;
#pragma unroll
  for (int i = 0; i < 4; ++i) {
    const int r = tr + i * 16;
    const ushort4 val = *(const ushort4*)&v[inbase + (size_t)(s0 + r) * 3072 + e0 + tc];
    tile[r][tc + 0] = val.x;
    tile[r][tc + 1] = val.y;
    tile[r][tc + 2] = val.z;
    tile[r][tc + 3] = val.w;
  }
  __syncthreads();
#pragma unroll
  for (int i = 0; i < 4; ++i) {
    const int n = tr + i * 16;
    ushort4 oo;
    oo.x = tile[tc + 0][n];
    oo.y = tile[tc + 1][n];
    oo.z = tile[tc + 2][n];
    oo.w = tile[tc + 3][n];
    *(ushort4*)&VT[(size_t)(bh * 128 + e0 + n) * 2048 + s0 + tc] = oo;
  }
}

// ---------------------------------------------------------------------------
// lambda[h]
// ---------------------------------------------------------------------------
__global__ void lam_kernel(const float* __restrict__ lq1, const float* __restrict__ lk1,
                           const float* __restrict__ lq2, const float* __restrict__ lk2,
                           float* __restrict__ lam) {
  const int w = threadIdx.x >> 6, d = threadIdx.x & 63;
  float a = lq1[w * 64 + d] * lk1[w * 64 + d];
  float c = lq2[w * 64 + d] * lk2[w * 64 + d];
#pragma unroll
  for (int off = 32; off; off >>= 1) {
    a += __shfl_xor(a, off);
    c += __shfl_xor(c, off);
  }
  if (d == 0) lam[w] = __expf(a) - __expf(c) + 0.8f;
}

// ---------------------------------------------------------------------------
// LayerNorm over rows of 1024.
// ---------------------------------------------------------------------------
template <int WRITE_F32>
__global__ __launch_bounds__(256)
void ln_kernel(const float* __restrict__ x, const float* __restrict__ g,
               const float* __restrict__ bsh, unsigned short* __restrict__ obf,
               float* __restrict__ of32) {
  __shared__ float red[16];
  const int row = blockIdx.x, tid = threadIdx.x;
  const float4 v = *(const float4*)&x[(size_t)row * 1024 + tid * 4];
  float s = v.x + v.y + v.z + v.w;
  float q = v.x * v.x + v.y * v.y + v.z * v.z + v.w * v.w;
#pragma unroll
  for (int off = 32; off; off >>= 1) {
    s += __shfl_xor(s, off);
    q += __shfl_xor(q, off);
  }
  if ((tid & 63) == 0) {
    red[tid >> 6] = s;
    red[8 + (tid >> 6)] = q;
  }
  __syncthreads();
  s = red[0] + red[1] + red[2] + red[3];
  q = red[8] + red[9] + red[10] + red[11];
  const float mean = s * (1.f / 1024.f);
  const float var = q * (1.f / 1024.f) - mean * mean;
  const float rstd = rsqrtf(var + 1e-5f);
  const float4 gg = *(const float4*)&g[tid * 4];
  const float4 bb = *(const float4*)&bsh[tid * 4];
  float y0 = (v.x - mean) * rstd * gg.x + bb.x;
  float y1 = (v.y - mean) * rstd * gg.y + bb.y;
  float y2 = (v.z - mean) * rstd * gg.z + bb.z;
  float y3 = (v.w - mean) * rstd * gg.w + bb.w;
  const size_t base = (size_t)row * 1024 + tid * 4;
  ushort4 o;
  o.x = f2bf(y0); o.y = f2bf(y1); o.z = f2bf(y2); o.w = f2bf(y3);
  *(ushort4*)&obf[base] = o;
  if (WRITE_F32) {
    *(float4*)&of32[base] = make_float4(y0, y1, y2, y3);
  }
}

// ---------------------------------------------------------------------------
// GEMM 128x64 tile, 4 waves (2Mx2N, wave tile 64x32), BK=32, double-buffered,
// counted vmcnt(3), T2 XOR swizzle byte^=(r&3)<<4 (pre-swizzled source).
// For the N=1024 GEMMs (Wo, W2): grid 16x32 = 512 blocks -> 2 blocks/CU.
// EPI 1: fp32 out = res + acc + bias.
// ---------------------------------------------------------------------------
template <int EPI>
__global__ __launch_bounds__(256)
void gemm_n64(const unsigned short* __restrict__ A,
              const unsigned short* __restrict__ BT,
              const float* __restrict__ bias,
              const float* __restrict__ res,
              void* __restrict__ Cout, int M, int N, int K, float bscale) {
  __shared__ unsigned short ldsA[2][128 * 32];
  __shared__ unsigned short ldsB[2][64 * 32];
  const int tid = threadIdx.x;
  const int wv = tid >> 6, ln = tid & 63, lg = ln >> 4, lc = ln & 15;
  const int wm = wv >> 1, wn = wv & 1;
  const int nwg = gridDim.x * gridDim.y;
  const int linear = blockIdx.y * gridDim.x + blockIdx.x;
  const int swz = (linear & 7) * (nwg >> 3) + (linear >> 3);
  const int m0 = (swz / gridDim.x) * 128, n0 = (swz % gridDim.x) * 64;
  const int rsub = ln >> 2;
  // pre-swizzled source column offset (bytes within the 64B row)
  const int sw_inner = ((ln & 3) * 16) ^ ((rsub & 3) << 4);
  const int acol = sw_inner >> 1;   // in shorts

  f32x4 acc[4][2];
#pragma unroll
  for (int i = 0; i < 4; ++i)
#pragma unroll
    for (int j = 0; j < 2; ++j) acc[i][j] = (f32x4)0.f;

  auto stage = [&](int buf, int k0) {
#pragma unroll
    for (int j = 0; j < 2; ++j) {
      const int rowblk = wv * 32 + j * 16;
      const unsigned short* ga = A + (size_t)(m0 + rowblk + rsub) * K + (k0 + acol);
      __builtin_amdgcn_global_load_lds((GAS void*)ga,
          (LAS void*)&ldsA[buf][rowblk * 32], 16, 0, 0);
    }
    const unsigned short* gb = BT + (size_t)(n0 + wv * 16 + rsub) * K + (k0 + acol);
    __builtin_amdgcn_global_load_lds((GAS void*)gb,
        (LAS void*)&ldsB[buf][wv * 16 * 32], 16, 0, 0);
  };

  const int nk = K / 32;
  stage(0, 0);
  int cur = 0;
  for (int i = 0; i < nk; ++i) {
    if (i + 1 < nk) {
      stage(cur ^ 1, (i + 1) * 32);
      asm volatile("s_waitcnt vmcnt(3)" ::: "memory");
    } else {
      asm volatile("s_waitcnt vmcnt(0)" ::: "memory");
    }
    __builtin_amdgcn_s_barrier();
    bf16x8 af[4], bf[2];
#pragma unroll
    for (int m = 0; m < 4; ++m) {
      const int r = wm * 64 + m * 16 + lc;
      af[m] = *(const bf16x8*)((const char*)&ldsA[cur][0] + r * 64 +
                               ((lg * 16) ^ ((r & 3) << 4)));
    }
#pragma unroll
    for (int n = 0; n < 2; ++n) {
      const int r = wn * 32 + n * 16 + lc;
      bf[n] = *(const bf16x8*)((const char*)&ldsB[cur][0] + r * 64 +
                               ((lg * 16) ^ ((r & 3) << 4)));
    }
    __builtin_amdgcn_s_setprio(1);
#pragma unroll
    for (int m = 0; m < 4; ++m)
#pragma unroll
      for (int n = 0; n < 2; ++n)
        acc[m][n] = __builtin_amdgcn_mfma_f32_16x16x32_bf16(af[m], bf[n], acc[m][n], 0, 0, 0);
    __builtin_amdgcn_s_setprio(0);
    __builtin_amdgcn_s_barrier();
    cur ^= 1;
  }

#pragma unroll
  for (int m = 0; m < 4; ++m) {
#pragma unroll
    for (int n = 0; n < 2; ++n) {
      const int c = n0 + wn * 32 + n * 16 + lc;
      const float bc = bias[c] * bscale;
#pragma unroll
      for (int j = 0; j < 4; ++j) {
        const int r = m0 + wm * 64 + m * 16 + lg * 4 + j;
        const size_t idx = (size_t)r * N + c;
        const float v = acc[m][n][j] + bc;
        if (EPI == 1) {
          ((float*)Cout)[idx] = res[idx] + v;
        } else {
          ((unsigned short*)Cout)[idx] = f2bf(v);
        }
      }
    }
  }
}

// ---------------------------------------------------------------------------
// GEMM 256x256, 8-wave, BK=64, 8-phase deep pipeline (m201 template).
// ---------------------------------------------------------------------------
template <int EPI>
__global__ __launch_bounds__(512)
void gemm256(const unsigned short* __restrict__ A,
             const unsigned short* __restrict__ BT,
             const float* __restrict__ bias,
             const unsigned short* __restrict__ gate_u,
             unsigned short* __restrict__ Cout, int M, int N, int K) {
  __shared__ unsigned short lds[65536];   // 128 KB = 8 x 16KB slots
  const int tid = threadIdx.x;
  const int w = tid >> 6, ln = tid & 63, lg = ln >> 4, lc = ln & 15;
  const int wm = w >> 2, wn = w & 3;
  const int nwg = gridDim.x * gridDim.y;
  const int linear = blockIdx.y * gridDim.x + blockIdx.x;
  const int swzb = (linear & 7) * (nwg >> 3) + (linear >> 3);
  const int m0 = (swzb / gridDim.x) * 256, n0 = (swzb % gridDim.x) * 256;

  f32x4 acc[8][4];
#pragma unroll
  for (int i = 0; i < 8; ++i)
#pragma unroll
    for (int j = 0; j < 4; ++j) acc[i][j] = (f32x4)0.f;

  auto stage_half = [&](int tensor, int j, int hh) {
    const unsigned short* base = tensor ? BT : A;
    const int row0 = (tensor ? n0 : m0) + hh * 128;
    const int slot = tensor * 4 + (j & 1) * 2 + hh;
#pragma unroll
    for (int c = 0; c < 2; ++c) {
      const int chunk = w * 2 + c;
      const int L = chunk * 1024 + ln * 16;
      const int r = L >> 7, inner = L & 127;
      const char* src = (const char*)(base + (size_t)(row0 + r) * K + j * 64) +
                        (inner ^ ((r & 7) << 4));
      __builtin_amdgcn_global_load_lds((GAS void*)src,
          (LAS void*)((char*)lds + slot * 16384 + chunk * 1024), 16, 0, 0);
    }
  };
  auto read_a = [&](int j, int mf, int ks) -> bf16x8 {
    const int r = mf * 16 + lc;
    const int slot = (j & 1) * 2 + wm;
    const int cb = ks * 64 + lg * 16;
    return *(const bf16x8*)((const char*)lds + slot * 16384 + r * 128 +
                            (cb ^ ((r & 7) << 4)));
  };
  auto read_b = [&](int j, int nf, int ks) -> bf16x8 {
    const int R = wn * 64 + nf * 16 + lc;
    const int slot = 4 + (j & 1) * 2 + (R >> 7);
    const int r = R & 127;
    const int cb = ks * 64 + lg * 16;
    return *(const bf16x8*)((const char*)lds + slot * 16384 + r * 128 +
                            (cb ^ ((r & 7) << 4)));
  };

  const int nkt = K / 64;

  stage_half(0, 0, 0); stage_half(0, 0, 1);
  stage_half(1, 0, 0); stage_half(1, 0, 1);
  stage_half(1, 1, 0); stage_half(1, 1, 1);
  asm volatile("s_waitcnt vmcnt(0)" ::: "memory");
  __builtin_amdgcn_s_barrier();

  bf16x8 bfr[4][2];
  for (int it = 0; it < nkt / 2; ++it) {
    const int J = it * 2;
#pragma unroll
    for (int half = 0; half < 2; ++half) {
      const int jc = J + half;
#pragma unroll
      for (int q = 0; q < 4; ++q) {
        if (q == 0) {
#pragma unroll
          for (int nf = 0; nf < 4; ++nf)
#pragma unroll
            for (int ks = 0; ks < 2; ++ks) bfr[nf][ks] = read_b(jc, nf, ks);
        }
        bf16x8 afr[2][2];
#pragma unroll
        for (int mm = 0; mm < 2; ++mm)
#pragma unroll
          for (int ks = 0; ks < 2; ++ks) afr[mm][ks] = read_a(jc, q * 2 + mm, ks);
        if (half == 0) {
          if (q == 0) stage_half(0, J + 1, 0);
          if (q == 1) stage_half(0, J + 1, 1);
          if (q == 2 && J + 2 < nkt) stage_half(1, J + 2, 0);
          if (q == 3 && J + 2 < nkt) stage_half(1, J + 2, 1);
        } else {
          if (q == 0 && J + 2 < nkt) stage_half(0, J + 2, 0);
          if (q == 1 && J + 2 < nkt) stage_half(0, J + 2, 1);
          if (q == 2 && J + 3 < nkt) stage_half(1, J + 3, 0);
          if (q == 3 && J + 3 < nkt) stage_half(1, J + 3, 1);
        }
        if (q == 0) asm volatile("s_waitcnt lgkmcnt(8)" ::: "memory");
        if (q == 3) asm volatile("s_waitcnt vmcnt(4)" ::: "memory");
        __builtin_amdgcn_s_barrier();
        __builtin_amdgcn_s_setprio(1);
#pragma unroll
        for (int mm = 0; mm < 2; ++mm)
#pragma unroll
          for (int nf = 0; nf < 4; ++nf)
#pragma unroll
            for (int ks = 0; ks < 2; ++ks)
              acc[q * 2 + mm][nf] = __builtin_amdgcn_mfma_f32_16x16x32_bf16(
                  afr[mm][ks], bfr[nf][ks], acc[q * 2 + mm][nf], 0, 0, 0);
        __builtin_amdgcn_s_setprio(0);
        __builtin_amdgcn_s_barrier();
      }
    }
  }

#pragma unroll
  for (int mf = 0; mf < 8; ++mf) {
#pragma unroll
    for (int nf = 0; nf < 4; ++nf) {
      const int c = n0 + wn * 64 + nf * 16 + lc;
      const float bc = bias[c];
#pragma unroll
      for (int jj = 0; jj < 4; ++jj) {
        const int r = m0 + wm * 128 + mf * 16 + lg * 4 + jj;
        const size_t idx = (size_t)r * N + c;
        const float v = acc[mf][nf][jj] + bc;
        if (EPI == 0) {
          Cout[idx] = f2bf(v);
        } else {
          const float uu = bf2f(gate_u[idx]);
          const float sw = v / (1.f + __expf(-v));   // silu
          Cout[idx] = f2bf(uu * sw);
        }
      }
    }
  }
}

// ---------------------------------------------------------------------------
// Differential attention partials: LDS-staged K/V (K from packed KP),
// double buffer, counted vmcnt(4). t-split NT=2.
// ---------------------------------------------------------------------------
__global__ __launch_bounds__(256)
void attn_kernel(const unsigned short* __restrict__ q,
                 const unsigned short* __restrict__ KP,
                 const unsigned short* __restrict__ VT,
                 float* __restrict__ Opart,
                 float* __restrict__ lsumPart) {
  constexpr int S = 2048;
  constexpr int QS = 3072;
  __shared__ unsigned short k_tile[2][32 * 128];
  __shared__ unsigned short v_tile[2][128 * 32];
  __shared__ unsigned short p_lds[4][2][512];
  const int tid = threadIdx.x, w = tid >> 6, ln = tid & 63, lg = ln >> 4, lc = ln & 15;
  const int id = blockIdx.x;
  const int bh = (id & 7) + 8 * ((id >> 9) & 1);
  const int qt = (id >> 3) & 31;
  const int tcn = (id >> 8) & 1;
  const size_t chan = (size_t)(bh >> 3) * S * QS + (bh & 7) * 128;
  const size_t kpbase = (size_t)bh * S * 128;
  const size_t vtbase = (size_t)bh * 128 * S;
  const int qrow = qt * 64 + w * 16 + lc;

  bf16x8 qf[2][2];
#pragma unroll
  for (int p = 0; p < 2; ++p)
#pragma unroll
    for (int ks = 0; ks < 2; ++ks)
      qf[p][ks] = *(const bf16x8*)&q[chan + (size_t)qrow * QS + p * 64 + ks * 32 + lg * 8];

  f32x4 O[2][8];
#pragma unroll
  for (int p = 0; p < 2; ++p)
#pragma unroll
    for (int ef = 0; ef < 8; ++ef) O[p][ef] = (f32x4)0.f;
  float lsum[2][4];
#pragma unroll
  for (int p = 0; p < 2; ++p)
#pragma unroll
    for (int j = 0; j < 4; ++j) lsum[p][j] = 0.f;

  const int prd = ((lc * 64 + lg * 16) ^ ((lc & 7) << 4)) >> 1;

  auto stage = [&](int buf, int t0) {
#pragma unroll
    for (int c = 0; c < 2; ++c) {
      {
        const int L = (w * 2 + c) * 1024 + ln * 16;
        const int r = L >> 8, inner = L & 255;
        const char* src = (const char*)(KP + kpbase + (size_t)(t0 + r) * 128) +
                          (inner ^ ((r & 7) << 4));
        __builtin_amdgcn_global_load_lds((GAS void*)src,
            (LAS void*)((char*)&k_tile[buf][0] + (w * 2 + c) * 1024), 16, 0, 0);
      }
      {
        const int L = (w * 2 + c) * 1024 + ln * 16;
        const int e = L >> 6, inner = L & 63;
        const char* src = (const char*)(VT + vtbase + (size_t)e * S + t0) +
                          (inner ^ ((e & 3) << 4));
        __builtin_amdgcn_global_load_lds((GAS void*)src,
            (LAS void*)((char*)&v_tile[buf][0] + (w * 2 + c) * 1024), 16, 0, 0);
      }
    }
  };

  auto compute = [&](int buf) {
    const char* kb = (const char*)&k_tile[buf][0];
    const char* vb = (const char*)&v_tile[buf][0];
    bf16x8 vf[8];
#pragma unroll
    for (int ef = 0; ef < 8; ++ef) {
      const int e = ef * 16 + lc;
      vf[ef] = *(const bf16x8*)(vb + e * 64 + ((lg * 16) ^ ((e & 3) << 4)));
    }
#pragma unroll
    for (int p = 0; p < 2; ++p) {
      bf16x8 kf[2][2];
#pragma unroll
      for (int tf = 0; tf < 2; ++tf) {
        const int r = tf * 16 + lc;
#pragma unroll
        for (int ks = 0; ks < 2; ++ks)
          kf[tf][ks] = *(const bf16x8*)(kb + r * 256 +
                          ((p * 128 + ks * 64 + lg * 16) ^ ((r & 7) << 4)));
      }
      f32x4 sfr[2];
      __builtin_amdgcn_s_setprio(1);
#pragma unroll
      for (int tf = 0; tf < 2; ++tf) {
        f32x4 acc = (f32x4)0.f;
#pragma unroll
        for (int ks = 0; ks < 2; ++ks)
          acc = __builtin_amdgcn_mfma_f32_16x16x32_bf16(qf[p][ks], kf[tf][ks], acc, 0, 0, 0);
        sfr[tf] = acc;
      }
      __builtin_amdgcn_s_setprio(0);

#pragma unroll
      for (int tf = 0; tf < 2; ++tf)
#pragma unroll
        for (int j = 0; j < 4; ++j) {
          const float e = __expf(sfr[tf][j]);
          lsum[p][j] += e;
          const int qq = lg * 4 + j;
          const int wi = ((qq * 64 + (tf * 16 + lc) * 2) ^ ((qq & 7) << 4)) >> 1;
          p_lds[w][p][wi] = f2bf(e);
        }

      const bf16x8 pa = *(const bf16x8*)&p_lds[w][p][prd];
      __builtin_amdgcn_s_setprio(1);
#pragma unroll
      for (int ef = 0; ef < 8; ++ef)
        O[p][ef] = __builtin_amdgcn_mfma_f32_16x16x32_bf16(pa, vf[ef], O[p][ef], 0, 0, 0);
      __builtin_amdgcn_s_setprio(0);
    }
  };

  const int tbeg = tcn * (S / 2);
  stage(0, tbeg);
  int cur = 0;
  for (int it = 0; it < 32; ++it) {
    if (it < 31) {
      stage(cur ^ 1, tbeg + (it + 1) * 32);
      asm volatile("s_waitcnt vmcnt(4)" ::: "memory");
    } else {
      asm volatile("s_waitcnt vmcnt(0)" ::: "memory");
    }
    __builtin_amdgcn_s_barrier();
    compute(cur);
    __builtin_amdgcn_s_barrier();
    cur ^= 1;
  }

  const size_t rowbase = ((size_t)tcn * 16 + bh) * S;
#pragma unroll
  for (int p = 0; p < 2; ++p)
#pragma unroll
    for (int j = 0; j < 4; ++j) {
      float s = lsum[p][j];
      s += __shfl_xor(s, 1);
      s += __shfl_xor(s, 2);
      s += __shfl_xor(s, 4);
      s += __shfl_xor(s, 8);
      const int row = qt * 64 + w * 16 + lg * 4 + j;
      if (lc == 0)
        lsumPart[(rowbase + row) * 2 + p] = s;
#pragma unroll
      for (int ef = 0; ef < 8; ++ef)
        Opart[(rowbase + row) * 256 + p * 128 + ef * 16 + lc] = O[p][ef][j];
    }
}

// ---------------------------------------------------------------------------
// Combine t-chunk partials: normalize, lambda-diff, headwise GroupNorm, *0.2.
// ---------------------------------------------------------------------------
__global__ __launch_bounds__(256)
void attn_reduce(const float* __restrict__ Opart, const float* __restrict__ lsumPart,
                 const float* __restrict__ lam,
                 const float* __restrict__ gn_w, const float* __restrict__ gn_b,
                 unsigned short* __restrict__ o) {
  constexpr int S = 2048;
  const int gw = (blockIdx.x * 256 + threadIdx.x) >> 6;
  const int ln = threadIdx.x & 63;
  const int bh = gw >> 11, s = gw & 2047;
  const int b = bh >> 3, h = bh & 7;
  const size_t r0 = ((size_t)bh * S + s) * 256;
  const size_t r1 = (((size_t)16 + bh) * S + s) * 256;
  const int e = ln * 2;
  const float2 o1a = *(const float2*)&Opart[r0 + e];
  const float2 o1b = *(const float2*)&Opart[r1 + e];
  const float2 o2a = *(const float2*)&Opart[r0 + 128 + e];
  const float2 o2b = *(const float2*)&Opart[r1 + 128 + e];
  const size_t l0 = ((size_t)bh * S + s) * 2;
  const size_t l1 = (((size_t)16 + bh) * S + s) * 2;
  const float inv1 = 1.f / (lsumPart[l0] + lsumPart[l1]);
  const float inv2 = lam[h] / (lsumPart[l0 + 1] + lsumPart[l1 + 1]);
  float d0 = (o1a.x + o1b.x) * inv1 - (o2a.x + o2b.x) * inv2;
  float d1 = (o1a.y + o1b.y) * inv1 - (o2a.y + o2b.y) * inv2;
  float sum = d0 + d1, sq = d0 * d0 + d1 * d1;
#pragma unroll
  for (int off = 32; off; off >>= 1) {
    sum += __shfl_xor(sum, off);
    sq += __shfl_xor(sq, off);
  }
  const float mean = sum * (1.f / 128.f);
  const float var = sq * (1.f / 128.f) - mean * mean;
  const float rstd = rsqrtf(var + 1e-5f);
  const float v0 = ((d0 - mean) * rstd * gn_w[h * 128 + e] + gn_b[h * 128 + e]) * 0.2f;
  const float v1 = ((d1 - mean) * rstd * gn_w[h * 128 + e + 1] + gn_b[h * 128 + e + 1]) * 0.2f;
  ushort2 ov;
  ov.x = f2bf(v0);
  ov.y = f2bf(v1);
  *(ushort2*)&o[(size_t)b * S * 1024 + (size_t)s * 1024 + h * 128 + e] = ov;
}

// ---------------------------------------------------------------------------
extern "C" void kernel_launch(void* const* d_in, const int* in_sizes, int n_in,
                              void* d_out, int out_size, void* d_ws, size_t ws_size,
                              hipStream_t stream) {
  (void)in_sizes; (void)n_in; (void)out_size; (void)ws_size;
  const float* x    = (const float*)d_in[0];
  const float* ln1g = (const float*)d_in[1];
  const float* ln1b = (const float*)d_in[2];
  const float* ln2g = (const float*)d_in[3];
  const float* ln2b = (const float*)d_in[4];
  const float* Wq   = (const float*)d_in[5];
  const float* bq   = (const float*)d_in[6];
  const float* Wk   = (const float*)d_in[7];
  const float* bk   = (const float*)d_in[8];
  const float* Wv   = (const float*)d_in[9];
  const float* bv   = (const float*)d_in[10];
  const float* Wo   = (const float*)d_in[11];
  const float* bo   = (const float*)d_in[12];
  const float* lq1  = (const float*)d_in[13];
  const float* lk1  = (const float*)d_in[14];
  const float* lq2  = (const float*)d_in[15];
  const float* lk2  = (const float*)d_in[16];
  const float* gnw  = (const float*)d_in[17];
  const float* gnb  = (const float*)d_in[18];
  const float* W1   = (const float*)d_in[19];
  const float* b1   = (const float*)d_in[20];
  const float* Wg   = (const float*)d_in[21];
  const float* bg   = (const float*)d_in[22];
  const float* W2   = (const float*)d_in[23];
  const float* b2   = (const float*)d_in[24];

  const int B = 2, S = 2048, D = 1024, F = 4096;
  const int M = B * S;  // 4096
  const float qscale = 0.125f;

  char* ws = (char*)d_ws;
  size_t off = 0;
  auto alloc = [&](size_t bytes) {
    char* p = ws + off;
    off += (bytes + 255) & ~(size_t)255;
    return p;
  };
  unsigned short* WqkvT = (unsigned short*)alloc((size_t)3 * D * D * 2);
  unsigned short* WoT = (unsigned short*)alloc((size_t)D * D * 2);
  unsigned short* W1T = (unsigned short*)alloc((size_t)F * D * 2);
  unsigned short* WgT = (unsigned short*)alloc((size_t)F * F * 2);
  unsigned short* W2T = (unsigned short*)alloc((size_t)D * F * 2);
  float*          lamw= (float*)alloc(256);
  float*          bqkv= (float*)alloc(3072 * 4);
  unsigned short* h_bf= (unsigned short*)alloc((size_t)M * D * 2);
  unsigned short* qkv = (unsigned short*)alloc((size_t)M * 3 * D * 2);
  unsigned short* o_bf= (unsigned short*)alloc((size_t)M * D * 2);
  float*          x1  = (float*)alloc((size_t)M * D * 4);
  float*          x2  = (float*)alloc((size_t)M * D * 4);
  unsigned short* x2b = (unsigned short*)alloc((size_t)M * D * 2);
  unsigned short* u_bf= (unsigned short*)alloc((size_t)M * F * 2);
  float*          lsumP = (float*)alloc((size_t)2 * 16 * S * 2 * 4);
  unsigned short* w_bf= h_bf;

  // Overlays (all spans dead during their overlay use):
  float* Opart = (float*)x1;                      // 64MB: x1+x2+x2b+u_bf[0:24MB)
  unsigned short* VT = u_bf + (size_t)12 * 1024 * 1024;   // u_bf[24:32MB)
  unsigned short* KP = o_bf;                      // 8MB; o_bf written later by reduce

  // --- weight prep ---
  transpose_cvt<<<dim3(D / 64, D / 64), 256, 0, stream>>>(Wq, WqkvT, D, D, qscale);
  transpose_cvt<<<dim3(D / 64, D / 64), 256, 0, stream>>>(Wk, WqkvT + (size_t)D * D, D, D, 1.0f);
  transpose_cvt<<<dim3(D / 64, D / 64), 256, 0, stream>>>(Wv, WqkvT + (size_t)2 * D * D, D, D, 1.0f);
  transpose_cvt<<<dim3(D / 64, D / 64), 256, 0, stream>>>(Wo, WoT, D, D, 1.0f);
  transpose_cvt<<<dim3(F / 64, D / 64), 256, 0, stream>>>(W1, W1T, D, F, 1.0f);
  transpose_cvt<<<dim3(F / 64, F / 64), 256, 0, stream>>>(Wg, WgT, F, F, 1.0f);
  transpose_cvt<<<dim3(D / 64, F / 64), 256, 0, stream>>>(W2, W2T, F, D, 1.0f);
  prep_bias<<<12, 256, 0, stream>>>(bq, bk, bv, bqkv, qscale);
  lam_kernel<<<1, 512, 0, stream>>>(lq1, lk1, lq2, lk2, lamw);

  // --- attention sublayer ---
  ln_kernel<0><<<M, 256, 0, stream>>>(x, ln1g, ln1b, h_bf, nullptr);
  gemm256<0><<<dim3(3 * D / 256, M / 256), 512, 0, stream>>>(h_bf, WqkvT, bqkv, nullptr, qkv, M, 3 * D, D);
  k_pack<<<dim3(S / 16, 16), 256, 0, stream>>>(qkv, KP);
  v_transpose<<<dim3(S / 64, 2, 16), 256, 0, stream>>>(qkv + 2048, VT);
  attn_kernel<<<dim3(1024), 256, 0, stream>>>(qkv, KP, VT, Opart, lsumP);
  attn_reduce<<<dim3(8192), 256, 0, stream>>>(Opart, lsumP, lamw, gnw, gnb, o_bf);
  gemm_n64<1><<<dim3(D / 64, M / 128), 256, 0, stream>>>(o_bf, WoT, bo, x, x1, M, D, D, 1.0f);

  // --- FFN sublayer ---
  ln_kernel<1><<<M, 256, 0, stream>>>(x1, ln2g, ln2b, x2b, x2);
  gemm256<0><<<dim3(F / 256, M / 256), 512, 0, stream>>>(x2b, W1T, b1, nullptr, u_bf, M, F, D);
  gemm256<2><<<dim3(F / 256, M / 256), 512, 0, stream>>>(u_bf, WgT, bg, u_bf, w_bf, M, F, F);
  gemm_n64<1><<<dim3(D / 64, M / 128), 256, 0, stream>>>(w_bf, W2T, b2, x2, (float*)d_out, M, D, F, 1.0f);
}

// Round 12
// 451.614 us; speedup vs baseline: 1.9456x; 1.0283x over previous
//
#include <hip/hip_runtime.h>
#include <hip/hip_bf16.h>

// ---------------------------------------------------------------------------
// EncoderBlock (differential attention + swiGLU FFN), MI355X / gfx950
// R11: (1) attention NT=1 with FUSED lambda-diff + GroupNorm epilogue —
//      the t-split's 130MB partial round-trip + attn_reduce dispatch were
//      pure overhead once the kernel became LDS-staged (same wave count).
//      (2) gemm256 vmcnt(4) moved after the P4/P8 MFMA cluster (one more
//      cluster of prefetch-latency cover, same barrier safety).
// ---------------------------------------------------------------------------

typedef __attribute__((ext_vector_type(8))) __bf16 bf16x8;
typedef __attribute__((ext_vector_type(4))) float f32x4;

#define GAS __attribute__((address_space(1)))
#define LAS __attribute__((address_space(3)))

__device__ __forceinline__ unsigned short f2bf(float f) {
  unsigned u = __float_as_uint(f);
  u += 0x7fffu + ((u >> 16) & 1u);   // RNE
  return (unsigned short)(u >> 16);
}
__device__ __forceinline__ float bf2f(unsigned short s) {
  return __uint_as_float(((unsigned)s) << 16);
}

// ---------------------------------------------------------------------------
// Transpose + convert: W[K][N] fp32 -> WT[N][K] bf16 * scale.
// ---------------------------------------------------------------------------
__global__ __launch_bounds__(256)
void transpose_cvt(const float* __restrict__ W, unsigned short* __restrict__ WT,
                   int K, int N, float scale) {
  __shared__ float tile[64][65];
  const int n0 = blockIdx.x * 64, k0 = blockIdx.y * 64;
  const int tr = threadIdx.x >> 4, tc = (threadIdx.x & 15) * 4;
#pragma unroll
  for (int i = 0; i < 4; ++i) {
    const float4 v = *(const float4*)&W[(size_t)(k0 + tr + i * 16) * N + n0 + tc];
    tile[tr + i * 16][tc + 0] = v.x;
    tile[tr + i * 16][tc + 1] = v.y;
    tile[tr + i * 16][tc + 2] = v.z;
    tile[tr + i * 16][tc + 3] = v.w;
  }
  __syncthreads();
#pragma unroll
  for (int i = 0; i < 4; ++i) {
    const int n = tr + i * 16;
    ushort4 o;
    o.x = f2bf(tile[tc + 0][n] * scale);
    o.y = f2bf(tile[tc + 1][n] * scale);
    o.z = f2bf(tile[tc + 2][n] * scale);
    o.w = f2bf(tile[tc + 3][n] * scale);
    *(ushort4*)&WT[(size_t)(n0 + n) * K + k0 + tc] = o;
  }
}

// ---------------------------------------------------------------------------
// Combined qkv bias: [0,1024)=bq*s, [1024,2048)=bk, [2048,3072)=bv.
// ---------------------------------------------------------------------------
__global__ void prep_bias(const float* __restrict__ bq, const float* __restrict__ bk,
                          const float* __restrict__ bv, float* __restrict__ out,
                          float qscale) {
  const int i = blockIdx.x * 256 + threadIdx.x;
  if (i < 1024) out[i] = bq[i] * qscale;
  else if (i < 2048) out[i] = bk[i - 1024];
  else out[i] = bv[i - 2048];
}

// ---------------------------------------------------------------------------
// K pack: qkv[b,s,1024+h*128+e] -> KP[(b*8+h)*2048 + s][e] (contiguous).
// ---------------------------------------------------------------------------
__global__ __launch_bounds__(256)
void k_pack(const unsigned short* __restrict__ qkv, unsigned short* __restrict__ KP) {
  const int bh = blockIdx.y, b = bh >> 3, h = bh & 7;
  const int s0 = blockIdx.x * 16;
  const int sl = threadIdx.x >> 4, e8 = (threadIdx.x & 15) * 8;
  const size_t src = (size_t)b * 2048 * 3072 + (size_t)(s0 + sl) * 3072 + 1024 + h * 128 + e8;
  const size_t dst = ((size_t)bh * 2048 + s0 + sl) * 128 + e8;
  *(uint4*)&KP[dst] = *(const uint4*)&qkv[src];
}

// ---------------------------------------------------------------------------
// V transpose (bf16): qkv[b,s,2048+h*128+e] -> VT[(b*8+h)*128+e][S].
// ---------------------------------------------------------------------------
__global__ __launch_bounds__(256)
void v_transpose(const unsigned short* __restrict__ v, unsigned short* __restrict__ VT) {
  __shared__ unsigned short tile[64][65];
  const int s0 = blockIdx.x * 64, e0 = blockIdx.y * 64, bh = blockIdx.z;
  const int b = bh >> 3, h = bh & 7;
  const int tr = threadIdx.x >> 4, tc = (threadIdx.x & 15) * 4;
  const size_t inbase = (size_t)b * 2048 * 3072 + h * 128;
#pragma unroll
  for (int i = 0; i < 4; ++i) {
    const int r = tr + i * 16;
    const ushort4 val = *(const ushort4*)&v[inbase + (size_t)(s0 + r) * 3072 + e0 + tc];
    tile[r][tc + 0] = val.x;
    tile[r][tc + 1] = val.y;
    tile[r][tc + 2] = val.z;
    tile[r][tc + 3] = val.w;
  }
  __syncthreads();
#pragma unroll
  for (int i = 0; i < 4; ++i) {
    const int n = tr + i * 16;
    ushort4 oo;
    oo.x = tile[tc + 0][n];
    oo.y = tile[tc + 1][n];
    oo.z = tile[tc + 2][n];
    oo.w = tile[tc + 3][n];
    *(ushort4*)&VT[(size_t)(bh * 128 + e0 + n) * 2048 + s0 + tc] = oo;
  }
}

// ---------------------------------------------------------------------------
// lambda[h]
// ---------------------------------------------------------------------------
__global__ void lam_kernel(const float* __restrict__ lq1, const float* __restrict__ lk1,
                           const float* __restrict__ lq2, const float* __restrict__ lk2,
                           float* __restrict__ lam) {
  const int w = threadIdx.x >> 6, d = threadIdx.x & 63;
  float a = lq1[w * 64 + d] * lk1[w * 64 + d];
  float c = lq2[w * 64 + d] * lk2[w * 64 + d];
#pragma unroll
  for (int off = 32; off; off >>= 1) {
    a += __shfl_xor(a, off);
    c += __shfl_xor(c, off);
  }
  if (d == 0) lam[w] = __expf(a) - __expf(c) + 0.8f;
}

// ---------------------------------------------------------------------------
// LayerNorm over rows of 1024.
// ---------------------------------------------------------------------------
template <int WRITE_F32>
__global__ __launch_bounds__(256)
void ln_kernel(const float* __restrict__ x, const float* __restrict__ g,
               const float* __restrict__ bsh, unsigned short* __restrict__ obf,
               float* __restrict__ of32) {
  __shared__ float red[16];
  const int row = blockIdx.x, tid = threadIdx.x;
  const float4 v = *(const float4*)&x[(size_t)row * 1024 + tid * 4];
  float s = v.x + v.y + v.z + v.w;
  float q = v.x * v.x + v.y * v.y + v.z * v.z + v.w * v.w;
#pragma unroll
  for (int off = 32; off; off >>= 1) {
    s += __shfl_xor(s, off);
    q += __shfl_xor(q, off);
  }
  if ((tid & 63) == 0) {
    red[tid >> 6] = s;
    red[8 + (tid >> 6)] = q;
  }
  __syncthreads();
  s = red[0] + red[1] + red[2] + red[3];
  q = red[8] + red[9] + red[10] + red[11];
  const float mean = s * (1.f / 1024.f);
  const float var = q * (1.f / 1024.f) - mean * mean;
  const float rstd = rsqrtf(var + 1e-5f);
  const float4 gg = *(const float4*)&g[tid * 4];
  const float4 bb = *(const float4*)&bsh[tid * 4];
  float y0 = (v.x - mean) * rstd * gg.x + bb.x;
  float y1 = (v.y - mean) * rstd * gg.y + bb.y;
  float y2 = (v.z - mean) * rstd * gg.z + bb.z;
  float y3 = (v.w - mean) * rstd * gg.w + bb.w;
  const size_t base = (size_t)row * 1024 + tid * 4;
  ushort4 o;
  o.x = f2bf(y0); o.y = f2bf(y1); o.z = f2bf(y2); o.w = f2bf(y3);
  *(ushort4*)&obf[base] = o;
  if (WRITE_F32) {
    *(float4*)&of32[base] = make_float4(y0, y1, y2, y3);
  }
}

// ---------------------------------------------------------------------------
// GEMM 128x64 tile, 4 waves, BK=32, double-buffered, counted vmcnt(3),
// T2 XOR swizzle. For the N=1024 GEMMs (Wo, W2).
// ---------------------------------------------------------------------------
template <int EPI>
__global__ __launch_bounds__(256)
void gemm_n64(const unsigned short* __restrict__ A,
              const unsigned short* __restrict__ BT,
              const float* __restrict__ bias,
              const float* __restrict__ res,
              void* __restrict__ Cout, int M, int N, int K, float bscale) {
  __shared__ unsigned short ldsA[2][128 * 32];
  __shared__ unsigned short ldsB[2][64 * 32];
  const int tid = threadIdx.x;
  const int wv = tid >> 6, ln = tid & 63, lg = ln >> 4, lc = ln & 15;
  const int wm = wv >> 1, wn = wv & 1;
  const int nwg = gridDim.x * gridDim.y;
  const int linear = blockIdx.y * gridDim.x + blockIdx.x;
  const int swz = (linear & 7) * (nwg >> 3) + (linear >> 3);
  const int m0 = (swz / gridDim.x) * 128, n0 = (swz % gridDim.x) * 64;
  const int rsub = ln >> 2;
  const int sw_inner = ((ln & 3) * 16) ^ ((rsub & 3) << 4);
  const int acol = sw_inner >> 1;

  f32x4 acc[4][2];
#pragma unroll
  for (int i = 0; i < 4; ++i)
#pragma unroll
    for (int j = 0; j < 2; ++j) acc[i][j] = (f32x4)0.f;

  auto stage = [&](int buf, int k0) {
#pragma unroll
    for (int j = 0; j < 2; ++j) {
      const int rowblk = wv * 32 + j * 16;
      const unsigned short* ga = A + (size_t)(m0 + rowblk + rsub) * K + (k0 + acol);
      __builtin_amdgcn_global_load_lds((GAS void*)ga,
          (LAS void*)&ldsA[buf][rowblk * 32], 16, 0, 0);
    }
    const unsigned short* gb = BT + (size_t)(n0 + wv * 16 + rsub) * K + (k0 + acol);
    __builtin_amdgcn_global_load_lds((GAS void*)gb,
        (LAS void*)&ldsB[buf][wv * 16 * 32], 16, 0, 0);
  };

  const int nk = K / 32;
  stage(0, 0);
  int cur = 0;
  for (int i = 0; i < nk; ++i) {
    if (i + 1 < nk) {
      stage(cur ^ 1, (i + 1) * 32);
      asm volatile("s_waitcnt vmcnt(3)" ::: "memory");
    } else {
      asm volatile("s_waitcnt vmcnt(0)" ::: "memory");
    }
    __builtin_amdgcn_s_barrier();
    bf16x8 af[4], bf[2];
#pragma unroll
    for (int m = 0; m < 4; ++m) {
      const int r = wm * 64 + m * 16 + lc;
      af[m] = *(const bf16x8*)((const char*)&ldsA[cur][0] + r * 64 +
                               ((lg * 16) ^ ((r & 3) << 4)));
    }
#pragma unroll
    for (int n = 0; n < 2; ++n) {
      const int r = wn * 32 + n * 16 + lc;
      bf[n] = *(const bf16x8*)((const char*)&ldsB[cur][0] + r * 64 +
                               ((lg * 16) ^ ((r & 3) << 4)));
    }
    __builtin_amdgcn_s_setprio(1);
#pragma unroll
    for (int m = 0; m < 4; ++m)
#pragma unroll
      for (int n = 0; n < 2; ++n)
        acc[m][n] = __builtin_amdgcn_mfma_f32_16x16x32_bf16(af[m], bf[n], acc[m][n], 0, 0, 0);
    __builtin_amdgcn_s_setprio(0);
    __builtin_amdgcn_s_barrier();
    cur ^= 1;
  }

#pragma unroll
  for (int m = 0; m < 4; ++m) {
#pragma unroll
    for (int n = 0; n < 2; ++n) {
      const int c = n0 + wn * 32 + n * 16 + lc;
      const float bc = bias[c] * bscale;
#pragma unroll
      for (int j = 0; j < 4; ++j) {
        const int r = m0 + wm * 64 + m * 16 + lg * 4 + j;
        const size_t idx = (size_t)r * N + c;
        const float v = acc[m][n][j] + bc;
        if (EPI == 1) {
          ((float*)Cout)[idx] = res[idx] + v;
        } else {
          ((unsigned short*)Cout)[idx] = f2bf(v);
        }
      }
    }
  }
}

// ---------------------------------------------------------------------------
// GEMM 256x256, 8-wave, BK=64, 8-phase deep pipeline (m201 template).
// R11: vmcnt(4) moved AFTER the P4/P8 MFMA cluster (still before the
// barrier that releases next-phase reads) — one extra cluster of cover.
// ---------------------------------------------------------------------------
template <int EPI>
__global__ __launch_bounds__(512)
void gemm256(const unsigned short* __restrict__ A,
             const unsigned short* __restrict__ BT,
             const float* __restrict__ bias,
             const unsigned short* __restrict__ gate_u,
             unsigned short* __restrict__ Cout, int M, int N, int K) {
  __shared__ unsigned short lds[65536];   // 128 KB = 8 x 16KB slots
  const int tid = threadIdx.x;
  const int w = tid >> 6, ln = tid & 63, lg = ln >> 4, lc = ln & 15;
  const int wm = w >> 2, wn = w & 3;
  const int nwg = gridDim.x * gridDim.y;
  const int linear = blockIdx.y * gridDim.x + blockIdx.x;
  const int swzb = (linear & 7) * (nwg >> 3) + (linear >> 3);
  const int m0 = (swzb / gridDim.x) * 256, n0 = (swzb % gridDim.x) * 256;

  f32x4 acc[8][4];
#pragma unroll
  for (int i = 0; i < 8; ++i)
#pragma unroll
    for (int j = 0; j < 4; ++j) acc[i][j] = (f32x4)0.f;

  auto stage_half = [&](int tensor, int j, int hh) {
    const unsigned short* base = tensor ? BT : A;
    const int row0 = (tensor ? n0 : m0) + hh * 128;
    const int slot = tensor * 4 + (j & 1) * 2 + hh;
#pragma unroll
    for (int c = 0; c < 2; ++c) {
      const int chunk = w * 2 + c;
      const int L = chunk * 1024 + ln * 16;
      const int r = L >> 7, inner = L & 127;
      const char* src = (const char*)(base + (size_t)(row0 + r) * K + j * 64) +
                        (inner ^ ((r & 7) << 4));
      __builtin_amdgcn_global_load_lds((GAS void*)src,
          (LAS void*)((char*)lds + slot * 16384 + chunk * 1024), 16, 0, 0);
    }
  };
  auto read_a = [&](int j, int mf, int ks) -> bf16x8 {
    const int r = mf * 16 + lc;
    const int slot = (j & 1) * 2 + wm;
    const int cb = ks * 64 + lg * 16;
    return *(const bf16x8*)((const char*)lds + slot * 16384 + r * 128 +
                            (cb ^ ((r & 7) << 4)));
  };
  auto read_b = [&](int j, int nf, int ks) -> bf16x8 {
    const int R = wn * 64 + nf * 16 + lc;
    const int slot = 4 + (j & 1) * 2 + (R >> 7);
    const int r = R & 127;
    const int cb = ks * 64 + lg * 16;
    return *(const bf16x8*)((const char*)lds + slot * 16384 + r * 128 +
                            (cb ^ ((r & 7) << 4)));
  };

  const int nkt = K / 64;

  stage_half(0, 0, 0); stage_half(0, 0, 1);
  stage_half(1, 0, 0); stage_half(1, 0, 1);
  stage_half(1, 1, 0); stage_half(1, 1, 1);
  asm volatile("s_waitcnt vmcnt(0)" ::: "memory");
  __builtin_amdgcn_s_barrier();

  bf16x8 bfr[4][2];
  for (int it = 0; it < nkt / 2; ++it) {
    const int J = it * 2;
#pragma unroll
    for (int half = 0; half < 2; ++half) {
      const int jc = J + half;
#pragma unroll
      for (int q = 0; q < 4; ++q) {
        if (q == 0) {
#pragma unroll
          for (int nf = 0; nf < 4; ++nf)
#pragma unroll
            for (int ks = 0; ks < 2; ++ks) bfr[nf][ks] = read_b(jc, nf, ks);
        }
        bf16x8 afr[2][2];
#pragma unroll
        for (int mm = 0; mm < 2; ++mm)
#pragma unroll
          for (int ks = 0; ks < 2; ++ks) afr[mm][ks] = read_a(jc, q * 2 + mm, ks);
        if (half == 0) {
          if (q == 0) stage_half(0, J + 1, 0);
          if (q == 1) stage_half(0, J + 1, 1);
          if (q == 2 && J + 2 < nkt) stage_half(1, J + 2, 0);
          if (q == 3 && J + 2 < nkt) stage_half(1, J + 2, 1);
        } else {
          if (q == 0 && J + 2 < nkt) stage_half(0, J + 2, 0);
          if (q == 1 && J + 2 < nkt) stage_half(0, J + 2, 1);
          if (q == 2 && J + 3 < nkt) stage_half(1, J + 3, 0);
          if (q == 3 && J + 3 < nkt) stage_half(1, J + 3, 1);
        }
        if (q == 0) asm volatile("s_waitcnt lgkmcnt(8)" ::: "memory");
        __builtin_amdgcn_s_barrier();
        __builtin_amdgcn_s_setprio(1);
#pragma unroll
        for (int mm = 0; mm < 2; ++mm)
#pragma unroll
          for (int nf = 0; nf < 4; ++nf)
#pragma unroll
            for (int ks = 0; ks < 2; ++ks)
              acc[q * 2 + mm][nf] = __builtin_amdgcn_mfma_f32_16x16x32_bf16(
                  afr[mm][ks], bfr[nf][ks], acc[q * 2 + mm][nf], 0, 0, 0);
        __builtin_amdgcn_s_setprio(0);
        if (q == 3) asm volatile("s_waitcnt vmcnt(4)" ::: "memory");
        __builtin_amdgcn_s_barrier();
      }
    }
  }

#pragma unroll
  for (int mf = 0; mf < 8; ++mf) {
#pragma unroll
    for (int nf = 0; nf < 4; ++nf) {
      const int c = n0 + wn * 64 + nf * 16 + lc;
      const float bc = bias[c];
#pragma unroll
      for (int jj = 0; jj < 4; ++jj) {
        const int r = m0 + wm * 128 + mf * 16 + lg * 4 + jj;
        const size_t idx = (size_t)r * N + c;
        const float v = acc[mf][nf][jj] + bc;
        if (EPI == 0) {
          Cout[idx] = f2bf(v);
        } else {
          const float uu = bf2f(gate_u[idx]);
          const float sw = v / (1.f + __expf(-v));   // silu
          Cout[idx] = f2bf(uu * sw);
        }
      }
    }
  }
}

// ---------------------------------------------------------------------------
// Differential attention, NT=1, FUSED epilogue (lambda-diff + GroupNorm).
// grid(512): bh=(id&7)+8*((id>>8)&1), qt=(id>>3)&31. 4 waves x 16 q-rows,
// 64 KV tiles of 32, LDS-staged K (KP) / V (VT), counted vmcnt(4).
// Writes o_bf[b,s,h*128+e] directly.
// ---------------------------------------------------------------------------
__global__ __launch_bounds__(256)
void attn_kernel(const unsigned short* __restrict__ q,
                 const unsigned short* __restrict__ KP,
                 const unsigned short* __restrict__ VT,
                 const float* __restrict__ lam,
                 const float* __restrict__ gn_w, const float* __restrict__ gn_b,
                 unsigned short* __restrict__ o) {
  constexpr int S = 2048;
  constexpr int QS = 3072;
  __shared__ unsigned short k_tile[2][32 * 128];
  __shared__ unsigned short v_tile[2][128 * 32];
  __shared__ unsigned short p_lds[4][2][512];
  const int tid = threadIdx.x, w = tid >> 6, ln = tid & 63, lg = ln >> 4, lc = ln & 15;
  const int id = blockIdx.x;
  const int bh = (id & 7) + 8 * ((id >> 8) & 1);
  const int qt = (id >> 3) & 31;
  const int h = bh & 7, b = bh >> 3;
  const size_t chan = (size_t)b * S * QS + h * 128;
  const size_t ochan = (size_t)b * S * 1024 + h * 128;
  const size_t kpbase = (size_t)bh * S * 128;
  const size_t vtbase = (size_t)bh * 128 * S;
  const int qrow = qt * 64 + w * 16 + lc;

  bf16x8 qf[2][2];
#pragma unroll
  for (int p = 0; p < 2; ++p)
#pragma unroll
    for (int ks = 0; ks < 2; ++ks)
      qf[p][ks] = *(const bf16x8*)&q[chan + (size_t)qrow * QS + p * 64 + ks * 32 + lg * 8];

  f32x4 O[2][8];
#pragma unroll
  for (int p = 0; p < 2; ++p)
#pragma unroll
    for (int ef = 0; ef < 8; ++ef) O[p][ef] = (f32x4)0.f;
  float lsum[2][4];
#pragma unroll
  for (int p = 0; p < 2; ++p)
#pragma unroll
    for (int j = 0; j < 4; ++j) lsum[p][j] = 0.f;

  const int prd = ((lc * 64 + lg * 16) ^ ((lc & 7) << 4)) >> 1;

  auto stage = [&](int buf, int t0) {
#pragma unroll
    for (int c = 0; c < 2; ++c) {
      {
        const int L = (w * 2 + c) * 1024 + ln * 16;
        const int r = L >> 8, inner = L & 255;
        const char* src = (const char*)(KP + kpbase + (size_t)(t0 + r) * 128) +
                          (inner ^ ((r & 7) << 4));
        __builtin_amdgcn_global_load_lds((GAS void*)src,
            (LAS void*)((char*)&k_tile[buf][0] + (w * 2 + c) * 1024), 16, 0, 0);
      }
      {
        const int L = (w * 2 + c) * 1024 + ln * 16;
        const int e = L >> 6, inner = L & 63;
        const char* src = (const char*)(VT + vtbase + (size_t)e * S + t0) +
                          (inner ^ ((e & 3) << 4));
        __builtin_amdgcn_global_load_lds((GAS void*)src,
            (LAS void*)((char*)&v_tile[buf][0] + (w * 2 + c) * 1024), 16, 0, 0);
      }
    }
  };

  auto compute = [&](int buf) {
    const char* kb = (const char*)&k_tile[buf][0];
    const char* vb = (const char*)&v_tile[buf][0];
    bf16x8 vf[8];
#pragma unroll
    for (int ef = 0; ef < 8; ++ef) {
      const int e = ef * 16 + lc;
      vf[ef] = *(const bf16x8*)(vb + e * 64 + ((lg * 16) ^ ((e & 3) << 4)));
    }
#pragma unroll
    for (int p = 0; p < 2; ++p) {
      bf16x8 kf[2][2];
#pragma unroll
      for (int tf = 0; tf < 2; ++tf) {
        const int r = tf * 16 + lc;
#pragma unroll
        for (int ks = 0; ks < 2; ++ks)
          kf[tf][ks] = *(const bf16x8*)(kb + r * 256 +
                          ((p * 128 + ks * 64 + lg * 16) ^ ((r & 7) << 4)));
      }
      f32x4 sfr[2];
      __builtin_amdgcn_s_setprio(1);
#pragma unroll
      for (int tf = 0; tf < 2; ++tf) {
        f32x4 acc = (f32x4)0.f;
#pragma unroll
        for (int ks = 0; ks < 2; ++ks)
          acc = __builtin_amdgcn_mfma_f32_16x16x32_bf16(qf[p][ks], kf[tf][ks], acc, 0, 0, 0);
        sfr[tf] = acc;
      }
      __builtin_amdgcn_s_setprio(0);

#pragma unroll
      for (int tf = 0; tf < 2; ++tf)
#pragma unroll
        for (int j = 0; j < 4; ++j) {
          const float e = __expf(sfr[tf][j]);
          lsum[p][j] += e;
          const int qq = lg * 4 + j;
          const int wi = ((qq * 64 + (tf * 16 + lc) * 2) ^ ((qq & 7) << 4)) >> 1;
          p_lds[w][p][wi] = f2bf(e);
        }

      const bf16x8 pa = *(const bf16x8*)&p_lds[w][p][prd];
      __builtin_amdgcn_s_setprio(1);
#pragma unroll
      for (int ef = 0; ef < 8; ++ef)
        O[p][ef] = __builtin_amdgcn_mfma_f32_16x16x32_bf16(pa, vf[ef], O[p][ef], 0, 0, 0);
      __builtin_amdgcn_s_setprio(0);
    }
  };

  stage(0, 0);
  int cur = 0;
  for (int it = 0; it < 64; ++it) {
    if (it < 63) {
      stage(cur ^ 1, (it + 1) * 32);
      asm volatile("s_waitcnt vmcnt(4)" ::: "memory");
    } else {
      asm volatile("s_waitcnt vmcnt(0)" ::: "memory");
    }
    __builtin_amdgcn_s_barrier();
    compute(cur);
    __builtin_amdgcn_s_barrier();
    cur ^= 1;
  }

  // ---- fused epilogue: row-sum reduce, lambda-diff, GroupNorm(128), *0.2 ----
#pragma unroll
  for (int p = 0; p < 2; ++p)
#pragma unroll
    for (int j = 0; j < 4; ++j) {
      float s = lsum[p][j];
      s += __shfl_xor(s, 1);
      s += __shfl_xor(s, 2);
      s += __shfl_xor(s, 4);
      s += __shfl_xor(s, 8);
      lsum[p][j] = s;
    }
  const float lamh = lam[h];
#pragma unroll
  for (int j = 0; j < 4; ++j) {
    const float inv1 = 1.f / lsum[0][j];
    const float inv2 = lamh / lsum[1][j];
    float dv[8], sum = 0.f, sq = 0.f;
#pragma unroll
    for (int ef = 0; ef < 8; ++ef) {
      dv[ef] = O[0][ef][j] * inv1 - O[1][ef][j] * inv2;
      sum += dv[ef];
      sq += dv[ef] * dv[ef];
    }
    sum += __shfl_xor(sum, 1); sq += __shfl_xor(sq, 1);
    sum += __shfl_xor(sum, 2); sq += __shfl_xor(sq, 2);
    sum += __shfl_xor(sum, 4); sq += __shfl_xor(sq, 4);
    sum += __shfl_xor(sum, 8); sq += __shfl_xor(sq, 8);
    const float mean = sum * (1.f / 128.f);
    const float var = sq * (1.f / 128.f) - mean * mean;
    const float rstd = rsqrtf(var + 1e-5f);
    const int row = qt * 64 + w * 16 + lg * 4 + j;
#pragma unroll
    for (int ef = 0; ef < 8; ++ef) {
      const int e = ef * 16 + lc;
      const float val = (dv[ef] - mean) * rstd * gn_w[h * 128 + e] + gn_b[h * 128 + e];
      o[ochan + (size_t)row * 1024 + e] = f2bf(val * 0.2f);
    }
  }
}

// ---------------------------------------------------------------------------
extern "C" void kernel_launch(void* const* d_in, const int* in_sizes, int n_in,
                              void* d_out, int out_size, void* d_ws, size_t ws_size,
                              hipStream_t stream) {
  (void)in_sizes; (void)n_in; (void)out_size; (void)ws_size;
  const float* x    = (const float*)d_in[0];
  const float* ln1g = (const float*)d_in[1];
  const float* ln1b = (const float*)d_in[2];
  const float* ln2g = (const float*)d_in[3];
  const float* ln2b = (const float*)d_in[4];
  const float* Wq   = (const float*)d_in[5];
  const float* bq   = (const float*)d_in[6];
  const float* Wk   = (const float*)d_in[7];
  const float* bk   = (const float*)d_in[8];
  const float* Wv   = (const float*)d_in[9];
  const float* bv   = (const float*)d_in[10];
  const float* Wo   = (const float*)d_in[11];
  const float* bo   = (const float*)d_in[12];
  const float* lq1  = (const float*)d_in[13];
  const float* lk1  = (const float*)d_in[14];
  const float* lq2  = (const float*)d_in[15];
  const float* lk2  = (const float*)d_in[16];
  const float* gnw  = (const float*)d_in[17];
  const float* gnb  = (const float*)d_in[18];
  const float* W1   = (const float*)d_in[19];
  const float* b1   = (const float*)d_in[20];
  const float* Wg   = (const float*)d_in[21];
  const float* bg   = (const float*)d_in[22];
  const float* W2   = (const float*)d_in[23];
  const float* b2   = (const float*)d_in[24];

  const int B = 2, S = 2048, D = 1024, F = 4096;
  const int M = B * S;  // 4096
  const float qscale = 0.125f;

  char* ws = (char*)d_ws;
  size_t off = 0;
  auto alloc = [&](size_t bytes) {
    char* p = ws + off;
    off += (bytes + 255) & ~(size_t)255;
    return p;
  };
  unsigned short* WqkvT = (unsigned short*)alloc((size_t)3 * D * D * 2);
  unsigned short* WoT = (unsigned short*)alloc((size_t)D * D * 2);
  unsigned short* W1T = (unsigned short*)alloc((size_t)F * D * 2);
  unsigned short* WgT = (unsigned short*)alloc((size_t)F * F * 2);
  unsigned short* W2T = (unsigned short*)alloc((size_t)D * F * 2);
  float*          lamw= (float*)alloc(256);
  float*          bqkv= (float*)alloc(3072 * 4);
  unsigned short* h_bf= (unsigned short*)alloc((size_t)M * D * 2);
  unsigned short* qkv = (unsigned short*)alloc((size_t)M * 3 * D * 2);
  unsigned short* o_bf= (unsigned short*)alloc((size_t)M * D * 2);
  float*          x1  = (float*)alloc((size_t)M * D * 4);
  float*          x2  = (float*)alloc((size_t)M * D * 4);
  unsigned short* x2b = (unsigned short*)alloc((size_t)M * D * 2);
  unsigned short* u_bf= (unsigned short*)alloc((size_t)M * F * 2);
  unsigned short* w_bf= h_bf;   // gated act reuses h span (dead after qkv GEMM)

  // Overlays (spans dead during overlay use):
  //  KP (8MB) on x1 (written later by Wo-gemm).
  //  VT (8MB) in u_bf[24:32MB) (u_bf written later by W1-gemm).
  unsigned short* KP = (unsigned short*)x1;
  unsigned short* VT = u_bf + (size_t)12 * 1024 * 1024;

  // --- weight prep ---
  transpose_cvt<<<dim3(D / 64, D / 64), 256, 0, stream>>>(Wq, WqkvT, D, D, qscale);
  transpose_cvt<<<dim3(D / 64, D / 64), 256, 0, stream>>>(Wk, WqkvT + (size_t)D * D, D, D, 1.0f);
  transpose_cvt<<<dim3(D / 64, D / 64), 256, 0, stream>>>(Wv, WqkvT + (size_t)2 * D * D, D, D, 1.0f);
  transpose_cvt<<<dim3(D / 64, D / 64), 256, 0, stream>>>(Wo, WoT, D, D, 1.0f);
  transpose_cvt<<<dim3(F / 64, D / 64), 256, 0, stream>>>(W1, W1T, D, F, 1.0f);
  transpose_cvt<<<dim3(F / 64, F / 64), 256, 0, stream>>>(Wg, WgT, F, F, 1.0f);
  transpose_cvt<<<dim3(D / 64, F / 64), 256, 0, stream>>>(W2, W2T, F, D, 1.0f);
  prep_bias<<<12, 256, 0, stream>>>(bq, bk, bv, bqkv, qscale);
  lam_kernel<<<1, 512, 0, stream>>>(lq1, lk1, lq2, lk2, lamw);

  // --- attention sublayer ---
  ln_kernel<0><<<M, 256, 0, stream>>>(x, ln1g, ln1b, h_bf, nullptr);
  gemm256<0><<<dim3(3 * D / 256, M / 256), 512, 0, stream>>>(h_bf, WqkvT, bqkv, nullptr, qkv, M, 3 * D, D);
  k_pack<<<dim3(S / 16, 16), 256, 0, stream>>>(qkv, KP);
  v_transpose<<<dim3(S / 64, 2, 16), 256, 0, stream>>>(qkv + 2048, VT);
  attn_kernel<<<dim3(512), 256, 0, stream>>>(qkv, KP, VT, lamw, gnw, gnb, o_bf);
  gemm_n64<1><<<dim3(D / 64, M / 128), 256, 0, stream>>>(o_bf, WoT, bo, x, x1, M, D, D, 1.0f);

  // --- FFN sublayer ---
  ln_kernel<1><<<M, 256, 0, stream>>>(x1, ln2g, ln2b, x2b, x2);
  gemm256<0><<<dim3(F / 256, M / 256), 512, 0, stream>>>(x2b, W1T, b1, nullptr, u_bf, M, F, D);
  gemm256<2><<<dim3(F / 256, M / 256), 512, 0, stream>>>(u_bf, WgT, bg, u_bf, w_bf, M, F, F);
  gemm_n64<1><<<dim3(D / 64, M / 128), 256, 0, stream>>>(w_bf, W2T, b2, x2, (float*)d_out, M, D, F, 1.0f);
}